// Round 17
// baseline (920.841 us; speedup 1.0000x reference)
//
#include <hip/hip_runtime.h>
#include <hip/hip_bf16.h>
#include <math.h>

#define B_ 2
#define T_ 2048
#define D_ 512
#define H_ 8
#define NL_ 4
#define V_ 32000
#define HD_ 64
#define BT_ (B_*T_)
#define EPS_ 1e-5f
#define SCALE_ 0.04419417382415922f  /* 1/sqrt(512) — source scales by D, not HD */
#define NEGBIG -1e30f

typedef __bf16 bf16x8 __attribute__((ext_vector_type(8)));
typedef float  f32x4  __attribute__((ext_vector_type(4)));

__device__ __forceinline__ unsigned short f2bf(float f) {
  union { float f; unsigned u; } v; v.f = f;
  unsigned r = v.u + 0x7fff + ((v.u >> 16) & 1);
  return (unsigned short)(r >> 16);
}

__device__ __forceinline__ void gl_lds16(const void* g, void* l) {
  __builtin_amdgcn_global_load_lds(
      (const __attribute__((address_space(1))) void*)g,
      (__attribute__((address_space(3))) void*)l, 16, 0, 0);
}

#define WAITVM(n) asm volatile("s_waitcnt vmcnt(" #n ")" ::: "memory")
#define WAITLG0   asm volatile("s_waitcnt lgkmcnt(0)" ::: "memory")

// ---------------------------------------------------------------- embed
__global__ __launch_bounds__(256) void embed_kernel(
    const int* __restrict__ ids, const float* __restrict__ tok,
    const float* __restrict__ pos, float* __restrict__ x)
{
  int i = blockIdx.x * 256 + threadIdx.x;
  int d4 = i & (D_/4 - 1);
  int bt = i >> 7;
  int t  = bt & (T_ - 1);
  const float4 a = reinterpret_cast<const float4*>(tok + (size_t)ids[bt] * D_)[d4];
  const float4 p = reinterpret_cast<const float4*>(pos + (size_t)t * D_)[d4];
  float4 r; r.x = a.x + p.x; r.y = a.y + p.y; r.z = a.z + p.z; r.w = a.w + p.w;
  reinterpret_cast<float4*>(x)[i] = r;
}

// ---------------------------------------------------------------- layernorm -> bf16 out
__global__ __launch_bounds__(256) void ln_kernel(
    const float* __restrict__ x, const float* __restrict__ g,
    const float* __restrict__ b, unsigned short* __restrict__ out)
{
  int row  = blockIdx.x * 4 + (threadIdx.x >> 6);
  int lane = threadIdx.x & 63;
  const float4* xr = reinterpret_cast<const float4*>(x + (size_t)row * D_);
  float4 v0 = xr[lane], v1 = xr[lane + 64];
  float s = v0.x + v0.y + v0.z + v0.w + v1.x + v1.y + v1.z + v1.w;
  float q = v0.x*v0.x + v0.y*v0.y + v0.z*v0.z + v0.w*v0.w
          + v1.x*v1.x + v1.y*v1.y + v1.z*v1.z + v1.w*v1.w;
  #pragma unroll
  for (int off = 1; off < 64; off <<= 1) {
    s += __shfl_xor(s, off);
    q += __shfl_xor(q, off);
  }
  float mean = s * (1.0f / D_);
  float var  = q * (1.0f / D_) - mean * mean;
  float rs   = rsqrtf(var + EPS_);
  const float4* g4 = reinterpret_cast<const float4*>(g);
  const float4* b4 = reinterpret_cast<const float4*>(b);
  float4 gv0 = g4[lane], gv1 = g4[lane + 64];
  float4 bv0 = b4[lane], bv1 = b4[lane + 64];
  ushort4 p0, p1;
  p0.x = f2bf((v0.x - mean) * rs * gv0.x + bv0.x);
  p0.y = f2bf((v0.y - mean) * rs * gv0.y + bv0.y);
  p0.z = f2bf((v0.z - mean) * rs * gv0.z + bv0.z);
  p0.w = f2bf((v0.w - mean) * rs * gv0.w + bv0.w);
  p1.x = f2bf((v1.x - mean) * rs * gv1.x + bv1.x);
  p1.y = f2bf((v1.y - mean) * rs * gv1.y + bv1.y);
  p1.z = f2bf((v1.z - mean) * rs * gv1.z + bv1.z);
  p1.w = f2bf((v1.w - mean) * rs * gv1.w + bv1.w);
  unsigned short* orow = out + (size_t)row * D_;
  *reinterpret_cast<ushort4*>(orow + lane * 4)       = p0;
  *reinterpret_cast<ushort4*>(orow + 256 + lane * 4) = p1;
}

// ---------------------------------------------------------------- transpose+cast fp32 [R][C] -> bf16 [C][R]
__global__ __launch_bounds__(256) void transpose_cast(
    const float* __restrict__ src, unsigned short* __restrict__ dst,
    int C, int R, long sstride, long dstride)
{
  src += (size_t)blockIdx.z * sstride;
  dst += (size_t)blockIdx.z * dstride;
  __shared__ float t[32][33];
  int r0 = blockIdx.x * 32, c0 = blockIdx.y * 32;
  int tx = threadIdx.x & 31, ty = threadIdx.x >> 5;
  #pragma unroll
  for (int i = 0; i < 4; i++)
    t[ty + i*8][tx] = src[(size_t)(r0 + ty + i*8) * C + c0 + tx];
  __syncthreads();
  #pragma unroll
  for (int i = 0; i < 4; i++)
    dst[(size_t)(c0 + ty + i*8) * R + r0 + tx] = f2bf(t[tx][ty + i*8]);
}

// WqkvT[l][mat*512 + h*64 + e][d] = W{q,k,v}[l][h][d][e]
__global__ __launch_bounds__(256) void qkvw_transpose(
    const float* __restrict__ Wq, const float* __restrict__ Wk,
    const float* __restrict__ Wv, unsigned short* __restrict__ dst)
{
  int z = blockIdx.z; int l = z / 24; int rem = z % 24; int mat = rem >> 3; int h = rem & 7;
  const float* W = (mat == 0 ? Wq : (mat == 1 ? Wk : Wv)) + ((size_t)(l * 8 + h)) * D_ * HD_;
  unsigned short* d = dst + ((size_t)l * 1536 + mat * 512 + h * 64) * D_;
  __shared__ float t[32][33];
  int d0 = blockIdx.x * 32, e0 = blockIdx.y * 32;
  int tx = threadIdx.x & 31, ty = threadIdx.x >> 5;
  #pragma unroll
  for (int i = 0; i < 4; i++)
    t[ty + i*8][tx] = W[(size_t)(d0 + ty + i*8) * HD_ + e0 + tx];
  __syncthreads();
  #pragma unroll
  for (int i = 0; i < 4; i++)
    d[(size_t)(e0 + ty + i*8) * D_ + d0 + tx] = f2bf(t[tx][ty + i*8]);
}

// ---------------------------------------------------------------- logits GEMM: 128x256 tile
// Grid MUST be (32, 125). Panel-per-XCD mapping keeps each Wp panel in one XCD L2.
__global__ __launch_bounds__(512, 4) void gemm_logits(
    const unsigned short* __restrict__ A,
    const unsigned short* __restrict__ Bt,
    int K, const float* __restrict__ bias,
    float* __restrict__ outF, int ldc,
    float2* __restrict__ ms, int npan)
{
  __shared__ __align__(16) char smem[73728];
  unsigned short* Abase = (unsigned short*)smem;
  unsigned short* Bbase = (unsigned short*)(smem + 24576);
  float* E = (float*)smem;

  const int tid = threadIdx.x;
  const int lane = tid & 63;
  const int lr = lane & 15, g = lane >> 4;
  const int wv = tid >> 6, wm = wv >> 2, wn = wv & 3;

  const int id0 = blockIdx.y * gridDim.x + blockIdx.x;
  const int xcd = id0 & 7, j = id0 >> 3;
  int p, bxn;
  if (j < 480) { p = xcd * 15 + (j >> 5); bxn = j & 31; }
  else { const int k = xcd * 20 + (j - 480); p = 120 + (k >> 5); bxn = k & 31; }
  const int bm = bxn * 128, bn = p * 256, bnp = p;

  const int schk = (lane & 3) ^ ((lane >> 3) & 3);
  const unsigned short* Ab = A  + (size_t)(bm + wv*16 + (lane >> 2)) * K + schk * 8;
  const unsigned short* Bb = Bt + (size_t)(bn + wv*16 + (lane >> 2)) * K + schk * 8;

#define STAGEL(s, sl)                                                       \
  { const int kof_ = (s) * 32;                                              \
    gl_lds16(Ab + kof_,                 Abase + (sl)*4096 + wv*512);        \
    gl_lds16(Bb + kof_,                 Bbase + (sl)*8192 + wv*512);        \
    gl_lds16(Bb + (size_t)128*K + kof_, Bbase + (sl)*8192 + 4096 + wv*512); }

  f32x4 acc[4][4];
  #pragma unroll
  for (int m = 0; m < 4; m++)
    #pragma unroll
    for (int n = 0; n < 4; n++)
      acc[m][n] = (f32x4){0.f, 0.f, 0.f, 0.f};

  const int nt = K >> 5;
  STAGEL(0, 0); STAGEL(1, 1);

  const int slotx = (g ^ ((lr >> 1) & 3)) << 3;

  for (int t = 0; t < nt; ++t) {
    const int s = t + 2;
    const int st = t % 3;
    __builtin_amdgcn_sched_barrier(0);
    if      (s < nt)  { const int ss = s % 3; STAGEL(s, ss); WAITVM(6); }
    else if (s == nt) { WAITVM(3); }
    else              { WAITVM(0); }
    __builtin_amdgcn_sched_barrier(0);
    __builtin_amdgcn_s_barrier();
    __builtin_amdgcn_sched_barrier(0);

    const unsigned short* Ac = Abase + st*4096;
    const unsigned short* Bc = Bbase + st*8192;
    bf16x8 af[4], bfr[4];
    #pragma unroll
    for (int m = 0; m < 4; m++)
      af[m] = *reinterpret_cast<const bf16x8*>(&Ac[(wm*64 + m*16 + lr) * 32 + slotx]);
    #pragma unroll
    for (int n = 0; n < 4; n++)
      bfr[n] = *reinterpret_cast<const bf16x8*>(&Bc[(wn*64 + n*16 + lr) * 32 + slotx]);
    __builtin_amdgcn_s_setprio(1);
    #pragma unroll
    for (int m = 0; m < 4; m++)
      #pragma unroll
      for (int n = 0; n < 4; n++)
        acc[m][n] = __builtin_amdgcn_mfma_f32_16x16x32_bf16(af[m], bfr[n], acc[m][n], 0, 0, 0);
    __builtin_amdgcn_s_setprio(0);
    __builtin_amdgcn_sched_barrier(0);
    __builtin_amdgcn_s_barrier();
  }
#undef STAGEL

  #pragma unroll
  for (int n = 0; n < 4; n++) {
    const float bv = bias ? bias[bn + wn*64 + n*16 + lr] : 0.f;
    #pragma unroll
    for (int m = 0; m < 4; m++)
      #pragma unroll
      for (int r = 0; r < 4; r++)
        acc[m][n][r] += bv;
  }

  if (ms) {
    #pragma unroll
    for (int m = 0; m < 4; m++) {
      float vmax[4] = {NEGBIG, NEGBIG, NEGBIG, NEGBIG};
      #pragma unroll
      for (int n = 0; n < 4; n++)
        #pragma unroll
        for (int r = 0; r < 4; r++)
          vmax[r] = fmaxf(vmax[r], acc[m][n][r]);
      #pragma unroll
      for (int r = 0; r < 4; r++) {
        #pragma unroll
        for (int off = 1; off < 16; off <<= 1)
          vmax[r] = fmaxf(vmax[r], __shfl_xor(vmax[r], off));
      }
      float vsum[4] = {0.f, 0.f, 0.f, 0.f};
      #pragma unroll
      for (int n = 0; n < 4; n++)
        #pragma unroll
        for (int r = 0; r < 4; r++)
          vsum[r] += __expf(acc[m][n][r] - vmax[r]);
      #pragma unroll
      for (int r = 0; r < 4; r++) {
        #pragma unroll
        for (int off = 1; off < 16; off <<= 1)
          vsum[r] += __shfl_xor(vsum[r], off);
      }
      if (lr == 0) {
        #pragma unroll
        for (int r = 0; r < 4; r++)
          ms[(size_t)(bm + wm*64 + m*16 + g*4 + r) * npan + bnp*4 + wn] =
              make_float2(vmax[r], vsum[r]);
      }
    }
  }

  #pragma unroll
  for (int c = 0; c < 2; ++c) {
    __syncthreads();
    if (wm == c) {
      #pragma unroll
      for (int m = 0; m < 4; m++)
        #pragma unroll
        for (int n = 0; n < 4; n++)
          #pragma unroll
          for (int r = 0; r < 4; r++)
            E[(m*16 + g*4 + r) * 260 + wn*64 + n*16 + lr] = acc[m][n][r];
    }
    __syncthreads();
    #pragma unroll
    for (int rep = 0; rep < 8; rep++) {
      const int row = rep*8 + wv;
      f32x4 v = *reinterpret_cast<const f32x4*>(&E[row*260 + lane*4]);
      __builtin_nontemporal_store(
          v, reinterpret_cast<f32x4*>(&outF[(size_t)(bm + c*64 + row) * ldc + bn + lane*4]));
    }
  }
}

// ---------------------------------------------------------------- pipelined bf16 MFMA GEMM
// BMxBN tile, BK=64 per sync, 3 LDS buffers, DEPTH-2 counted vmcnt, XOR swizzle.
template<int BM_T, int BN_T, int WM, int WN>
__global__ __launch_bounds__(256) void gemm_pipe(
    const unsigned short* __restrict__ A,
    const unsigned short* __restrict__ Bt,
    int K,
    const float* __restrict__ bias,
    const float* __restrict__ resid,
    float* __restrict__ outF,
    unsigned short* __restrict__ outH,
    int ldc, int relu)
{
  constexpr int BKp = 64;
  constexpr int ALOADS = BM_T / 32;
  constexpr int BLOADS = BN_T / 32;
  constexpr int LOADS  = ALOADS + BLOADS;
  constexpr int MR = BM_T / (16 * WM);
  constexpr int NR = BN_T / (16 * WN);
  __shared__ __align__(16) unsigned short As[3][BM_T * BKp];
  __shared__ __align__(16) unsigned short Bs[3][BN_T * BKp];

  const int tid = threadIdx.x;
  const int lane = tid & 63, wv = tid >> 6;
  const int lr = lane & 15, g = lane >> 4;

  const int gx = gridDim.x;
  int id = blockIdx.y * gx + blockIdx.x;
  const int nwg = gx * gridDim.y;
  if ((nwg & 7) == 0) {
    const int q = nwg >> 3;
    id = (id & 7) * q + (id >> 3);
  }
  const int bm = (id % gx) * BM_T, bn = (id / gx) * BN_T;

  const int m0w = (wv / WN) * (BM_T / WM);
  const int n0w = (wv % WN) * (BN_T / WN);

  const int srow = wv*8 + (lane >> 3);
  const int schk = (lane & 7) ^ (lane >> 3);
  const unsigned short* Ab = A  + (size_t)(bm + srow) * K + schk * 8;
  const unsigned short* Bb = Bt + (size_t)(bn + srow) * K + schk * 8;

#define STAGEP(s, sl)                                                           \
  { const int kof_ = (s) * BKp;                                                 \
    _Pragma("unroll")                                                           \
    for (int i_ = 0; i_ < ALOADS; ++i_)                                         \
      gl_lds16(Ab + (size_t)(i_*32)*K + kof_, As[sl] + i_*2048 + wv*512);       \
    _Pragma("unroll")                                                           \
    for (int i_ = 0; i_ < BLOADS; ++i_)                                         \
      gl_lds16(Bb + (size_t)(i_*32)*K + kof_, Bs[sl] + i_*2048 + wv*512); }

  f32x4 acc[MR][NR];
  #pragma unroll
  for (int m = 0; m < MR; m++)
    #pragma unroll
    for (int n = 0; n < NR; n++)
      acc[m][n] = (f32x4){0.f, 0.f, 0.f, 0.f};

  const int nt = K >> 6;
  STAGEP(0, 0);
  STAGEP(1, 1);

  for (int t = 0; t < nt; ++t) {
    const int st = t % 3;
    __builtin_amdgcn_sched_barrier(0);
    if (t + 2 < nt) {
      const int ss = (t + 2) % 3;
      STAGEP(t + 2, ss);
      if constexpr (LOADS == 4) WAITVM(8);
      else if constexpr (LOADS == 6) WAITVM(12);
      else WAITVM(8);
    } else if (t + 1 < nt) {
      if constexpr (LOADS == 4) WAITVM(4);
      else if constexpr (LOADS == 6) WAITVM(6);
      else WAITVM(4);
    } else {
      WAITVM(0);
    }
    __builtin_amdgcn_sched_barrier(0);
    __builtin_amdgcn_s_barrier();          // tile t visible to all waves
    __builtin_amdgcn_sched_barrier(0);

    const unsigned short* Ac = As[st];
    const unsigned short* Bc = Bs[st];
    #pragma unroll
    for (int kk = 0; kk < 2; ++kk) {
      const int sl = ((kk*4 + g) ^ (lr & 7)) << 3;
      bf16x8 af[MR], bfr[NR];
      #pragma unroll
      for (int m = 0; m < MR; m++)
        af[m] = *reinterpret_cast<const bf16x8*>(&Ac[(m0w + m*16 + lr) * BKp + sl]);
      #pragma unroll
      for (int n = 0; n < NR; n++)
        bfr[n] = *reinterpret_cast<const bf16x8*>(&Bc[(n0w + n*16 + lr) * BKp + sl]);
      __builtin_amdgcn_s_setprio(1);
      #pragma unroll
      for (int m = 0; m < MR; m++)
        #pragma unroll
        for (int n = 0; n < NR; n++)
          acc[m][n] = __builtin_amdgcn_mfma_f32_16x16x32_bf16(af[m], bfr[n], acc[m][n], 0, 0, 0);
      __builtin_amdgcn_s_setprio(0);
    }
    __builtin_amdgcn_sched_barrier(0);
    __builtin_amdgcn_s_barrier();          // all waves done reading buf[st]
  }
#undef STAGEP

  const int cr = g * 4;
  const int cc = lr;
  #pragma unroll
  for (int m = 0; m < MR; m++) {
    #pragma unroll
    for (int n = 0; n < NR; n++) {
      int row = bm + m0w + m*16 + cr;
      int col = bn + n0w + n*16 + cc;
      f32x4 a = acc[m][n];
      #pragma unroll
      for (int r = 0; r < 4; r++) {
        float v = a[r];
        if (bias)  v += bias[col];
        if (resid) v += resid[(size_t)(row + r) * ldc + col];
        if (relu)  v = fmaxf(v, 0.f);
        if (outF)  outF[(size_t)(row + r) * ldc + col] = v;
        if (outH)  outH[(size_t)(row + r) * ldc + col] = f2bf(v);
      }
    }
  }
}

// ---------------------------------------------------------------- MFMA flash attention (bf16 in/out)
// 128 q-rows per block, 8 waves, work-split (flash-decoding for qb>=8),
// defer-max (THR=8), launch_bounds caps VGPR at 128 -> 2 blocks/CU.
__global__ __launch_bounds__(512, 4) void attn_mfma(
    const unsigned short* __restrict__ qkv,  // bf16 [B*T][1536]
    unsigned short* __restrict__ o,          // bf16 [B*T][512]
    float* __restrict__ Opart,               // [128 blk][2][128][64] fp32
    float2* __restrict__ ml)                 // [128 blk][2][128]
{
  __shared__ __align__(16) unsigned short Ks[2][64*64];
  __shared__ __align__(16) unsigned short Vt[2][64*64];
  __shared__ __align__(16) unsigned short Ps[8][16*64];

  static const unsigned char ord[24] = {7,22,23,20,21,6,18,19,16,17,5,14,15,12,13,4,10,11,8,9,3,2,1,0};
  const int slot = ord[blockIdx.x];
  const int bh = blockIdx.y, bb = bh >> 3, hh = bh & 7;
  int qb, it0, itn, half;
  if (slot < 8) { qb = slot; it0 = 0; itn = 2*qb + 2; half = -1; }
  else { const int p = slot - 8; qb = 8 + (p >> 1); half = p & 1;
         const int nh = qb + 1; it0 = half * nh; itn = nh; }

  const int tid = threadIdx.x, lane = tid & 63, wv = tid >> 6;
  const int lr = lane & 15, g = lane >> 4;

  const unsigned short* qp = qkv + ((size_t)(bb*T_ + qb*128))*1536 + hh*64;
  const unsigned short* kp = qkv + ((size_t)bb*T_)*1536 + 512  + hh*64;
  const unsigned short* vp = qkv + ((size_t)bb*T_)*1536 + 1024 + hh*64;

  bf16x8 qf[2];
  qf[0] = *reinterpret_cast<const bf16x8*>(qp + (size_t)(wv*16 + lr)*1536 + g*8);
  qf[1] = *reinterpret_cast<const bf16x8*>(qp + (size_t)(wv*16 + lr)*1536 + 32 + g*8);

  const int krow = wv*8 + (lane >> 3);
  const int khb  = (lane & 7) ^ (lane >> 3);

#define STAGE_K(s0_, buf_)                                           \
  gl_lds16(kp + (size_t)((s0_)*64 + krow)*1536 + khb*8,              \
           (void*)(Ks[buf_] + wv*512));

  uint4 uvr;
#define LOAD_V(s0_)                                                  \
  uvr = *reinterpret_cast<const uint4*>(                             \
      vp + (size_t)((s0_)*64 + lane)*1536 + wv*8);

  f32x4 ov[4];
  #pragma unroll
  for (int n = 0; n < 4; n++) ov[n] = (f32x4){0.f, 0.f, 0.f, 0.f};
  float mrow[4] = {NEGBIG, NEGBIG, NEGBIG, NEGBIG};
  float lrow[4] = {0.f, 0.f, 0.f, 0.f};

  STAGE_K(it0, 0);
  LOAD_V(it0);

  for (int ii = 0; ii < itn; ++ii) {
    const int s0 = it0 + ii;
    const int cur = ii & 1;
    WAITVM(0);
    __builtin_amdgcn_sched_barrier(0);
    {
      union { uint4 v; unsigned short e[8]; } uv; uv.v = uvr;
      #pragma unroll
      for (int j = 0; j < 8; j++)
        Vt[cur][(wv*8 + j)*64 + (((lane >> 3) ^ j) << 3) + (lane & 7)] = uv.e[j];
    }
    WAITLG0;
    __builtin_amdgcn_sched_barrier(0);
    __builtin_amdgcn_s_barrier();
    __builtin_amdgcn_sched_barrier(0);

    if (ii + 1 < itn) {
      STAGE_K(s0 + 1, cur ^ 1);
      LOAD_V(s0 + 1);
    }

    // --- S = Q @ K^T
    f32x4 sf[4];
    #pragma unroll
    for (int n = 0; n < 4; n++) sf[n] = (f32x4){0.f, 0.f, 0.f, 0.f};
    __builtin_amdgcn_s_setprio(1);
    #pragma unroll
    for (int kk = 0; kk < 2; kk++) {
      #pragma unroll
      for (int n = 0; n < 4; n++) {
        const bf16x8 kf = *reinterpret_cast<const bf16x8*>(
            &Ks[cur][(n*16 + lr)*64 + (((kk*4 + g) ^ (lr & 7)) << 3)]);
        sf[n] = __builtin_amdgcn_mfma_f32_16x16x32_bf16(qf[kk], kf, sf[n], 0, 0, 0);
      }
    }
    __builtin_amdgcn_s_setprio(0);

    // --- scale + causal mask
    float sv[4][4];
    #pragma unroll
    for (int n = 0; n < 4; n++)
      #pragma unroll
      for (int r = 0; r < 4; r++) {
        const int kvg = s0*64 + n*16 + lr;
        const int qg  = qb*128 + wv*16 + g*4 + r;
        sv[n][r] = (kvg > qg) ? NEGBIG : sf[n][r] * SCALE_;
      }

    // --- tile max per row; defer-max: rescale only if some row grew > THR=8
    float pmv[4];
    bool need = false;
    #pragma unroll
    for (int r = 0; r < 4; r++) {
      float pm = fmaxf(fmaxf(sv[0][r], sv[1][r]), fmaxf(sv[2][r], sv[3][r]));
      pm = fmaxf(pm, __shfl_xor(pm, 1));
      pm = fmaxf(pm, __shfl_xor(pm, 2));
      pm = fmaxf(pm, __shfl_xor(pm, 4));
      pm = fmaxf(pm, __shfl_xor(pm, 8));
      pmv[r] = pm;
      need |= (pm > mrow[r] + 8.0f);
    }
    if (__ballot(need)) {
      #pragma unroll
      for (int r = 0; r < 4; r++) {
        float mn = fmaxf(mrow[r], pmv[r]);
        float aa = __expf(mrow[r] - mn);
        mrow[r] = mn;
        lrow[r] *= aa;
        #pragma unroll
        for (int n = 0; n < 4; n++) ov[n][r] *= aa;
      }
    }
    float rs[4] = {0.f, 0.f, 0.f, 0.f};
    #pragma unroll
    for (int n = 0; n < 4; n++)
      #pragma unroll
      for (int r = 0; r < 4; r++) {
        float p = __expf(sv[n][r] - mrow[r]);   // bounded by e^8 under defer
        rs[r] += p;
        Ps[wv][(g*4 + r)*64 + ((((n << 1) + (lr >> 3)) ^ ((g*4 + r) & 7)) << 3) + (lr & 7)] = f2bf(p);
      }
    #pragma unroll
    for (int r = 0; r < 4; r++) {
      float s = rs[r];
      s += __shfl_xor(s, 1); s += __shfl_xor(s, 2);
      s += __shfl_xor(s, 4); s += __shfl_xor(s, 8);
      lrow[r] += s;
    }

    // --- O += P @ V
    __builtin_amdgcn_s_setprio(1);
    #pragma unroll
    for (int kk = 0; kk < 2; kk++) {
      const bf16x8 pf = *reinterpret_cast<const bf16x8*>(
          &Ps[wv][lr*64 + (((kk*4 + g) ^ (lr & 7)) << 3)]);
      #pragma unroll
      for (int n = 0; n < 4; n++) {
        const bf16x8 vf = *reinterpret_cast<const bf16x8*>(
            &Vt[cur][(n*16 + lr)*64 + (((kk*4 + g) ^ (lr & 7)) << 3)]);
        ov[n] = __builtin_amdgcn_mfma_f32_16x16x32_bf16(pf, vf, ov[n], 0, 0, 0);
      }
    }
    __builtin_amdgcn_s_setprio(0);
    __builtin_amdgcn_sched_barrier(0);
    __builtin_amdgcn_s_barrier();
  }
#undef STAGE_K
#undef LOAD_V

  if (half < 0) {
    #pragma unroll
    for (int r = 0; r < 4; r++) {
      float inv = 1.0f / lrow[r];
      size_t row = (size_t)(bb*T_ + qb*128 + wv*16 + g*4 + r);
      #pragma unroll
      for (int n = 0; n < 4; n++)
        o[row*D_ + hh*64 + n*16 + lr] = f2bf(ov[n][r] * inv);
    }
  } else {
    const int blk = bh*8 + (qb - 8);
    float* Od = Opart + ((size_t)blk*2 + half)*128*64;
    #pragma unroll
    for (int r = 0; r < 4; r++) {
      const int rloc = wv*16 + g*4 + r;
      #pragma unroll
      for (int n = 0; n < 4; n++)
        Od[rloc*64 + n*16 + lr] = ov[n][r];
      if (lr == 0)
        ml[((size_t)blk*2 + half)*128 + rloc] = make_float2(mrow[r], lrow[r]);
    }
  }
}

// ---------------------------------------------------------------- attention split-merge
__global__ __launch_bounds__(256) void attn_merge(
    const float* __restrict__ Opart, const float2* __restrict__ ml,
    unsigned short* __restrict__ o)
{
  const int blk = blockIdx.x;
  const int bh = blk >> 3, qb = (blk & 7) + 8;
  const int bb = bh >> 3, hh = bh & 7;
  const int tid = threadIdx.x;
  const int row = tid >> 1, ch = (tid & 1) * 32;
  const float* O0 = Opart + ((size_t)blk*2 + 0)*128*64;
  const float* O1 = Opart + ((size_t)blk*2 + 1)*128*64;
  const float2 a = ml[(size_t)blk*2*128 + row];
  const float2 b = ml[((size_t)blk*2 + 1)*128 + row];
  const float M  = fmaxf(a.x, b.x);
  const float e0 = __expf(a.x - M), e1 = __expf(b.x - M);
  const float inv = 1.0f / (a.y*e0 + b.y*e1);
  unsigned short* orow = o + ((size_t)(bb*T_ + qb*128 + row))*D_ + hh*64 + ch;
  #pragma unroll
  for (int c = 0; c < 32; c += 4) {
    f32x4 v0 = *reinterpret_cast<const f32x4*>(&O0[row*64 + ch + c]);
    f32x4 v1 = *reinterpret_cast<const f32x4*>(&O1[row*64 + ch + c]);
    ushort4 pk;
    pk.x = f2bf((v0[0]*e0 + v1[0]*e1) * inv);
    pk.y = f2bf((v0[1]*e0 + v1[1]*e1) * inv);
    pk.z = f2bf((v0[2]*e0 + v1[2]*e1) * inv);
    pk.w = f2bf((v0[3]*e0 + v1[3]*e1) * inv);
    *reinterpret_cast<ushort4*>(&orow[c]) = pk;
  }
}

// ---------------------------------------------------------------- loss: merge per-panel partials
__global__ __launch_bounds__(256) void loss_merge_kernel(
    const float2* __restrict__ ms, const float* __restrict__ logits,
    const int* __restrict__ labels, float* __restrict__ rowloss, int npan)
{
  const int tid = threadIdx.x, lane = tid & 63, wid = tid >> 6;
  const int row = blockIdx.x * 4 + wid;
  float M = NEGBIG, S = 0.f;
  const float2* p = ms + (size_t)row * npan;
  for (int i = lane; i < npan; i += 64) {
    float2 e = p[i];
    float Mn = fmaxf(M, e.x);
    S = S * __expf(M - Mn) + e.y * __expf(e.x - Mn);
    M = Mn;
  }
  #pragma unroll
  for (int off = 1; off < 64; off <<= 1) {
    float Mo = __shfl_xor(M, off), So = __shfl_xor(S, off);
    float Mn = fmaxf(M, Mo);
    S = S * __expf(M - Mn) + So * __expf(Mo - Mn);
    M = Mn;
  }
  if (lane == 0)
    rowloss[row] = logits[(size_t)row * V_ + labels[row]] - M - logf(S);
}

__global__ __launch_bounds__(256) void loss_final_kernel(
    const float* __restrict__ rowloss, float* __restrict__ out)
{
  __shared__ float red[4];
  const int tid = threadIdx.x, lane = tid & 63, wid = tid >> 6;
  float s = 0.f;
  for (int i = tid; i < BT_; i += 256) s += rowloss[i];
  #pragma unroll
  for (int off = 1; off < 64; off <<= 1) s += __shfl_xor(s, off);
  if (lane == 0) red[wid] = s;
  __syncthreads();
  if (tid == 0) out[0] = -(red[0] + red[1] + red[2] + red[3]) * (1.0f / BT_);
}

// ---------------------------------------------------------------- launch
extern "C" void kernel_launch(void* const* d_in, const int* in_sizes, int n_in,
                              void* d_out, int out_size, void* d_ws, size_t ws_size,
                              hipStream_t stream)
{
  (void)in_sizes; (void)n_in; (void)out_size; (void)ws_size;
  const int*   ids    = (const int*)d_in[0];
  const int*   labels = (const int*)d_in[1];
  const float* tok    = (const float*)d_in[2];
  const float* pos    = (const float*)d_in[3];
  const float* Wq     = (const float*)d_in[4];
  const float* Wk     = (const float*)d_in[5];
  const float* Wv     = (const float*)d_in[6];
  const float* Wo     = (const float*)d_in[7];
  const float* bo     = (const float*)d_in[8];
  const float* ln1g   = (const float*)d_in[9];
  const float* ln1b   = (const float*)d_in[10];
  const float* ln2g   = (const float*)d_in[11];
  const float* ln2b   = (const float*)d_in[12];
  const float* W1     = (const float*)d_in[13];
  const float* b1     = (const float*)d_in[14];
  const float* W2     = (const float*)d_in[15];
  const float* b2     = (const float*)d_in[16];
  const float* lnfg   = (const float*)d_in[17];
  const float* lnfb   = (const float*)d_in[18];
  const float* Wp     = (const float*)d_in[19];
  const float* bp     = (const float*)d_in[20];

  float* out = (float*)d_out;
  char* base = (char*)d_ws;
  float*          x       = (float*)(base + 0);                 //  8,388,608
  unsigned short* xn      = (unsigned short*)(base + 8388608);  //  4,194,304
  float*          rowloss = (float*)(base + 12582912);          //     16,384
  unsigned short* WqkvT   = (unsigned short*)(base + 12599296); //  6,291,456
  unsigned short* W1T     = (unsigned short*)(base + 18890752); //  8,388,608
  unsigned short* W2T     = (unsigned short*)(base + 27279360); //  8,388,608
  unsigned short* WoT     = (unsigned short*)(base + 35667968); //  2,097,152
  unsigned short* qkvh    = (unsigned short*)(base + 37765120); // 12,582,912
  unsigned short* ob      = (unsigned short*)(base + 50348032); //  4,194,304
  unsigned short* h1      = (unsigned short*)(base + 54542336); // 16,777,216
  float*          Opart   = (float*)(base + 54542336);          //  8,388,608 (alias h1: dead during attn)
  float2*         mlbuf   = (float2*)(base + 62930944);         //    262,144 (alias h1 upper half)
  unsigned short* WpT     = (unsigned short*)(base + 37765120); // 32,768,000 (alias: dead at logits time)
  float2*         msbuf   = (float2*)(base + 12599296);         // 16,384,000 (alias: weight-T region, dead at logits time)

  embed_kernel<<<BT_ * D_ / 4 / 256, 256, 0, stream>>>(ids, tok, pos, x);

  qkvw_transpose<<<dim3(16, 2, 96), 256, 0, stream>>>(Wq, Wk, Wv, WqkvT);
  transpose_cast<<<dim3(16, 64, 4), 256, 0, stream>>>(W1, W1T, 2048, 512, 1048576, 1048576);
  transpose_cast<<<dim3(64, 16, 4), 256, 0, stream>>>(W2, W2T, 512, 2048, 1048576, 1048576);
  transpose_cast<<<dim3(16, 16, 4), 256, 0, stream>>>(Wo, WoT, 512, 512, 262144, 262144);

  for (int l = 0; l < NL_; l++) {
    ln_kernel<<<BT_ / 4, 256, 0, stream>>>(x, ln1g + l * D_, ln1b + l * D_, xn);
    gemm_pipe<64,64,2,2><<<dim3(64, 24), 256, 0, stream>>>(
        xn, WqkvT + (size_t)l * 1536 * 512, 512, nullptr, nullptr, nullptr, qkvh, 1536, 0);
    attn_mfma<<<dim3(24, B_ * H_), 512, 0, stream>>>(qkvh, ob, Opart, mlbuf);
    attn_merge<<<128, 256, 0, stream>>>(Opart, mlbuf, ob);
    gemm_pipe<64,64,2,2><<<dim3(64, 8), 256, 0, stream>>>(
        ob, WoT + (size_t)l * 512 * 512, 512, bo + l * D_, x, x, nullptr, D_, 0);
    ln_kernel<<<BT_ / 4, 256, 0, stream>>>(x, ln2g + l * D_, ln2b + l * D_, xn);
    gemm_pipe<64,64,2,2><<<dim3(64, 32), 256, 0, stream>>>(
        xn, W1T + (size_t)l * 2048 * 512, 512, b1 + l * 4 * D_, nullptr, nullptr, h1, 4 * D_, 1);
    gemm_pipe<64,64,2,2><<<dim3(64, 8), 256, 0, stream>>>(
        h1, W2T + (size_t)l * 512 * 2048, 2048, b2 + l * D_, x, x, nullptr, D_, 0);
  }

  transpose_cast<<<dim3(16, 1000, 1), 256, 0, stream>>>(Wp, WpT, 32000, 512, 0, 0);
  ln_kernel<<<BT_ / 4, 256, 0, stream>>>(x, lnfg, lnfb, xn);
  gemm_logits<<<dim3(32, 125), 512, 0, stream>>>(
      xn, WpT, 512, bp, out, V_, msbuf, 500);

  loss_merge_kernel<<<BT_ / 4, 256, 0, stream>>>(msbuf, out, labels, rowloss, 500);
  loss_final_kernel<<<1, 256, 0, stream>>>(rowloss, out + (size_t)BT_ * V_);
}

// Round 18
// 887.445 us; speedup vs baseline: 1.0376x; 1.0376x over previous
//
#include <hip/hip_runtime.h>
#include <hip/hip_bf16.h>
#include <math.h>

#define B_ 2
#define T_ 2048
#define D_ 512
#define H_ 8
#define NL_ 4
#define V_ 32000
#define HD_ 64
#define BT_ (B_*T_)
#define EPS_ 1e-5f
#define SCALE_ 0.04419417382415922f  /* 1/sqrt(512) — source scales by D, not HD */
#define NEGBIG -1e30f

typedef __bf16 bf16x8 __attribute__((ext_vector_type(8)));
typedef float  f32x4  __attribute__((ext_vector_type(4)));

__device__ __forceinline__ unsigned short f2bf(float f) {
  union { float f; unsigned u; } v; v.f = f;
  unsigned r = v.u + 0x7fff + ((v.u >> 16) & 1);
  return (unsigned short)(r >> 16);
}

__device__ __forceinline__ void gl_lds16(const void* g, void* l) {
  __builtin_amdgcn_global_load_lds(
      (const __attribute__((address_space(1))) void*)g,
      (__attribute__((address_space(3))) void*)l, 16, 0, 0);
}

#define WAITVM(n) asm volatile("s_waitcnt vmcnt(" #n ")" ::: "memory")
#define WAITLG0   asm volatile("s_waitcnt lgkmcnt(0)" ::: "memory")

// ---------------------------------------------------------------- embed
__global__ __launch_bounds__(256) void embed_kernel(
    const int* __restrict__ ids, const float* __restrict__ tok,
    const float* __restrict__ pos, float* __restrict__ x)
{
  int i = blockIdx.x * 256 + threadIdx.x;
  int d4 = i & (D_/4 - 1);
  int bt = i >> 7;
  int t  = bt & (T_ - 1);
  const float4 a = reinterpret_cast<const float4*>(tok + (size_t)ids[bt] * D_)[d4];
  const float4 p = reinterpret_cast<const float4*>(pos + (size_t)t * D_)[d4];
  float4 r; r.x = a.x + p.x; r.y = a.y + p.y; r.z = a.z + p.z; r.w = a.w + p.w;
  reinterpret_cast<float4*>(x)[i] = r;
}

// ---------------------------------------------------------------- layernorm -> bf16 out
__global__ __launch_bounds__(256) void ln_kernel(
    const float* __restrict__ x, const float* __restrict__ g,
    const float* __restrict__ b, unsigned short* __restrict__ out)
{
  int row  = blockIdx.x * 4 + (threadIdx.x >> 6);
  int lane = threadIdx.x & 63;
  const float4* xr = reinterpret_cast<const float4*>(x + (size_t)row * D_);
  float4 v0 = xr[lane], v1 = xr[lane + 64];
  float s = v0.x + v0.y + v0.z + v0.w + v1.x + v1.y + v1.z + v1.w;
  float q = v0.x*v0.x + v0.y*v0.y + v0.z*v0.z + v0.w*v0.w
          + v1.x*v1.x + v1.y*v1.y + v1.z*v1.z + v1.w*v1.w;
  #pragma unroll
  for (int off = 1; off < 64; off <<= 1) {
    s += __shfl_xor(s, off);
    q += __shfl_xor(q, off);
  }
  float mean = s * (1.0f / D_);
  float var  = q * (1.0f / D_) - mean * mean;
  float rs   = rsqrtf(var + EPS_);
  const float4* g4 = reinterpret_cast<const float4*>(g);
  const float4* b4 = reinterpret_cast<const float4*>(b);
  float4 gv0 = g4[lane], gv1 = g4[lane + 64];
  float4 bv0 = b4[lane], bv1 = b4[lane + 64];
  ushort4 p0, p1;
  p0.x = f2bf((v0.x - mean) * rs * gv0.x + bv0.x);
  p0.y = f2bf((v0.y - mean) * rs * gv0.y + bv0.y);
  p0.z = f2bf((v0.z - mean) * rs * gv0.z + bv0.z);
  p0.w = f2bf((v0.w - mean) * rs * gv0.w + bv0.w);
  p1.x = f2bf((v1.x - mean) * rs * gv1.x + bv1.x);
  p1.y = f2bf((v1.y - mean) * rs * gv1.y + bv1.y);
  p1.z = f2bf((v1.z - mean) * rs * gv1.z + bv1.z);
  p1.w = f2bf((v1.w - mean) * rs * gv1.w + bv1.w);
  unsigned short* orow = out + (size_t)row * D_;
  *reinterpret_cast<ushort4*>(orow + lane * 4)       = p0;
  *reinterpret_cast<ushort4*>(orow + 256 + lane * 4) = p1;
}

// ---------------------------------------------------------------- transpose+cast fp32 [R][C] -> bf16 [C][R]
__global__ __launch_bounds__(256) void transpose_cast(
    const float* __restrict__ src, unsigned short* __restrict__ dst,
    int C, int R, long sstride, long dstride)
{
  src += (size_t)blockIdx.z * sstride;
  dst += (size_t)blockIdx.z * dstride;
  __shared__ float t[32][33];
  int r0 = blockIdx.x * 32, c0 = blockIdx.y * 32;
  int tx = threadIdx.x & 31, ty = threadIdx.x >> 5;
  #pragma unroll
  for (int i = 0; i < 4; i++)
    t[ty + i*8][tx] = src[(size_t)(r0 + ty + i*8) * C + c0 + tx];
  __syncthreads();
  #pragma unroll
  for (int i = 0; i < 4; i++)
    dst[(size_t)(c0 + ty + i*8) * R + r0 + tx] = f2bf(t[tx][ty + i*8]);
}

// WqkvT[l][mat*512 + h*64 + e][d] = W{q,k,v}[l][h][d][e]
__global__ __launch_bounds__(256) void qkvw_transpose(
    const float* __restrict__ Wq, const float* __restrict__ Wk,
    const float* __restrict__ Wv, unsigned short* __restrict__ dst)
{
  int z = blockIdx.z; int l = z / 24; int rem = z % 24; int mat = rem >> 3; int h = rem & 7;
  const float* W = (mat == 0 ? Wq : (mat == 1 ? Wk : Wv)) + ((size_t)(l * 8 + h)) * D_ * HD_;
  unsigned short* d = dst + ((size_t)l * 1536 + mat * 512 + h * 64) * D_;
  __shared__ float t[32][33];
  int d0 = blockIdx.x * 32, e0 = blockIdx.y * 32;
  int tx = threadIdx.x & 31, ty = threadIdx.x >> 5;
  #pragma unroll
  for (int i = 0; i < 4; i++)
    t[ty + i*8][tx] = W[(size_t)(d0 + ty + i*8) * HD_ + e0 + tx];
  __syncthreads();
  #pragma unroll
  for (int i = 0; i < 4; i++)
    d[(size_t)(e0 + ty + i*8) * D_ + d0 + tx] = f2bf(t[tx][ty + i*8]);
}

// ---------------------------------------------------------------- logits GEMM: 128x256 tile
__global__ __launch_bounds__(512, 4) void gemm_logits(
    const unsigned short* __restrict__ A,
    const unsigned short* __restrict__ Bt,
    int K, const float* __restrict__ bias,
    float* __restrict__ outF, int ldc,
    float2* __restrict__ ms, int npan)
{
  __shared__ __align__(16) char smem[73728];
  unsigned short* Abase = (unsigned short*)smem;
  unsigned short* Bbase = (unsigned short*)(smem + 24576);
  float* E = (float*)smem;

  const int tid = threadIdx.x;
  const int lane = tid & 63;
  const int lr = lane & 15, g = lane >> 4;
  const int wv = tid >> 6, wm = wv >> 2, wn = wv & 3;

  const int gx = gridDim.x;
  int id = blockIdx.y * gx + blockIdx.x;
  const int nwg = gx * gridDim.y;
  if ((nwg & 7) == 0) { const int q = nwg >> 3; id = (id & 7) * q + (id >> 3); }
  const int bm = (id % gx) * 128, bn = (id / gx) * 256, bnp = id / gx;

  const int schk = (lane & 3) ^ ((lane >> 3) & 3);
  const unsigned short* Ab = A  + (size_t)(bm + wv*16 + (lane >> 2)) * K + schk * 8;
  const unsigned short* Bb = Bt + (size_t)(bn + wv*16 + (lane >> 2)) * K + schk * 8;

#define STAGEL(s, sl)                                                       \
  { const int kof_ = (s) * 32;                                              \
    gl_lds16(Ab + kof_,                 Abase + (sl)*4096 + wv*512);        \
    gl_lds16(Bb + kof_,                 Bbase + (sl)*8192 + wv*512);        \
    gl_lds16(Bb + (size_t)128*K + kof_, Bbase + (sl)*8192 + 4096 + wv*512); }

  f32x4 acc[4][4];
  #pragma unroll
  for (int m = 0; m < 4; m++)
    #pragma unroll
    for (int n = 0; n < 4; n++)
      acc[m][n] = (f32x4){0.f, 0.f, 0.f, 0.f};

  const int nt = K >> 5;
  STAGEL(0, 0); STAGEL(1, 1);

  const int slotx = (g ^ ((lr >> 1) & 3)) << 3;

  for (int t = 0; t < nt; ++t) {
    const int s = t + 2;
    const int st = t % 3;
    __builtin_amdgcn_sched_barrier(0);
    if      (s < nt)  { const int ss = s % 3; STAGEL(s, ss); WAITVM(6); }
    else if (s == nt) { WAITVM(3); }
    else              { WAITVM(0); }
    __builtin_amdgcn_sched_barrier(0);
    __builtin_amdgcn_s_barrier();
    __builtin_amdgcn_sched_barrier(0);

    const unsigned short* Ac = Abase + st*4096;
    const unsigned short* Bc = Bbase + st*8192;
    bf16x8 af[4], bfr[4];
    #pragma unroll
    for (int m = 0; m < 4; m++)
      af[m] = *reinterpret_cast<const bf16x8*>(&Ac[(wm*64 + m*16 + lr) * 32 + slotx]);
    #pragma unroll
    for (int n = 0; n < 4; n++)
      bfr[n] = *reinterpret_cast<const bf16x8*>(&Bc[(wn*64 + n*16 + lr) * 32 + slotx]);
    __builtin_amdgcn_s_setprio(1);
    #pragma unroll
    for (int m = 0; m < 4; m++)
      #pragma unroll
      for (int n = 0; n < 4; n++)
        acc[m][n] = __builtin_amdgcn_mfma_f32_16x16x32_bf16(af[m], bfr[n], acc[m][n], 0, 0, 0);
    __builtin_amdgcn_s_setprio(0);
    __builtin_amdgcn_sched_barrier(0);
    __builtin_amdgcn_s_barrier();
  }
#undef STAGEL

  #pragma unroll
  for (int n = 0; n < 4; n++) {
    const float bv = bias ? bias[bn + wn*64 + n*16 + lr] : 0.f;
    #pragma unroll
    for (int m = 0; m < 4; m++)
      #pragma unroll
      for (int r = 0; r < 4; r++)
        acc[m][n][r] += bv;
  }

  if (ms) {
    #pragma unroll
    for (int m = 0; m < 4; m++) {
      float vmax[4] = {NEGBIG, NEGBIG, NEGBIG, NEGBIG};
      #pragma unroll
      for (int n = 0; n < 4; n++)
        #pragma unroll
        for (int r = 0; r < 4; r++)
          vmax[r] = fmaxf(vmax[r], acc[m][n][r]);
      #pragma unroll
      for (int r = 0; r < 4; r++) {
        #pragma unroll
        for (int off = 1; off < 16; off <<= 1)
          vmax[r] = fmaxf(vmax[r], __shfl_xor(vmax[r], off));
      }
      float vsum[4] = {0.f, 0.f, 0.f, 0.f};
      #pragma unroll
      for (int n = 0; n < 4; n++)
        #pragma unroll
        for (int r = 0; r < 4; r++)
          vsum[r] += __expf(acc[m][n][r] - vmax[r]);
      #pragma unroll
      for (int r = 0; r < 4; r++) {
        #pragma unroll
        for (int off = 1; off < 16; off <<= 1)
          vsum[r] += __shfl_xor(vsum[r], off);
      }
      if (lr == 0) {
        #pragma unroll
        for (int r = 0; r < 4; r++)
          ms[(size_t)(bm + wm*64 + m*16 + g*4 + r) * npan + bnp*4 + wn] =
              make_float2(vmax[r], vsum[r]);
      }
    }
  }

  #pragma unroll
  for (int c = 0; c < 2; ++c) {
    __syncthreads();
    if (wm == c) {
      #pragma unroll
      for (int m = 0; m < 4; m++)
        #pragma unroll
        for (int n = 0; n < 4; n++)
          #pragma unroll
          for (int r = 0; r < 4; r++)
            E[(m*16 + g*4 + r) * 260 + wn*64 + n*16 + lr] = acc[m][n][r];
    }
    __syncthreads();
    #pragma unroll
    for (int rep = 0; rep < 8; rep++) {
      const int row = rep*8 + wv;
      f32x4 v = *reinterpret_cast<const f32x4*>(&E[row*260 + lane*4]);
      __builtin_nontemporal_store(
          v, reinterpret_cast<f32x4*>(&outF[(size_t)(bm + c*64 + row) * ldc + bn + lane*4]));
    }
  }
}

// ---------------------------------------------------------------- pipelined bf16 MFMA GEMM
// BMxBN tile, BK=64 per sync (8 MFMAs per barrier pair), 2 LDS buffers,
// depth-1 counted vmcnt, XOR chunk swizzle (chunk ^= row&7, both sides).
template<int BM_T, int BN_T, int WM, int WN>
__global__ __launch_bounds__(256) void gemm_pipe(
    const unsigned short* __restrict__ A,
    const unsigned short* __restrict__ Bt,
    int K,
    const float* __restrict__ bias,
    const float* __restrict__ resid,
    float* __restrict__ outF,
    unsigned short* __restrict__ outH,
    int ldc, int relu)
{
  constexpr int BKp = 64;
  constexpr int ALOADS = BM_T / 32;
  constexpr int BLOADS = BN_T / 32;
  constexpr int LOADS  = ALOADS + BLOADS;
  constexpr int MR = BM_T / (16 * WM);
  constexpr int NR = BN_T / (16 * WN);
  __shared__ __align__(16) unsigned short As[2][BM_T * BKp];
  __shared__ __align__(16) unsigned short Bs[2][BN_T * BKp];

  const int tid = threadIdx.x;
  const int lane = tid & 63, wv = tid >> 6;
  const int lr = lane & 15, g = lane >> 4;

  const int gx = gridDim.x;
  int id = blockIdx.y * gx + blockIdx.x;
  const int nwg = gx * gridDim.y;
  if ((nwg & 7) == 0) {
    const int q = nwg >> 3;
    id = (id & 7) * q + (id >> 3);
  }
  const int bm = (id % gx) * BM_T, bn = (id / gx) * BN_T;

  const int m0w = (wv / WN) * (BM_T / WM);
  const int n0w = (wv % WN) * (BN_T / WN);

  const int srow = wv*8 + (lane >> 3);
  const int schk = (lane & 7) ^ (lane >> 3);
  const unsigned short* Ab = A  + (size_t)(bm + srow) * K + schk * 8;
  const unsigned short* Bb = Bt + (size_t)(bn + srow) * K + schk * 8;

#define STAGEP(s, sl)                                                           \
  { const int kof_ = (s) * BKp;                                                 \
    _Pragma("unroll")                                                           \
    for (int i_ = 0; i_ < ALOADS; ++i_)                                         \
      gl_lds16(Ab + (size_t)(i_*32)*K + kof_, As[sl] + i_*2048 + wv*512);       \
    _Pragma("unroll")                                                           \
    for (int i_ = 0; i_ < BLOADS; ++i_)                                         \
      gl_lds16(Bb + (size_t)(i_*32)*K + kof_, Bs[sl] + i_*2048 + wv*512); }

  f32x4 acc[MR][NR];
  #pragma unroll
  for (int m = 0; m < MR; m++)
    #pragma unroll
    for (int n = 0; n < NR; n++)
      acc[m][n] = (f32x4){0.f, 0.f, 0.f, 0.f};

  const int nt = K >> 6;
  STAGEP(0, 0);

  for (int t = 0; t < nt; ++t) {
    __builtin_amdgcn_sched_barrier(0);
    if (t + 1 < nt) {
      STAGEP(t + 1, (t + 1) & 1);
      if constexpr (LOADS == 4) WAITVM(4);
      else if constexpr (LOADS == 6) WAITVM(6);
      else WAITVM(8);
    } else {
      WAITVM(0);
    }
    __builtin_amdgcn_sched_barrier(0);
    __builtin_amdgcn_s_barrier();          // tile t visible to all waves
    __builtin_amdgcn_sched_barrier(0);

    const unsigned short* Ac = As[t & 1];
    const unsigned short* Bc = Bs[t & 1];
    #pragma unroll
    for (int kk = 0; kk < 2; ++kk) {
      const int sl = ((kk*4 + g) ^ (lr & 7)) << 3;
      bf16x8 af[MR], bfr[NR];
      #pragma unroll
      for (int m = 0; m < MR; m++)
        af[m] = *reinterpret_cast<const bf16x8*>(&Ac[(m0w + m*16 + lr) * BKp + sl]);
      #pragma unroll
      for (int n = 0; n < NR; n++)
        bfr[n] = *reinterpret_cast<const bf16x8*>(&Bc[(n0w + n*16 + lr) * BKp + sl]);
      __builtin_amdgcn_s_setprio(1);
      #pragma unroll
      for (int m = 0; m < MR; m++)
        #pragma unroll
        for (int n = 0; n < NR; n++)
          acc[m][n] = __builtin_amdgcn_mfma_f32_16x16x32_bf16(af[m], bfr[n], acc[m][n], 0, 0, 0);
      __builtin_amdgcn_s_setprio(0);
    }
    __builtin_amdgcn_sched_barrier(0);
    __builtin_amdgcn_s_barrier();          // all waves done reading buf[t&1]
  }
#undef STAGEP

  const int cr = g * 4;
  const int cc = lr;
  #pragma unroll
  for (int m = 0; m < MR; m++) {
    #pragma unroll
    for (int n = 0; n < NR; n++) {
      int row = bm + m0w + m*16 + cr;
      int col = bn + n0w + n*16 + cc;
      f32x4 a = acc[m][n];
      #pragma unroll
      for (int r = 0; r < 4; r++) {
        float v = a[r];
        if (bias)  v += bias[col];
        if (resid) v += resid[(size_t)(row + r) * ldc + col];
        if (relu)  v = fmaxf(v, 0.f);
        if (outF)  outF[(size_t)(row + r) * ldc + col] = v;
        if (outH)  outH[(size_t)(row + r) * ldc + col] = f2bf(v);
      }
    }
  }
}

// ---------------------------------------------------------------- MFMA flash attention (bf16 in/out)
// 128 q-rows per block, 8 waves. Work-split scheduling: tasks qb<8 run whole;
// qb>=8 split KV range into 2 halves (flash-decoding), merged by attn_merge.
__global__ __launch_bounds__(512) void attn_mfma(
    const unsigned short* __restrict__ qkv,  // bf16 [B*T][1536]
    unsigned short* __restrict__ o,          // bf16 [B*T][512]
    float* __restrict__ Opart,               // [128 blk][2][128][64] fp32
    float2* __restrict__ ml)                 // [128 blk][2][128]
{
  __shared__ __align__(16) unsigned short Ks[2][64*64];
  __shared__ __align__(16) unsigned short Vt[2][64*64];
  __shared__ __align__(16) unsigned short Ps[8][16*64];

  static const unsigned char ord[24] = {7,22,23,20,21,6,18,19,16,17,5,14,15,12,13,4,10,11,8,9,3,2,1,0};
  const int slot = ord[blockIdx.x];
  const int bh = blockIdx.y, bb = bh >> 3, hh = bh & 7;
  int qb, it0, itn, half;
  if (slot < 8) { qb = slot; it0 = 0; itn = 2*qb + 2; half = -1; }
  else { const int p = slot - 8; qb = 8 + (p >> 1); half = p & 1;
         const int nh = qb + 1; it0 = half * nh; itn = nh; }

  const int tid = threadIdx.x, lane = tid & 63, wv = tid >> 6;
  const int lr = lane & 15, g = lane >> 4;

  const unsigned short* qp = qkv + ((size_t)(bb*T_ + qb*128))*1536 + hh*64;
  const unsigned short* kp = qkv + ((size_t)bb*T_)*1536 + 512  + hh*64;
  const unsigned short* vp = qkv + ((size_t)bb*T_)*1536 + 1024 + hh*64;

  bf16x8 qf[2];
  qf[0] = *reinterpret_cast<const bf16x8*>(qp + (size_t)(wv*16 + lr)*1536 + g*8);
  qf[1] = *reinterpret_cast<const bf16x8*>(qp + (size_t)(wv*16 + lr)*1536 + 32 + g*8);

  const int krow = wv*8 + (lane >> 3);
  const int khb  = (lane & 7) ^ (lane >> 3);

#define STAGE_K(s0_, buf_)                                           \
  gl_lds16(kp + (size_t)((s0_)*64 + krow)*1536 + khb*8,              \
           (void*)(Ks[buf_] + wv*512));

  uint4 uvr;
#define LOAD_V(s0_)                                                  \
  uvr = *reinterpret_cast<const uint4*>(                             \
      vp + (size_t)((s0_)*64 + lane)*1536 + wv*8);

  f32x4 ov[4];
  #pragma unroll
  for (int n = 0; n < 4; n++) ov[n] = (f32x4){0.f, 0.f, 0.f, 0.f};
  float mrow[4] = {NEGBIG, NEGBIG, NEGBIG, NEGBIG};
  float lrow[4] = {0.f, 0.f, 0.f, 0.f};

  STAGE_K(it0, 0);
  LOAD_V(it0);

  for (int ii = 0; ii < itn; ++ii) {
    const int s0 = it0 + ii;
    const int cur = ii & 1;
    WAITVM(0);                         // K(cur) in LDS, V(cur) in regs
    __builtin_amdgcn_sched_barrier(0);
    {                                  // write V(cur) regs -> Vt[cur] (swizzled)
      union { uint4 v; unsigned short e[8]; } uv; uv.v = uvr;
      #pragma unroll
      for (int j = 0; j < 8; j++)
        Vt[cur][(wv*8 + j)*64 + (((lane >> 3) ^ j) << 3) + (lane & 7)] = uv.e[j];
    }
    WAITLG0;
    __builtin_amdgcn_sched_barrier(0);
    __builtin_amdgcn_s_barrier();      // K/V tile cur visible to all waves
    __builtin_amdgcn_sched_barrier(0);

    if (ii + 1 < itn) {                // async prefetch of next tile
      STAGE_K(s0 + 1, cur ^ 1);
      LOAD_V(s0 + 1);
    }

    // --- S = Q @ K^T
    f32x4 sf[4];
    #pragma unroll
    for (int n = 0; n < 4; n++) sf[n] = (f32x4){0.f, 0.f, 0.f, 0.f};
    __builtin_amdgcn_s_setprio(1);
    #pragma unroll
    for (int kk = 0; kk < 2; kk++) {
      #pragma unroll
      for (int n = 0; n < 4; n++) {
        const bf16x8 kf = *reinterpret_cast<const bf16x8*>(
            &Ks[cur][(n*16 + lr)*64 + (((kk*4 + g) ^ (lr & 7)) << 3)]);
        sf[n] = __builtin_amdgcn_mfma_f32_16x16x32_bf16(qf[kk], kf, sf[n], 0, 0, 0);
      }
    }
    __builtin_amdgcn_s_setprio(0);

    // --- scale + causal mask
    float sv[4][4];
    #pragma unroll
    for (int n = 0; n < 4; n++)
      #pragma unroll
      for (int r = 0; r < 4; r++) {
        const int kvg = s0*64 + n*16 + lr;
        const int qg  = qb*128 + wv*16 + g*4 + r;
        sv[n][r] = (kvg > qg) ? NEGBIG : sf[n][r] * SCALE_;
      }

    float aa[4];
    #pragma unroll
    for (int r = 0; r < 4; r++) {
      float pm = fmaxf(fmaxf(sv[0][r], sv[1][r]), fmaxf(sv[2][r], sv[3][r]));
      pm = fmaxf(pm, __shfl_xor(pm, 1));
      pm = fmaxf(pm, __shfl_xor(pm, 2));
      pm = fmaxf(pm, __shfl_xor(pm, 4));
      pm = fmaxf(pm, __shfl_xor(pm, 8));
      float mn = fmaxf(mrow[r], pm);
      aa[r] = __expf(mrow[r] - mn);
      mrow[r] = mn;
    }
    float rs[4] = {0.f, 0.f, 0.f, 0.f};
    #pragma unroll
    for (int n = 0; n < 4; n++)
      #pragma unroll
      for (int r = 0; r < 4; r++) {
        float p = __expf(sv[n][r] - mrow[r]);
        rs[r] += p;
        Ps[wv][(g*4 + r)*64 + ((((n << 1) + (lr >> 3)) ^ ((g*4 + r) & 7)) << 3) + (lr & 7)] = f2bf(p);
      }
    #pragma unroll
    for (int r = 0; r < 4; r++) {
      float s = rs[r];
      s += __shfl_xor(s, 1); s += __shfl_xor(s, 2);
      s += __shfl_xor(s, 4); s += __shfl_xor(s, 8);
      lrow[r] = lrow[r]*aa[r] + s;
    }
    #pragma unroll
    for (int n = 0; n < 4; n++)
      #pragma unroll
      for (int r = 0; r < 4; r++)
        ov[n][r] *= aa[r];

    // --- O += P @ V
    __builtin_amdgcn_s_setprio(1);
    #pragma unroll
    for (int kk = 0; kk < 2; kk++) {
      const bf16x8 pf = *reinterpret_cast<const bf16x8*>(
          &Ps[wv][lr*64 + (((kk*4 + g) ^ (lr & 7)) << 3)]);
      #pragma unroll
      for (int n = 0; n < 4; n++) {
        const bf16x8 vf = *reinterpret_cast<const bf16x8*>(
            &Vt[cur][(n*16 + lr)*64 + (((kk*4 + g) ^ (lr & 7)) << 3)]);
        ov[n] = __builtin_amdgcn_mfma_f32_16x16x32_bf16(pf, vf, ov[n], 0, 0, 0);
      }
    }
    __builtin_amdgcn_s_setprio(0);
    __builtin_amdgcn_sched_barrier(0);
    __builtin_amdgcn_s_barrier();      // all waves done reading tile cur
  }
#undef STAGE_K
#undef LOAD_V

  if (half < 0) {
    #pragma unroll
    for (int r = 0; r < 4; r++) {
      float inv = 1.0f / lrow[r];
      size_t row = (size_t)(bb*T_ + qb*128 + wv*16 + g*4 + r);
      #pragma unroll
      for (int n = 0; n < 4; n++)
        o[row*D_ + hh*64 + n*16 + lr] = f2bf(ov[n][r] * inv);
    }
  } else {
    const int blk = bh*8 + (qb - 8);
    float* Od = Opart + ((size_t)blk*2 + half)*128*64;
    #pragma unroll
    for (int r = 0; r < 4; r++) {
      const int rloc = wv*16 + g*4 + r;
      #pragma unroll
      for (int n = 0; n < 4; n++)
        Od[rloc*64 + n*16 + lr] = ov[n][r];
      if (lr == 0)
        ml[((size_t)blk*2 + half)*128 + rloc] = make_float2(mrow[r], lrow[r]);
    }
  }
}

// ---------------------------------------------------------------- attention split-merge
__global__ __launch_bounds__(256) void attn_merge(
    const float* __restrict__ Opart, const float2* __restrict__ ml,
    unsigned short* __restrict__ o)
{
  const int blk = blockIdx.x;              // bh*8 + (qb-8)
  const int bh = blk >> 3, qb = (blk & 7) + 8;
  const int bb = bh >> 3, hh = bh & 7;
  const int tid = threadIdx.x;
  const int row = tid >> 1, ch = (tid & 1) * 32;
  const float* O0 = Opart + ((size_t)blk*2 + 0)*128*64;
  const float* O1 = Opart + ((size_t)blk*2 + 1)*128*64;
  const float2 a = ml[(size_t)blk*2*128 + row];
  const float2 b = ml[((size_t)blk*2 + 1)*128 + row];
  const float M  = fmaxf(a.x, b.x);
  const float e0 = __expf(a.x - M), e1 = __expf(b.x - M);
  const float inv = 1.0f / (a.y*e0 + b.y*e1);
  unsigned short* orow = o + ((size_t)(bb*T_ + qb*128 + row))*D_ + hh*64 + ch;
  #pragma unroll
  for (int c = 0; c < 32; c += 4) {
    f32x4 v0 = *reinterpret_cast<const f32x4*>(&O0[row*64 + ch + c]);
    f32x4 v1 = *reinterpret_cast<const f32x4*>(&O1[row*64 + ch + c]);
    ushort4 pk;
    pk.x = f2bf((v0[0]*e0 + v1[0]*e1) * inv);
    pk.y = f2bf((v0[1]*e0 + v1[1]*e1) * inv);
    pk.z = f2bf((v0[2]*e0 + v1[2]*e1) * inv);
    pk.w = f2bf((v0[3]*e0 + v1[3]*e1) * inv);
    *reinterpret_cast<ushort4*>(&orow[c]) = pk;
  }
}

// ---------------------------------------------------------------- loss: merge per-panel partials
__global__ __launch_bounds__(256) void loss_merge_kernel(
    const float2* __restrict__ ms, const float* __restrict__ logits,
    const int* __restrict__ labels, float* __restrict__ rowloss, int npan)
{
  const int tid = threadIdx.x, lane = tid & 63, wid = tid >> 6;
  const int row = blockIdx.x * 4 + wid;
  float M = NEGBIG, S = 0.f;
  const float2* p = ms + (size_t)row * npan;
  for (int i = lane; i < npan; i += 64) {
    float2 e = p[i];
    float Mn = fmaxf(M, e.x);
    S = S * __expf(M - Mn) + e.y * __expf(e.x - Mn);
    M = Mn;
  }
  #pragma unroll
  for (int off = 1; off < 64; off <<= 1) {
    float Mo = __shfl_xor(M, off), So = __shfl_xor(S, off);
    float Mn = fmaxf(M, Mo);
    S = S * __expf(M - Mn) + So * __expf(Mo - Mn);
    M = Mn;
  }
  if (lane == 0)
    rowloss[row] = logits[(size_t)row * V_ + labels[row]] - M - logf(S);
}

__global__ __launch_bounds__(256) void loss_final_kernel(
    const float* __restrict__ rowloss, float* __restrict__ out)
{
  __shared__ float red[4];
  const int tid = threadIdx.x, lane = tid & 63, wid = tid >> 6;
  float s = 0.f;
  for (int i = tid; i < BT_; i += 256) s += rowloss[i];
  #pragma unroll
  for (int off = 1; off < 64; off <<= 1) s += __shfl_xor(s, off);
  if (lane == 0) red[wid] = s;
  __syncthreads();
  if (tid == 0) out[0] = -(red[0] + red[1] + red[2] + red[3]) * (1.0f / BT_);
}

// ---------------------------------------------------------------- launch
extern "C" void kernel_launch(void* const* d_in, const int* in_sizes, int n_in,
                              void* d_out, int out_size, void* d_ws, size_t ws_size,
                              hipStream_t stream)
{
  (void)in_sizes; (void)n_in; (void)out_size; (void)ws_size;
  const int*   ids    = (const int*)d_in[0];
  const int*   labels = (const int*)d_in[1];
  const float* tok    = (const float*)d_in[2];
  const float* pos    = (const float*)d_in[3];
  const float* Wq     = (const float*)d_in[4];
  const float* Wk     = (const float*)d_in[5];
  const float* Wv     = (const float*)d_in[6];
  const float* Wo     = (const float*)d_in[7];
  const float* bo     = (const float*)d_in[8];
  const float* ln1g   = (const float*)d_in[9];
  const float* ln1b   = (const float*)d_in[10];
  const float* ln2g   = (const float*)d_in[11];
  const float* ln2b   = (const float*)d_in[12];
  const float* W1     = (const float*)d_in[13];
  const float* b1     = (const float*)d_in[14];
  const float* W2     = (const float*)d_in[15];
  const float* b2     = (const float*)d_in[16];
  const float* lnfg   = (const float*)d_in[17];
  const float* lnfb   = (const float*)d_in[18];
  const float* Wp     = (const float*)d_in[19];
  const float* bp     = (const float*)d_in[20];

  float* out = (float*)d_out;
  char* base = (char*)d_ws;
  float*          x       = (float*)(base + 0);                 //  8,388,608
  unsigned short* xn      = (unsigned short*)(base + 8388608);  //  4,194,304
  float*          rowloss = (float*)(base + 12582912);          //     16,384
  unsigned short* WqkvT   = (unsigned short*)(base + 12599296); //  6,291,456
  unsigned short* W1T     = (unsigned short*)(base + 18890752); //  8,388,608
  unsigned short* W2T     = (unsigned short*)(base + 27279360); //  8,388,608
  unsigned short* WoT     = (unsigned short*)(base + 35667968); //  2,097,152
  unsigned short* qkvh    = (unsigned short*)(base + 37765120); // 12,582,912
  unsigned short* ob      = (unsigned short*)(base + 50348032); //  4,194,304
  unsigned short* h1      = (unsigned short*)(base + 54542336); // 16,777,216
  float*          Opart   = (float*)(base + 54542336);          //  8,388,608 (alias h1: dead during attn)
  float2*         mlbuf   = (float2*)(base + 62930944);         //    262,144 (alias h1 upper half)
  unsigned short* WpT     = (unsigned short*)(base + 37765120); // 32,768,000 (alias: dead at logits time)
  float2*         msbuf   = (float2*)(base + 12599296);         // 16,384,000 (alias: weight-T region, dead at logits time)

  embed_kernel<<<BT_ * D_ / 4 / 256, 256, 0, stream>>>(ids, tok, pos, x);

  qkvw_transpose<<<dim3(16, 2, 96), 256, 0, stream>>>(Wq, Wk, Wv, WqkvT);
  transpose_cast<<<dim3(16, 64, 4), 256, 0, stream>>>(W1, W1T, 2048, 512, 1048576, 1048576);
  transpose_cast<<<dim3(64, 16, 4), 256, 0, stream>>>(W2, W2T, 512, 2048, 1048576, 1048576);
  transpose_cast<<<dim3(16, 16, 4), 256, 0, stream>>>(Wo, WoT, 512, 512, 262144, 262144);

  for (int l = 0; l < NL_; l++) {
    ln_kernel<<<BT_ / 4, 256, 0, stream>>>(x, ln1g + l * D_, ln1b + l * D_, xn);
    gemm_pipe<64,64,2,2><<<dim3(64, 24), 256, 0, stream>>>(
        xn, WqkvT + (size_t)l * 1536 * 512, 512, nullptr, nullptr, nullptr, qkvh, 1536, 0);
    attn_mfma<<<dim3(24, B_ * H_), 512, 0, stream>>>(qkvh, ob, Opart, mlbuf);
    attn_merge<<<128, 256, 0, stream>>>(Opart, mlbuf, ob);
    gemm_pipe<64,64,2,2><<<dim3(64, 8), 256, 0, stream>>>(
        ob, WoT + (size_t)l * 512 * 512, 512, bo + l * D_, x, x, nullptr, D_, 0);
    ln_kernel<<<BT_ / 4, 256, 0, stream>>>(x, ln2g + l * D_, ln2b + l * D_, xn);
    gemm_pipe<64,64,2,2><<<dim3(64, 32), 256, 0, stream>>>(
        xn, W1T + (size_t)l * 2048 * 512, 512, b1 + l * 4 * D_, nullptr, nullptr, h1, 4 * D_, 1);
    gemm_pipe<64,64,2,2><<<dim3(64, 8), 256, 0, stream>>>(
        h1, W2T + (size_t)l * 512 * 2048, 2048, b2 + l * D_, x, x, nullptr, D_, 0);
  }

  transpose_cast<<<dim3(16, 1000, 1), 256, 0, stream>>>(Wp, WpT, 32000, 512, 0, 0);
  ln_kernel<<<BT_ / 4, 256, 0, stream>>>(x, lnfg, lnfb, xn);
  gemm_logits<<<dim3(32, 125), 512, 0, stream>>>(
      xn, WpT, 512, bp, out, V_, msbuf, 500);

  loss_merge_kernel<<<BT_ / 4, 256, 0, stream>>>(msbuf, out, labels, rowloss, 500);
  loss_final_kernel<<<1, 256, 0, stream>>>(rowloss, out + (size_t)BT_ * V_);
}

// Round 19
// 879.894 us; speedup vs baseline: 1.0465x; 1.0086x over previous
//
#include <hip/hip_runtime.h>
#include <hip/hip_bf16.h>
#include <math.h>

#define B_ 2
#define T_ 2048
#define D_ 512
#define H_ 8
#define NL_ 4
#define V_ 32000
#define HD_ 64
#define BT_ (B_*T_)
#define EPS_ 1e-5f
#define SCALE_ 0.04419417382415922f  /* 1/sqrt(512) — source scales by D, not HD */
#define NEGBIG -1e30f

typedef __bf16 bf16x8 __attribute__((ext_vector_type(8)));
typedef float  f32x4  __attribute__((ext_vector_type(4)));

__device__ __forceinline__ unsigned short f2bf(float f) {
  union { float f; unsigned u; } v; v.f = f;
  unsigned r = v.u + 0x7fff + ((v.u >> 16) & 1);
  return (unsigned short)(r >> 16);
}
__device__ __forceinline__ float bf2f(unsigned short h) {
  union { unsigned u; float f; } c; c.u = ((unsigned)h) << 16; return c.f;
}

__device__ __forceinline__ void gl_lds16(const void* g, void* l) {
  __builtin_amdgcn_global_load_lds(
      (const __attribute__((address_space(1))) void*)g,
      (__attribute__((address_space(3))) void*)l, 16, 0, 0);
}

#define WAITVM(n) asm volatile("s_waitcnt vmcnt(" #n ")" ::: "memory")
#define WAITLG0   asm volatile("s_waitcnt lgkmcnt(0)" ::: "memory")

// ---------------------------------------------------------------- embed -> bf16 x
__global__ __launch_bounds__(256) void embed_kernel(
    const int* __restrict__ ids, const float* __restrict__ tok,
    const float* __restrict__ pos, unsigned short* __restrict__ x)
{
  int i = blockIdx.x * 256 + threadIdx.x;   // chunk of 8 elems
  int c8 = i & 63;
  int bt = i >> 6;
  int t  = bt & (T_ - 1);
  const float4* tr = reinterpret_cast<const float4*>(tok + (size_t)ids[bt] * D_ + c8*8);
  const float4* pr = reinterpret_cast<const float4*>(pos + (size_t)t * D_ + c8*8);
  float4 a0 = tr[0], a1 = tr[1], p0 = pr[0], p1 = pr[1];
  ushort4 o0, o1;
  o0.x = f2bf(a0.x + p0.x); o0.y = f2bf(a0.y + p0.y);
  o0.z = f2bf(a0.z + p0.z); o0.w = f2bf(a0.w + p0.w);
  o1.x = f2bf(a1.x + p1.x); o1.y = f2bf(a1.y + p1.y);
  o1.z = f2bf(a1.z + p1.z); o1.w = f2bf(a1.w + p1.w);
  unsigned short* orow = x + (size_t)bt * D_ + c8*8;
  *reinterpret_cast<ushort4*>(orow)     = o0;
  *reinterpret_cast<ushort4*>(orow + 4) = o1;
}

// ---------------------------------------------------------------- layernorm (bf16 in) -> bf16 out
__global__ __launch_bounds__(256) void ln_kernel(
    const unsigned short* __restrict__ x, const float* __restrict__ g,
    const float* __restrict__ b, unsigned short* __restrict__ out)
{
  int row  = blockIdx.x * 4 + (threadIdx.x >> 6);
  int lane = threadIdx.x & 63;
  const unsigned short* xr = x + (size_t)row * D_;
  ushort4 u0 = *reinterpret_cast<const ushort4*>(xr + lane*4);
  ushort4 u1 = *reinterpret_cast<const ushort4*>(xr + 256 + lane*4);
  float v0x = bf2f(u0.x), v0y = bf2f(u0.y), v0z = bf2f(u0.z), v0w = bf2f(u0.w);
  float v1x = bf2f(u1.x), v1y = bf2f(u1.y), v1z = bf2f(u1.z), v1w = bf2f(u1.w);
  float s = v0x + v0y + v0z + v0w + v1x + v1y + v1z + v1w;
  float q = v0x*v0x + v0y*v0y + v0z*v0z + v0w*v0w
          + v1x*v1x + v1y*v1y + v1z*v1z + v1w*v1w;
  #pragma unroll
  for (int off = 1; off < 64; off <<= 1) {
    s += __shfl_xor(s, off);
    q += __shfl_xor(q, off);
  }
  float mean = s * (1.0f / D_);
  float var  = q * (1.0f / D_) - mean * mean;
  float rs   = rsqrtf(var + EPS_);
  const float4* g4 = reinterpret_cast<const float4*>(g);
  const float4* b4 = reinterpret_cast<const float4*>(b);
  float4 gv0 = g4[lane], gv1 = g4[lane + 64];
  float4 bv0 = b4[lane], bv1 = b4[lane + 64];
  ushort4 p0, p1;
  p0.x = f2bf((v0x - mean) * rs * gv0.x + bv0.x);
  p0.y = f2bf((v0y - mean) * rs * gv0.y + bv0.y);
  p0.z = f2bf((v0z - mean) * rs * gv0.z + bv0.z);
  p0.w = f2bf((v0w - mean) * rs * gv0.w + bv0.w);
  p1.x = f2bf((v1x - mean) * rs * gv1.x + bv1.x);
  p1.y = f2bf((v1y - mean) * rs * gv1.y + bv1.y);
  p1.z = f2bf((v1z - mean) * rs * gv1.z + bv1.z);
  p1.w = f2bf((v1w - mean) * rs * gv1.w + bv1.w);
  unsigned short* orow = out + (size_t)row * D_;
  *reinterpret_cast<ushort4*>(orow + lane * 4)       = p0;
  *reinterpret_cast<ushort4*>(orow + 256 + lane * 4) = p1;
}

// ---------------------------------------------------------------- transpose+cast fp32 [R][C] -> bf16 [C][R]
__global__ __launch_bounds__(256) void transpose_cast(
    const float* __restrict__ src, unsigned short* __restrict__ dst,
    int C, int R, long sstride, long dstride)
{
  src += (size_t)blockIdx.z * sstride;
  dst += (size_t)blockIdx.z * dstride;
  __shared__ float t[32][33];
  int r0 = blockIdx.x * 32, c0 = blockIdx.y * 32;
  int tx = threadIdx.x & 31, ty = threadIdx.x >> 5;
  #pragma unroll
  for (int i = 0; i < 4; i++)
    t[ty + i*8][tx] = src[(size_t)(r0 + ty + i*8) * C + c0 + tx];
  __syncthreads();
  #pragma unroll
  for (int i = 0; i < 4; i++)
    dst[(size_t)(c0 + ty + i*8) * R + r0 + tx] = f2bf(t[tx][ty + i*8]);
}

// WqkvT[l][mat*512 + h*64 + e][d] = W{q,k,v}[l][h][d][e]
__global__ __launch_bounds__(256) void qkvw_transpose(
    const float* __restrict__ Wq, const float* __restrict__ Wk,
    const float* __restrict__ Wv, unsigned short* __restrict__ dst)
{
  int z = blockIdx.z; int l = z / 24; int rem = z % 24; int mat = rem >> 3; int h = rem & 7;
  const float* W = (mat == 0 ? Wq : (mat == 1 ? Wk : Wv)) + ((size_t)(l * 8 + h)) * D_ * HD_;
  unsigned short* d = dst + ((size_t)l * 1536 + mat * 512 + h * 64) * D_;
  __shared__ float t[32][33];
  int d0 = blockIdx.x * 32, e0 = blockIdx.y * 32;
  int tx = threadIdx.x & 31, ty = threadIdx.x >> 5;
  #pragma unroll
  for (int i = 0; i < 4; i++)
    t[ty + i*8][tx] = W[(size_t)(d0 + ty + i*8) * HD_ + e0 + tx];
  __syncthreads();
  #pragma unroll
  for (int i = 0; i < 4; i++)
    d[(size_t)(e0 + ty + i*8) * D_ + d0 + tx] = f2bf(t[tx][ty + i*8]);
}

// ---------------------------------------------------------------- logits GEMM: 128x256 tile
__global__ __launch_bounds__(512, 4) void gemm_logits(
    const unsigned short* __restrict__ A,
    const unsigned short* __restrict__ Bt,
    int K, const float* __restrict__ bias,
    float* __restrict__ outF, int ldc,
    float2* __restrict__ ms, int npan)
{
  __shared__ __align__(16) char smem[73728];
  unsigned short* Abase = (unsigned short*)smem;
  unsigned short* Bbase = (unsigned short*)(smem + 24576);
  float* E = (float*)smem;

  const int tid = threadIdx.x;
  const int lane = tid & 63;
  const int lr = lane & 15, g = lane >> 4;
  const int wv = tid >> 6, wm = wv >> 2, wn = wv & 3;

  const int gx = gridDim.x;
  int id = blockIdx.y * gx + blockIdx.x;
  const int nwg = gx * gridDim.y;
  if ((nwg & 7) == 0) { const int q = nwg >> 3; id = (id & 7) * q + (id >> 3); }
  const int bm = (id % gx) * 128, bn = (id / gx) * 256, bnp = id / gx;

  const int schk = (lane & 3) ^ ((lane >> 3) & 3);
  const unsigned short* Ab = A  + (size_t)(bm + wv*16 + (lane >> 2)) * K + schk * 8;
  const unsigned short* Bb = Bt + (size_t)(bn + wv*16 + (lane >> 2)) * K + schk * 8;

#define STAGEL(s, sl)                                                       \
  { const int kof_ = (s) * 32;                                              \
    gl_lds16(Ab + kof_,                 Abase + (sl)*4096 + wv*512);        \
    gl_lds16(Bb + kof_,                 Bbase + (sl)*8192 + wv*512);        \
    gl_lds16(Bb + (size_t)128*K + kof_, Bbase + (sl)*8192 + 4096 + wv*512); }

  f32x4 acc[4][4];
  #pragma unroll
  for (int m = 0; m < 4; m++)
    #pragma unroll
    for (int n = 0; n < 4; n++)
      acc[m][n] = (f32x4){0.f, 0.f, 0.f, 0.f};

  const int nt = K >> 5;
  STAGEL(0, 0); STAGEL(1, 1);

  const int slotx = (g ^ ((lr >> 1) & 3)) << 3;

  for (int t = 0; t < nt; ++t) {
    const int s = t + 2;
    const int st = t % 3;
    __builtin_amdgcn_sched_barrier(0);
    if      (s < nt)  { const int ss = s % 3; STAGEL(s, ss); WAITVM(6); }
    else if (s == nt) { WAITVM(3); }
    else              { WAITVM(0); }
    __builtin_amdgcn_sched_barrier(0);
    __builtin_amdgcn_s_barrier();
    __builtin_amdgcn_sched_barrier(0);

    const unsigned short* Ac = Abase + st*4096;
    const unsigned short* Bc = Bbase + st*8192;
    bf16x8 af[4], bfr[4];
    #pragma unroll
    for (int m = 0; m < 4; m++)
      af[m] = *reinterpret_cast<const bf16x8*>(&Ac[(wm*64 + m*16 + lr) * 32 + slotx]);
    #pragma unroll
    for (int n = 0; n < 4; n++)
      bfr[n] = *reinterpret_cast<const bf16x8*>(&Bc[(wn*64 + n*16 + lr) * 32 + slotx]);
    __builtin_amdgcn_s_setprio(1);
    #pragma unroll
    for (int m = 0; m < 4; m++)
      #pragma unroll
      for (int n = 0; n < 4; n++)
        acc[m][n] = __builtin_amdgcn_mfma_f32_16x16x32_bf16(af[m], bfr[n], acc[m][n], 0, 0, 0);
    __builtin_amdgcn_s_setprio(0);
    __builtin_amdgcn_sched_barrier(0);
    __builtin_amdgcn_s_barrier();
  }
#undef STAGEL

  #pragma unroll
  for (int n = 0; n < 4; n++) {
    const float bv = bias ? bias[bn + wn*64 + n*16 + lr] : 0.f;
    #pragma unroll
    for (int m = 0; m < 4; m++)
      #pragma unroll
      for (int r = 0; r < 4; r++)
        acc[m][n][r] += bv;
  }

  if (ms) {
    #pragma unroll
    for (int m = 0; m < 4; m++) {
      float vmax[4] = {NEGBIG, NEGBIG, NEGBIG, NEGBIG};
      #pragma unroll
      for (int n = 0; n < 4; n++)
        #pragma unroll
        for (int r = 0; r < 4; r++)
          vmax[r] = fmaxf(vmax[r], acc[m][n][r]);
      #pragma unroll
      for (int r = 0; r < 4; r++) {
        #pragma unroll
        for (int off = 1; off < 16; off <<= 1)
          vmax[r] = fmaxf(vmax[r], __shfl_xor(vmax[r], off));
      }
      float vsum[4] = {0.f, 0.f, 0.f, 0.f};
      #pragma unroll
      for (int n = 0; n < 4; n++)
        #pragma unroll
        for (int r = 0; r < 4; r++)
          vsum[r] += __expf(acc[m][n][r] - vmax[r]);
      #pragma unroll
      for (int r = 0; r < 4; r++) {
        #pragma unroll
        for (int off = 1; off < 16; off <<= 1)
          vsum[r] += __shfl_xor(vsum[r], off);
      }
      if (lr == 0) {
        #pragma unroll
        for (int r = 0; r < 4; r++)
          ms[(size_t)(bm + wm*64 + m*16 + g*4 + r) * npan + bnp*4 + wn] =
              make_float2(vmax[r], vsum[r]);
      }
    }
  }

  #pragma unroll
  for (int c = 0; c < 2; ++c) {
    __syncthreads();
    if (wm == c) {
      #pragma unroll
      for (int m = 0; m < 4; m++)
        #pragma unroll
        for (int n = 0; n < 4; n++)
          #pragma unroll
          for (int r = 0; r < 4; r++)
            E[(m*16 + g*4 + r) * 260 + wn*64 + n*16 + lr] = acc[m][n][r];
    }
    __syncthreads();
    #pragma unroll
    for (int rep = 0; rep < 8; rep++) {
      const int row = rep*8 + wv;
      f32x4 v = *reinterpret_cast<const f32x4*>(&E[row*260 + lane*4]);
      __builtin_nontemporal_store(
          v, reinterpret_cast<f32x4*>(&outF[(size_t)(bm + c*64 + row) * ldc + bn + lane*4]));
    }
  }
}

// ---------------------------------------------------------------- pipelined bf16 MFMA GEMM
// BMxBN tile, BK=64 per sync, 2 LDS buffers, depth-1 counted vmcnt, XOR swizzle.
// resid (optional) is bf16; outputs via outF (fp32) or outH (bf16).
template<int BM_T, int BN_T, int WM, int WN>
__global__ __launch_bounds__(256) void gemm_pipe(
    const unsigned short* __restrict__ A,
    const unsigned short* __restrict__ Bt,
    int K,
    const float* __restrict__ bias,
    const unsigned short* __restrict__ resid,
    float* __restrict__ outF,
    unsigned short* __restrict__ outH,
    int ldc, int relu)
{
  constexpr int BKp = 64;
  constexpr int ALOADS = BM_T / 32;
  constexpr int BLOADS = BN_T / 32;
  constexpr int LOADS  = ALOADS + BLOADS;
  constexpr int MR = BM_T / (16 * WM);
  constexpr int NR = BN_T / (16 * WN);
  __shared__ __align__(16) unsigned short As[2][BM_T * BKp];
  __shared__ __align__(16) unsigned short Bs[2][BN_T * BKp];

  const int tid = threadIdx.x;
  const int lane = tid & 63, wv = tid >> 6;
  const int lr = lane & 15, g = lane >> 4;

  const int gx = gridDim.x;
  int id = blockIdx.y * gx + blockIdx.x;
  const int nwg = gx * gridDim.y;
  if ((nwg & 7) == 0) {
    const int q = nwg >> 3;
    id = (id & 7) * q + (id >> 3);
  }
  const int bm = (id % gx) * BM_T, bn = (id / gx) * BN_T;

  const int m0w = (wv / WN) * (BM_T / WM);
  const int n0w = (wv % WN) * (BN_T / WN);

  const int srow = wv*8 + (lane >> 3);
  const int schk = (lane & 7) ^ (lane >> 3);
  const unsigned short* Ab = A  + (size_t)(bm + srow) * K + schk * 8;
  const unsigned short* Bb = Bt + (size_t)(bn + srow) * K + schk * 8;

#define STAGEP(s, sl)                                                           \
  { const int kof_ = (s) * BKp;                                                 \
    _Pragma("unroll")                                                           \
    for (int i_ = 0; i_ < ALOADS; ++i_)                                         \
      gl_lds16(Ab + (size_t)(i_*32)*K + kof_, As[sl] + i_*2048 + wv*512);       \
    _Pragma("unroll")                                                           \
    for (int i_ = 0; i_ < BLOADS; ++i_)                                         \
      gl_lds16(Bb + (size_t)(i_*32)*K + kof_, Bs[sl] + i_*2048 + wv*512); }

  f32x4 acc[MR][NR];
  #pragma unroll
  for (int m = 0; m < MR; m++)
    #pragma unroll
    for (int n = 0; n < NR; n++)
      acc[m][n] = (f32x4){0.f, 0.f, 0.f, 0.f};

  const int nt = K >> 6;
  STAGEP(0, 0);

  for (int t = 0; t < nt; ++t) {
    __builtin_amdgcn_sched_barrier(0);
    if (t + 1 < nt) {
      STAGEP(t + 1, (t + 1) & 1);
      if constexpr (LOADS == 4) WAITVM(4);
      else if constexpr (LOADS == 6) WAITVM(6);
      else WAITVM(8);
    } else {
      WAITVM(0);
    }
    __builtin_amdgcn_sched_barrier(0);
    __builtin_amdgcn_s_barrier();          // tile t visible to all waves
    __builtin_amdgcn_sched_barrier(0);

    const unsigned short* Ac = As[t & 1];
    const unsigned short* Bc = Bs[t & 1];
    #pragma unroll
    for (int kk = 0; kk < 2; ++kk) {
      const int sl = ((kk*4 + g) ^ (lr & 7)) << 3;
      bf16x8 af[MR], bfr[NR];
      #pragma unroll
      for (int m = 0; m < MR; m++)
        af[m] = *reinterpret_cast<const bf16x8*>(&Ac[(m0w + m*16 + lr) * BKp + sl]);
      #pragma unroll
      for (int n = 0; n < NR; n++)
        bfr[n] = *reinterpret_cast<const bf16x8*>(&Bc[(n0w + n*16 + lr) * BKp + sl]);
      __builtin_amdgcn_s_setprio(1);
      #pragma unroll
      for (int m = 0; m < MR; m++)
        #pragma unroll
        for (int n = 0; n < NR; n++)
          acc[m][n] = __builtin_amdgcn_mfma_f32_16x16x32_bf16(af[m], bfr[n], acc[m][n], 0, 0, 0);
      __builtin_amdgcn_s_setprio(0);
    }
    __builtin_amdgcn_sched_barrier(0);
    __builtin_amdgcn_s_barrier();          // all waves done reading buf[t&1]
  }
#undef STAGEP

  const int cr = g * 4;
  const int cc = lr;
  #pragma unroll
  for (int m = 0; m < MR; m++) {
    #pragma unroll
    for (int n = 0; n < NR; n++) {
      int row = bm + m0w + m*16 + cr;
      int col = bn + n0w + n*16 + cc;
      f32x4 a = acc[m][n];
      #pragma unroll
      for (int r = 0; r < 4; r++) {
        float v = a[r];
        if (bias)  v += bias[col];
        if (resid) v += bf2f(resid[(size_t)(row + r) * ldc + col]);
        if (relu)  v = fmaxf(v, 0.f);
        if (outF)  outF[(size_t)(row + r) * ldc + col] = v;
        if (outH)  outH[(size_t)(row + r) * ldc + col] = f2bf(v);
      }
    }
  }
}

// ---------------------------------------------------------------- MFMA flash attention (bf16 in/out)
// 128 q-rows per block, 8 waves. Work-split scheduling: tasks qb<8 run whole;
// qb>=8 split KV range into 2 halves (flash-decoding), merged by attn_merge.
__global__ __launch_bounds__(512) void attn_mfma(
    const unsigned short* __restrict__ qkv,  // bf16 [B*T][1536]
    unsigned short* __restrict__ o,          // bf16 [B*T][512]
    float* __restrict__ Opart,               // [128 blk][2][128][64] fp32
    float2* __restrict__ ml)                 // [128 blk][2][128]
{
  __shared__ __align__(16) unsigned short Ks[2][64*64];
  __shared__ __align__(16) unsigned short Vt[2][64*64];
  __shared__ __align__(16) unsigned short Ps[8][16*64];

  static const unsigned char ord[24] = {7,22,23,20,21,6,18,19,16,17,5,14,15,12,13,4,10,11,8,9,3,2,1,0};
  const int slot = ord[blockIdx.x];
  const int bh = blockIdx.y, bb = bh >> 3, hh = bh & 7;
  int qb, it0, itn, half;
  if (slot < 8) { qb = slot; it0 = 0; itn = 2*qb + 2; half = -1; }
  else { const int p = slot - 8; qb = 8 + (p >> 1); half = p & 1;
         const int nh = qb + 1; it0 = half * nh; itn = nh; }

  const int tid = threadIdx.x, lane = tid & 63, wv = tid >> 6;
  const int lr = lane & 15, g = lane >> 4;

  const unsigned short* qp = qkv + ((size_t)(bb*T_ + qb*128))*1536 + hh*64;
  const unsigned short* kp = qkv + ((size_t)bb*T_)*1536 + 512  + hh*64;
  const unsigned short* vp = qkv + ((size_t)bb*T_)*1536 + 1024 + hh*64;

  bf16x8 qf[2];
  qf[0] = *reinterpret_cast<const bf16x8*>(qp + (size_t)(wv*16 + lr)*1536 + g*8);
  qf[1] = *reinterpret_cast<const bf16x8*>(qp + (size_t)(wv*16 + lr)*1536 + 32 + g*8);

  const int krow = wv*8 + (lane >> 3);
  const int khb  = (lane & 7) ^ (lane >> 3);

#define STAGE_K(s0_, buf_)                                           \
  gl_lds16(kp + (size_t)((s0_)*64 + krow)*1536 + khb*8,              \
           (void*)(Ks[buf_] + wv*512));

  uint4 uvr;
#define LOAD_V(s0_)                                                  \
  uvr = *reinterpret_cast<const uint4*>(                             \
      vp + (size_t)((s0_)*64 + lane)*1536 + wv*8);

  f32x4 ov[4];
  #pragma unroll
  for (int n = 0; n < 4; n++) ov[n] = (f32x4){0.f, 0.f, 0.f, 0.f};
  float mrow[4] = {NEGBIG, NEGBIG, NEGBIG, NEGBIG};
  float lrow[4] = {0.f, 0.f, 0.f, 0.f};

  STAGE_K(it0, 0);
  LOAD_V(it0);

  for (int ii = 0; ii < itn; ++ii) {
    const int s0 = it0 + ii;
    const int cur = ii & 1;
    WAITVM(0);                         // K(cur) in LDS, V(cur) in regs
    __builtin_amdgcn_sched_barrier(0);
    {                                  // write V(cur) regs -> Vt[cur] (swizzled)
      union { uint4 v; unsigned short e[8]; } uv; uv.v = uvr;
      #pragma unroll
      for (int j = 0; j < 8; j++)
        Vt[cur][(wv*8 + j)*64 + (((lane >> 3) ^ j) << 3) + (lane & 7)] = uv.e[j];
    }
    WAITLG0;
    __builtin_amdgcn_sched_barrier(0);
    __builtin_amdgcn_s_barrier();      // K/V tile cur visible to all waves
    __builtin_amdgcn_sched_barrier(0);

    if (ii + 1 < itn) {                // async prefetch of next tile
      STAGE_K(s0 + 1, cur ^ 1);
      LOAD_V(s0 + 1);
    }

    // --- S = Q @ K^T
    f32x4 sf[4];
    #pragma unroll
    for (int n = 0; n < 4; n++) sf[n] = (f32x4){0.f, 0.f, 0.f, 0.f};
    __builtin_amdgcn_s_setprio(1);
    #pragma unroll
    for (int kk = 0; kk < 2; kk++) {
      #pragma unroll
      for (int n = 0; n < 4; n++) {
        const bf16x8 kf = *reinterpret_cast<const bf16x8*>(
            &Ks[cur][(n*16 + lr)*64 + (((kk*4 + g) ^ (lr & 7)) << 3)]);
        sf[n] = __builtin_amdgcn_mfma_f32_16x16x32_bf16(qf[kk], kf, sf[n], 0, 0, 0);
      }
    }
    __builtin_amdgcn_s_setprio(0);

    // --- scale + causal mask
    float sv[4][4];
    #pragma unroll
    for (int n = 0; n < 4; n++)
      #pragma unroll
      for (int r = 0; r < 4; r++) {
        const int kvg = s0*64 + n*16 + lr;
        const int qg  = qb*128 + wv*16 + g*4 + r;
        sv[n][r] = (kvg > qg) ? NEGBIG : sf[n][r] * SCALE_;
      }

    float aa[4];
    #pragma unroll
    for (int r = 0; r < 4; r++) {
      float pm = fmaxf(fmaxf(sv[0][r], sv[1][r]), fmaxf(sv[2][r], sv[3][r]));
      pm = fmaxf(pm, __shfl_xor(pm, 1));
      pm = fmaxf(pm, __shfl_xor(pm, 2));
      pm = fmaxf(pm, __shfl_xor(pm, 4));
      pm = fmaxf(pm, __shfl_xor(pm, 8));
      float mn = fmaxf(mrow[r], pm);
      aa[r] = __expf(mrow[r] - mn);
      mrow[r] = mn;
    }
    float rs[4] = {0.f, 0.f, 0.f, 0.f};
    #pragma unroll
    for (int n = 0; n < 4; n++)
      #pragma unroll
      for (int r = 0; r < 4; r++) {
        float p = __expf(sv[n][r] - mrow[r]);
        rs[r] += p;
        Ps[wv][(g*4 + r)*64 + ((((n << 1) + (lr >> 3)) ^ ((g*4 + r) & 7)) << 3) + (lr & 7)] = f2bf(p);
      }
    #pragma unroll
    for (int r = 0; r < 4; r++) {
      float s = rs[r];
      s += __shfl_xor(s, 1); s += __shfl_xor(s, 2);
      s += __shfl_xor(s, 4); s += __shfl_xor(s, 8);
      lrow[r] = lrow[r]*aa[r] + s;
    }
    #pragma unroll
    for (int n = 0; n < 4; n++)
      #pragma unroll
      for (int r = 0; r < 4; r++)
        ov[n][r] *= aa[r];

    // --- O += P @ V
    __builtin_amdgcn_s_setprio(1);
    #pragma unroll
    for (int kk = 0; kk < 2; kk++) {
      const bf16x8 pf = *reinterpret_cast<const bf16x8*>(
          &Ps[wv][lr*64 + (((kk*4 + g) ^ (lr & 7)) << 3)]);
      #pragma unroll
      for (int n = 0; n < 4; n++) {
        const bf16x8 vf = *reinterpret_cast<const bf16x8*>(
            &Vt[cur][(n*16 + lr)*64 + (((kk*4 + g) ^ (lr & 7)) << 3)]);
        ov[n] = __builtin_amdgcn_mfma_f32_16x16x32_bf16(pf, vf, ov[n], 0, 0, 0);
      }
    }
    __builtin_amdgcn_s_setprio(0);
    __builtin_amdgcn_sched_barrier(0);
    __builtin_amdgcn_s_barrier();      // all waves done reading tile cur
  }
#undef STAGE_K
#undef LOAD_V

  if (half < 0) {
    #pragma unroll
    for (int r = 0; r < 4; r++) {
      float inv = 1.0f / lrow[r];
      size_t row = (size_t)(bb*T_ + qb*128 + wv*16 + g*4 + r);
      #pragma unroll
      for (int n = 0; n < 4; n++)
        o[row*D_ + hh*64 + n*16 + lr] = f2bf(ov[n][r] * inv);
    }
  } else {
    const int blk = bh*8 + (qb - 8);
    float* Od = Opart + ((size_t)blk*2 + half)*128*64;
    #pragma unroll
    for (int r = 0; r < 4; r++) {
      const int rloc = wv*16 + g*4 + r;
      #pragma unroll
      for (int n = 0; n < 4; n++)
        Od[rloc*64 + n*16 + lr] = ov[n][r];
      if (lr == 0)
        ml[((size_t)blk*2 + half)*128 + rloc] = make_float2(mrow[r], lrow[r]);
    }
  }
}

// ---------------------------------------------------------------- attention split-merge
__global__ __launch_bounds__(256) void attn_merge(
    const float* __restrict__ Opart, const float2* __restrict__ ml,
    unsigned short* __restrict__ o)
{
  const int blk = blockIdx.x;              // bh*8 + (qb-8)
  const int bh = blk >> 3, qb = (blk & 7) + 8;
  const int bb = bh >> 3, hh = bh & 7;
  const int tid = threadIdx.x;
  const int row = tid >> 1, ch = (tid & 1) * 32;
  const float* O0 = Opart + ((size_t)blk*2 + 0)*128*64;
  const float* O1 = Opart + ((size_t)blk*2 + 1)*128*64;
  const float2 a = ml[(size_t)blk*2*128 + row];
  const float2 b = ml[((size_t)blk*2 + 1)*128 + row];
  const float M  = fmaxf(a.x, b.x);
  const float e0 = __expf(a.x - M), e1 = __expf(b.x - M);
  const float inv = 1.0f / (a.y*e0 + b.y*e1);
  unsigned short* orow = o + ((size_t)(bb*T_ + qb*128 + row))*D_ + hh*64 + ch;
  #pragma unroll
  for (int c = 0; c < 32; c += 4) {
    f32x4 v0 = *reinterpret_cast<const f32x4*>(&O0[row*64 + ch + c]);
    f32x4 v1 = *reinterpret_cast<const f32x4*>(&O1[row*64 + ch + c]);
    ushort4 pk;
    pk.x = f2bf((v0[0]*e0 + v1[0]*e1) * inv);
    pk.y = f2bf((v0[1]*e0 + v1[1]*e1) * inv);
    pk.z = f2bf((v0[2]*e0 + v1[2]*e1) * inv);
    pk.w = f2bf((v0[3]*e0 + v1[3]*e1) * inv);
    *reinterpret_cast<ushort4*>(&orow[c]) = pk;
  }
}

// ---------------------------------------------------------------- loss: merge per-panel partials
__global__ __launch_bounds__(256) void loss_merge_kernel(
    const float2* __restrict__ ms, const float* __restrict__ logits,
    const int* __restrict__ labels, float* __restrict__ rowloss, int npan)
{
  const int tid = threadIdx.x, lane = tid & 63, wid = tid >> 6;
  const int row = blockIdx.x * 4 + wid;
  float M = NEGBIG, S = 0.f;
  const float2* p = ms + (size_t)row * npan;
  for (int i = lane; i < npan; i += 64) {
    float2 e = p[i];
    float Mn = fmaxf(M, e.x);
    S = S * __expf(M - Mn) + e.y * __expf(e.x - Mn);
    M = Mn;
  }
  #pragma unroll
  for (int off = 1; off < 64; off <<= 1) {
    float Mo = __shfl_xor(M, off), So = __shfl_xor(S, off);
    float Mn = fmaxf(M, Mo);
    S = S * __expf(M - Mn) + So * __expf(Mo - Mn);
    M = Mn;
  }
  if (lane == 0)
    rowloss[row] = logits[(size_t)row * V_ + labels[row]] - M - logf(S);
}

__global__ __launch_bounds__(256) void loss_final_kernel(
    const float* __restrict__ rowloss, float* __restrict__ out)
{
  __shared__ float red[4];
  const int tid = threadIdx.x, lane = tid & 63, wid = tid >> 6;
  float s = 0.f;
  for (int i = tid; i < BT_; i += 256) s += rowloss[i];
  #pragma unroll
  for (int off = 1; off < 64; off <<= 1) s += __shfl_xor(s, off);
  if (lane == 0) red[wid] = s;
  __syncthreads();
  if (tid == 0) out[0] = -(red[0] + red[1] + red[2] + red[3]) * (1.0f / BT_);
}

// ---------------------------------------------------------------- launch
extern "C" void kernel_launch(void* const* d_in, const int* in_sizes, int n_in,
                              void* d_out, int out_size, void* d_ws, size_t ws_size,
                              hipStream_t stream)
{
  (void)in_sizes; (void)n_in; (void)out_size; (void)ws_size;
  const int*   ids    = (const int*)d_in[0];
  const int*   labels = (const int*)d_in[1];
  const float* tok    = (const float*)d_in[2];
  const float* pos    = (const float*)d_in[3];
  const float* Wq     = (const float*)d_in[4];
  const float* Wk     = (const float*)d_in[5];
  const float* Wv     = (const float*)d_in[6];
  const float* Wo     = (const float*)d_in[7];
  const float* bo     = (const float*)d_in[8];
  const float* ln1g   = (const float*)d_in[9];
  const float* ln1b   = (const float*)d_in[10];
  const float* ln2g   = (const float*)d_in[11];
  const float* ln2b   = (const float*)d_in[12];
  const float* W1     = (const float*)d_in[13];
  const float* b1     = (const float*)d_in[14];
  const float* W2     = (const float*)d_in[15];
  const float* b2     = (const float*)d_in[16];
  const float* lnfg   = (const float*)d_in[17];
  const float* lnfb   = (const float*)d_in[18];
  const float* Wp     = (const float*)d_in[19];
  const float* bp     = (const float*)d_in[20];

  float* out = (float*)d_out;
  char* base = (char*)d_ws;
  unsigned short* x       = (unsigned short*)(base + 0);        //  4,194,304 (bf16 residual)
  unsigned short* xn      = (unsigned short*)(base + 8388608);  //  4,194,304
  float*          rowloss = (float*)(base + 12582912);          //     16,384
  unsigned short* WqkvT   = (unsigned short*)(base + 12599296); //  6,291,456
  unsigned short* W1T     = (unsigned short*)(base + 18890752); //  8,388,608
  unsigned short* W2T     = (unsigned short*)(base + 27279360); //  8,388,608
  unsigned short* WoT     = (unsigned short*)(base + 35667968); //  2,097,152
  unsigned short* qkvh    = (unsigned short*)(base + 37765120); // 12,582,912
  unsigned short* ob      = (unsigned short*)(base + 50348032); //  4,194,304
  unsigned short* h1      = (unsigned short*)(base + 54542336); // 16,777,216
  float*          Opart   = (float*)(base + 54542336);          //  8,388,608 (alias h1: dead during attn)
  float2*         mlbuf   = (float2*)(base + 62930944);         //    262,144 (alias h1 upper half)
  unsigned short* WpT     = (unsigned short*)(base + 37765120); // 32,768,000 (alias: dead at logits time)
  float2*         msbuf   = (float2*)(base + 12599296);         // 16,384,000 (alias: weight-T region, dead at logits time)

  embed_kernel<<<BT_ * D_ / 8 / 256, 256, 0, stream>>>(ids, tok, pos, x);

  qkvw_transpose<<<dim3(16, 2, 96), 256, 0, stream>>>(Wq, Wk, Wv, WqkvT);
  transpose_cast<<<dim3(16, 64, 4), 256, 0, stream>>>(W1, W1T, 2048, 512, 1048576, 1048576);
  transpose_cast<<<dim3(64, 16, 4), 256, 0, stream>>>(W2, W2T, 512, 2048, 1048576, 1048576);
  transpose_cast<<<dim3(16, 16, 4), 256, 0, stream>>>(Wo, WoT, 512, 512, 262144, 262144);

  for (int l = 0; l < NL_; l++) {
    ln_kernel<<<BT_ / 4, 256, 0, stream>>>(x, ln1g + l * D_, ln1b + l * D_, xn);
    gemm_pipe<64,64,2,2><<<dim3(64, 24), 256, 0, stream>>>(
        xn, WqkvT + (size_t)l * 1536 * 512, 512, nullptr, nullptr, nullptr, qkvh, 1536, 0);
    attn_mfma<<<dim3(24, B_ * H_), 512, 0, stream>>>(qkvh, ob, Opart, mlbuf);
    attn_merge<<<128, 256, 0, stream>>>(Opart, mlbuf, ob);
    gemm_pipe<64,64,2,2><<<dim3(64, 8), 256, 0, stream>>>(
        ob, WoT + (size_t)l * 512 * 512, 512, bo + l * D_, x, nullptr, x, D_, 0);
    ln_kernel<<<BT_ / 4, 256, 0, stream>>>(x, ln2g + l * D_, ln2b + l * D_, xn);
    gemm_pipe<64,64,2,2><<<dim3(64, 32), 256, 0, stream>>>(
        xn, W1T + (size_t)l * 2048 * 512, 512, b1 + l * 4 * D_, nullptr, nullptr, h1, 4 * D_, 1);
    gemm_pipe<64,64,2,2><<<dim3(64, 8), 256, 0, stream>>>(
        h1, W2T + (size_t)l * 512 * 2048, 2048, b2 + l * D_, x, nullptr, x, D_, 0);
  }

  transpose_cast<<<dim3(16, 1000, 1), 256, 0, stream>>>(Wp, WpT, 32000, 512, 0, 0);
  ln_kernel<<<BT_ / 4, 256, 0, stream>>>(x, lnfg, lnfb, xn);
  gemm_logits<<<dim3(32, 125), 512, 0, stream>>>(
      xn, WpT, 512, bp, out, V_, msbuf, 500);

  loss_merge_kernel<<<BT_ / 4, 256, 0, stream>>>(msbuf, out, labels, rowloss, 500);
  loss_final_kernel<<<1, 256, 0, stream>>>(rowloss, out + (size_t)BT_ * V_);
}

// Round 20
// 878.108 us; speedup vs baseline: 1.0487x; 1.0020x over previous
//
#include <hip/hip_runtime.h>
#include <hip/hip_bf16.h>
#include <math.h>

#define B_ 2
#define T_ 2048
#define D_ 512
#define H_ 8
#define NL_ 4
#define V_ 32000
#define HD_ 64
#define BT_ (B_*T_)
#define EPS_ 1e-5f
#define SCALE_ 0.04419417382415922f  /* 1/sqrt(512) — source scales by D, not HD */
#define NEGBIG -1e30f

typedef __bf16 bf16x8 __attribute__((ext_vector_type(8)));
typedef float  f32x4  __attribute__((ext_vector_type(4)));

__device__ __forceinline__ unsigned short f2bf(float f) {
  union { float f; unsigned u; } v; v.f = f;
  unsigned r = v.u + 0x7fff + ((v.u >> 16) & 1);
  return (unsigned short)(r >> 16);
}
__device__ __forceinline__ float bf2f(unsigned short h) {
  union { unsigned u; float f; } c; c.u = ((unsigned)h) << 16; return c.f;
}

__device__ __forceinline__ void gl_lds16(const void* g, void* l) {
  __builtin_amdgcn_global_load_lds(
      (const __attribute__((address_space(1))) void*)g,
      (__attribute__((address_space(3))) void*)l, 16, 0, 0);
}

#define WAITVM(n) asm volatile("s_waitcnt vmcnt(" #n ")" ::: "memory")
#define WAITLG0   asm volatile("s_waitcnt lgkmcnt(0)" ::: "memory")

// ---------------------------------------------------------------- embed -> bf16 x
__global__ __launch_bounds__(256) void embed_kernel(
    const int* __restrict__ ids, const float* __restrict__ tok,
    const float* __restrict__ pos, unsigned short* __restrict__ x)
{
  int i = blockIdx.x * 256 + threadIdx.x;   // chunk of 8 elems
  int c8 = i & 63;
  int bt = i >> 6;
  int t  = bt & (T_ - 1);
  const float4* tr = reinterpret_cast<const float4*>(tok + (size_t)ids[bt] * D_ + c8*8);
  const float4* pr = reinterpret_cast<const float4*>(pos + (size_t)t * D_ + c8*8);
  float4 a0 = tr[0], a1 = tr[1], p0 = pr[0], p1 = pr[1];
  ushort4 o0, o1;
  o0.x = f2bf(a0.x + p0.x); o0.y = f2bf(a0.y + p0.y);
  o0.z = f2bf(a0.z + p0.z); o0.w = f2bf(a0.w + p0.w);
  o1.x = f2bf(a1.x + p1.x); o1.y = f2bf(a1.y + p1.y);
  o1.z = f2bf(a1.z + p1.z); o1.w = f2bf(a1.w + p1.w);
  unsigned short* orow = x + (size_t)bt * D_ + c8*8;
  *reinterpret_cast<ushort4*>(orow)     = o0;
  *reinterpret_cast<ushort4*>(orow + 4) = o1;
}

// ---------------------------------------------------------------- layernorm (bf16 in) -> bf16 out
__global__ __launch_bounds__(256) void ln_kernel(
    const unsigned short* __restrict__ x, const float* __restrict__ g,
    const float* __restrict__ b, unsigned short* __restrict__ out)
{
  int row  = blockIdx.x * 4 + (threadIdx.x >> 6);
  int lane = threadIdx.x & 63;
  const unsigned short* xr = x + (size_t)row * D_;
  ushort4 u0 = *reinterpret_cast<const ushort4*>(xr + lane*4);
  ushort4 u1 = *reinterpret_cast<const ushort4*>(xr + 256 + lane*4);
  float v0x = bf2f(u0.x), v0y = bf2f(u0.y), v0z = bf2f(u0.z), v0w = bf2f(u0.w);
  float v1x = bf2f(u1.x), v1y = bf2f(u1.y), v1z = bf2f(u1.z), v1w = bf2f(u1.w);
  float s = v0x + v0y + v0z + v0w + v1x + v1y + v1z + v1w;
  float q = v0x*v0x + v0y*v0y + v0z*v0z + v0w*v0w
          + v1x*v1x + v1y*v1y + v1z*v1z + v1w*v1w;
  #pragma unroll
  for (int off = 1; off < 64; off <<= 1) {
    s += __shfl_xor(s, off);
    q += __shfl_xor(q, off);
  }
  float mean = s * (1.0f / D_);
  float var  = q * (1.0f / D_) - mean * mean;
  float rs   = rsqrtf(var + EPS_);
  const float4* g4 = reinterpret_cast<const float4*>(g);
  const float4* b4 = reinterpret_cast<const float4*>(b);
  float4 gv0 = g4[lane], gv1 = g4[lane + 64];
  float4 bv0 = b4[lane], bv1 = b4[lane + 64];
  ushort4 p0, p1;
  p0.x = f2bf((v0x - mean) * rs * gv0.x + bv0.x);
  p0.y = f2bf((v0y - mean) * rs * gv0.y + bv0.y);
  p0.z = f2bf((v0z - mean) * rs * gv0.z + bv0.z);
  p0.w = f2bf((v0w - mean) * rs * gv0.w + bv0.w);
  p1.x = f2bf((v1x - mean) * rs * gv1.x + bv1.x);
  p1.y = f2bf((v1y - mean) * rs * gv1.y + bv1.y);
  p1.z = f2bf((v1z - mean) * rs * gv1.z + bv1.z);
  p1.w = f2bf((v1w - mean) * rs * gv1.w + bv1.w);
  unsigned short* orow = out + (size_t)row * D_;
  *reinterpret_cast<ushort4*>(orow + lane * 4)       = p0;
  *reinterpret_cast<ushort4*>(orow + 256 + lane * 4) = p1;
}

// ---------------------------------------------------------------- transpose+cast fp32 [R][C] -> bf16 [C][R]
__global__ __launch_bounds__(256) void transpose_cast(
    const float* __restrict__ src, unsigned short* __restrict__ dst,
    int C, int R, long sstride, long dstride)
{
  src += (size_t)blockIdx.z * sstride;
  dst += (size_t)blockIdx.z * dstride;
  __shared__ float t[32][33];
  int r0 = blockIdx.x * 32, c0 = blockIdx.y * 32;
  int tx = threadIdx.x & 31, ty = threadIdx.x >> 5;
  #pragma unroll
  for (int i = 0; i < 4; i++)
    t[ty + i*8][tx] = src[(size_t)(r0 + ty + i*8) * C + c0 + tx];
  __syncthreads();
  #pragma unroll
  for (int i = 0; i < 4; i++)
    dst[(size_t)(c0 + ty + i*8) * R + r0 + tx] = f2bf(t[tx][ty + i*8]);
}

// WqkvT[l][mat*512 + h*64 + e][d] = W{q,k,v}[l][h][d][e]
__global__ __launch_bounds__(256) void qkvw_transpose(
    const float* __restrict__ Wq, const float* __restrict__ Wk,
    const float* __restrict__ Wv, unsigned short* __restrict__ dst)
{
  int z = blockIdx.z; int l = z / 24; int rem = z % 24; int mat = rem >> 3; int h = rem & 7;
  const float* W = (mat == 0 ? Wq : (mat == 1 ? Wk : Wv)) + ((size_t)(l * 8 + h)) * D_ * HD_;
  unsigned short* d = dst + ((size_t)l * 1536 + mat * 512 + h * 64) * D_;
  __shared__ float t[32][33];
  int d0 = blockIdx.x * 32, e0 = blockIdx.y * 32;
  int tx = threadIdx.x & 31, ty = threadIdx.x >> 5;
  #pragma unroll
  for (int i = 0; i < 4; i++)
    t[ty + i*8][tx] = W[(size_t)(d0 + ty + i*8) * HD_ + e0 + tx];
  __syncthreads();
  #pragma unroll
  for (int i = 0; i < 4; i++)
    d[(size_t)(e0 + ty + i*8) * D_ + d0 + tx] = f2bf(t[tx][ty + i*8]);
}

// ---------------------------------------------------------------- logits GEMM: 128x256 tile
// Fused per-(row,panel) softmax partials (LDS-merged to 1 entry) +
// LDS-transposed nontemporal dwordx4 fp32 stores.
__global__ __launch_bounds__(512, 4) void gemm_logits(
    const unsigned short* __restrict__ A,
    const unsigned short* __restrict__ Bt,
    int K, const float* __restrict__ bias,
    float* __restrict__ outF, int ldc,
    float2* __restrict__ ms, int npan)
{
  __shared__ __align__(16) char smem[73728];
  unsigned short* Abase = (unsigned short*)smem;
  unsigned short* Bbase = (unsigned short*)(smem + 24576);
  float* E = (float*)smem;
  float2* msL = (float2*)smem;    // 128 rows x 4 wn = 4 KB (used between K-loop and E pass)

  const int tid = threadIdx.x;
  const int lane = tid & 63;
  const int lr = lane & 15, g = lane >> 4;
  const int wv = tid >> 6, wm = wv >> 2, wn = wv & 3;

  const int gx = gridDim.x;
  int id = blockIdx.y * gx + blockIdx.x;
  const int nwg = gx * gridDim.y;
  if ((nwg & 7) == 0) { const int q = nwg >> 3; id = (id & 7) * q + (id >> 3); }
  const int bm = (id % gx) * 128, bn = (id / gx) * 256, bnp = id / gx;

  const int schk = (lane & 3) ^ ((lane >> 3) & 3);
  const unsigned short* Ab = A  + (size_t)(bm + wv*16 + (lane >> 2)) * K + schk * 8;
  const unsigned short* Bb = Bt + (size_t)(bn + wv*16 + (lane >> 2)) * K + schk * 8;

#define STAGEL(s, sl)                                                       \
  { const int kof_ = (s) * 32;                                              \
    gl_lds16(Ab + kof_,                 Abase + (sl)*4096 + wv*512);        \
    gl_lds16(Bb + kof_,                 Bbase + (sl)*8192 + wv*512);        \
    gl_lds16(Bb + (size_t)128*K + kof_, Bbase + (sl)*8192 + 4096 + wv*512); }

  f32x4 acc[4][4];
  #pragma unroll
  for (int m = 0; m < 4; m++)
    #pragma unroll
    for (int n = 0; n < 4; n++)
      acc[m][n] = (f32x4){0.f, 0.f, 0.f, 0.f};

  const int nt = K >> 5;
  STAGEL(0, 0); STAGEL(1, 1);

  const int slotx = (g ^ ((lr >> 1) & 3)) << 3;

  for (int t = 0; t < nt; ++t) {
    const int s = t + 2;
    const int st = t % 3;
    __builtin_amdgcn_sched_barrier(0);
    if      (s < nt)  { const int ss = s % 3; STAGEL(s, ss); WAITVM(6); }
    else if (s == nt) { WAITVM(3); }
    else              { WAITVM(0); }
    __builtin_amdgcn_sched_barrier(0);
    __builtin_amdgcn_s_barrier();
    __builtin_amdgcn_sched_barrier(0);

    const unsigned short* Ac = Abase + st*4096;
    const unsigned short* Bc = Bbase + st*8192;
    bf16x8 af[4], bfr[4];
    #pragma unroll
    for (int m = 0; m < 4; m++)
      af[m] = *reinterpret_cast<const bf16x8*>(&Ac[(wm*64 + m*16 + lr) * 32 + slotx]);
    #pragma unroll
    for (int n = 0; n < 4; n++)
      bfr[n] = *reinterpret_cast<const bf16x8*>(&Bc[(wn*64 + n*16 + lr) * 32 + slotx]);
    __builtin_amdgcn_s_setprio(1);
    #pragma unroll
    for (int m = 0; m < 4; m++)
      #pragma unroll
      for (int n = 0; n < 4; n++)
        acc[m][n] = __builtin_amdgcn_mfma_f32_16x16x32_bf16(af[m], bfr[n], acc[m][n], 0, 0, 0);
    __builtin_amdgcn_s_setprio(0);
    __builtin_amdgcn_sched_barrier(0);
    __builtin_amdgcn_s_barrier();
  }
#undef STAGEL

  #pragma unroll
  for (int n = 0; n < 4; n++) {
    const float bv = bias ? bias[bn + wn*64 + n*16 + lr] : 0.f;
    #pragma unroll
    for (int m = 0; m < 4; m++)
      #pragma unroll
      for (int r = 0; r < 4; r++)
        acc[m][n][r] += bv;
  }

  if (ms) {
    // per-wave (row, 64-col-span) partials -> LDS
    #pragma unroll
    for (int m = 0; m < 4; m++) {
      float vmax[4] = {NEGBIG, NEGBIG, NEGBIG, NEGBIG};
      #pragma unroll
      for (int n = 0; n < 4; n++)
        #pragma unroll
        for (int r = 0; r < 4; r++)
          vmax[r] = fmaxf(vmax[r], acc[m][n][r]);
      #pragma unroll
      for (int r = 0; r < 4; r++) {
        #pragma unroll
        for (int off = 1; off < 16; off <<= 1)
          vmax[r] = fmaxf(vmax[r], __shfl_xor(vmax[r], off));
      }
      float vsum[4] = {0.f, 0.f, 0.f, 0.f};
      #pragma unroll
      for (int n = 0; n < 4; n++)
        #pragma unroll
        for (int r = 0; r < 4; r++)
          vsum[r] += __expf(acc[m][n][r] - vmax[r]);
      #pragma unroll
      for (int r = 0; r < 4; r++) {
        #pragma unroll
        for (int off = 1; off < 16; off <<= 1)
          vsum[r] += __shfl_xor(vsum[r], off);
      }
      if (lr == 0) {
        #pragma unroll
        for (int r = 0; r < 4; r++)
          msL[(wm*64 + m*16 + g*4 + r) * 4 + wn] = make_float2(vmax[r], vsum[r]);
      }
    }
    __syncthreads();
    if (tid < 128) {
      float M = NEGBIG, S = 0.f;
      #pragma unroll
      for (int w = 0; w < 4; w++) {
        float2 e = msL[tid * 4 + w];
        float Mn = fmaxf(M, e.x);
        S = S * __expf(M - Mn) + e.y * __expf(e.x - Mn);
        M = Mn;
      }
      ms[(size_t)(bm + tid) * npan + bnp] = make_float2(M, S);
    }
  }

  #pragma unroll
  for (int c = 0; c < 2; ++c) {
    __syncthreads();
    if (wm == c) {
      #pragma unroll
      for (int m = 0; m < 4; m++)
        #pragma unroll
        for (int n = 0; n < 4; n++)
          #pragma unroll
          for (int r = 0; r < 4; r++)
            E[(m*16 + g*4 + r) * 260 + wn*64 + n*16 + lr] = acc[m][n][r];
    }
    __syncthreads();
    #pragma unroll
    for (int rep = 0; rep < 8; rep++) {
      const int row = rep*8 + wv;
      f32x4 v = *reinterpret_cast<const f32x4*>(&E[row*260 + lane*4]);
      __builtin_nontemporal_store(
          v, reinterpret_cast<f32x4*>(&outF[(size_t)(bm + c*64 + row) * ldc + bn + lane*4]));
    }
  }
}

// ---------------------------------------------------------------- pipelined bf16 MFMA GEMM
// BMxBN tile, BK=64 per sync, 2 LDS buffers, depth-1 counted vmcnt, XOR swizzle.
// resid (optional) is bf16; outputs via outF (fp32) or outH (bf16).
template<int BM_T, int BN_T, int WM, int WN>
__global__ __launch_bounds__(256) void gemm_pipe(
    const unsigned short* __restrict__ A,
    const unsigned short* __restrict__ Bt,
    int K,
    const float* __restrict__ bias,
    const unsigned short* __restrict__ resid,
    float* __restrict__ outF,
    unsigned short* __restrict__ outH,
    int ldc, int relu)
{
  constexpr int BKp = 64;
  constexpr int ALOADS = BM_T / 32;
  constexpr int BLOADS = BN_T / 32;
  constexpr int LOADS  = ALOADS + BLOADS;
  constexpr int MR = BM_T / (16 * WM);
  constexpr int NR = BN_T / (16 * WN);
  __shared__ __align__(16) unsigned short As[2][BM_T * BKp];
  __shared__ __align__(16) unsigned short Bs[2][BN_T * BKp];

  const int tid = threadIdx.x;
  const int lane = tid & 63, wv = tid >> 6;
  const int lr = lane & 15, g = lane >> 4;

  const int gx = gridDim.x;
  int id = blockIdx.y * gx + blockIdx.x;
  const int nwg = gx * gridDim.y;
  if ((nwg & 7) == 0) {
    const int q = nwg >> 3;
    id = (id & 7) * q + (id >> 3);
  }
  const int bm = (id % gx) * BM_T, bn = (id / gx) * BN_T;

  const int m0w = (wv / WN) * (BM_T / WM);
  const int n0w = (wv % WN) * (BN_T / WN);

  const int srow = wv*8 + (lane >> 3);
  const int schk = (lane & 7) ^ (lane >> 3);
  const unsigned short* Ab = A  + (size_t)(bm + srow) * K + schk * 8;
  const unsigned short* Bb = Bt + (size_t)(bn + srow) * K + schk * 8;

#define STAGEP(s, sl)                                                           \
  { const int kof_ = (s) * BKp;                                                 \
    _Pragma("unroll")                                                           \
    for (int i_ = 0; i_ < ALOADS; ++i_)                                         \
      gl_lds16(Ab + (size_t)(i_*32)*K + kof_, As[sl] + i_*2048 + wv*512);       \
    _Pragma("unroll")                                                           \
    for (int i_ = 0; i_ < BLOADS; ++i_)                                         \
      gl_lds16(Bb + (size_t)(i_*32)*K + kof_, Bs[sl] + i_*2048 + wv*512); }

  f32x4 acc[MR][NR];
  #pragma unroll
  for (int m = 0; m < MR; m++)
    #pragma unroll
    for (int n = 0; n < NR; n++)
      acc[m][n] = (f32x4){0.f, 0.f, 0.f, 0.f};

  const int nt = K >> 6;
  STAGEP(0, 0);

  for (int t = 0; t < nt; ++t) {
    __builtin_amdgcn_sched_barrier(0);
    if (t + 1 < nt) {
      STAGEP(t + 1, (t + 1) & 1);
      if constexpr (LOADS == 4) WAITVM(4);
      else if constexpr (LOADS == 6) WAITVM(6);
      else WAITVM(8);
    } else {
      WAITVM(0);
    }
    __builtin_amdgcn_sched_barrier(0);
    __builtin_amdgcn_s_barrier();          // tile t visible to all waves
    __builtin_amdgcn_sched_barrier(0);

    const unsigned short* Ac = As[t & 1];
    const unsigned short* Bc = Bs[t & 1];
    #pragma unroll
    for (int kk = 0; kk < 2; ++kk) {
      const int sl = ((kk*4 + g) ^ (lr & 7)) << 3;
      bf16x8 af[MR], bfr[NR];
      #pragma unroll
      for (int m = 0; m < MR; m++)
        af[m] = *reinterpret_cast<const bf16x8*>(&Ac[(m0w + m*16 + lr) * BKp + sl]);
      #pragma unroll
      for (int n = 0; n < NR; n++)
        bfr[n] = *reinterpret_cast<const bf16x8*>(&Bc[(n0w + n*16 + lr) * BKp + sl]);
      __builtin_amdgcn_s_setprio(1);
      #pragma unroll
      for (int m = 0; m < MR; m++)
        #pragma unroll
        for (int n = 0; n < NR; n++)
          acc[m][n] = __builtin_amdgcn_mfma_f32_16x16x32_bf16(af[m], bfr[n], acc[m][n], 0, 0, 0);
      __builtin_amdgcn_s_setprio(0);
    }
    __builtin_amdgcn_sched_barrier(0);
    __builtin_amdgcn_s_barrier();          // all waves done reading buf[t&1]
  }
#undef STAGEP

  const int cr = g * 4;
  const int cc = lr;
  #pragma unroll
  for (int m = 0; m < MR; m++) {
    #pragma unroll
    for (int n = 0; n < NR; n++) {
      int row = bm + m0w + m*16 + cr;
      int col = bn + n0w + n*16 + cc;
      f32x4 a = acc[m][n];
      #pragma unroll
      for (int r = 0; r < 4; r++) {
        float v = a[r];
        if (bias)  v += bias[col];
        if (resid) v += bf2f(resid[(size_t)(row + r) * ldc + col]);
        if (relu)  v = fmaxf(v, 0.f);
        if (outF)  outF[(size_t)(row + r) * ldc + col] = v;
        if (outH)  outH[(size_t)(row + r) * ldc + col] = f2bf(v);
      }
    }
  }
}

// ---------------------------------------------------------------- MFMA flash attention (bf16 in/out)
// 128 q-rows per block, 8 waves. Work-split scheduling: tasks qb<8 run whole;
// qb>=8 split KV range into 2 halves (flash-decoding), merged by attn_merge.
// Split partials stored in bf16 (halves Opart traffic).
__global__ __launch_bounds__(512) void attn_mfma(
    const unsigned short* __restrict__ qkv,  // bf16 [B*T][1536]
    unsigned short* __restrict__ o,          // bf16 [B*T][512]
    unsigned short* __restrict__ Opart,      // [128 blk][2][128][64] bf16
    float2* __restrict__ ml)                 // [128 blk][2][128]
{
  __shared__ __align__(16) unsigned short Ks[2][64*64];
  __shared__ __align__(16) unsigned short Vt[2][64*64];
  __shared__ __align__(16) unsigned short Ps[8][16*64];

  static const unsigned char ord[24] = {7,22,23,20,21,6,18,19,16,17,5,14,15,12,13,4,10,11,8,9,3,2,1,0};
  const int slot = ord[blockIdx.x];
  const int bh = blockIdx.y, bb = bh >> 3, hh = bh & 7;
  int qb, it0, itn, half;
  if (slot < 8) { qb = slot; it0 = 0; itn = 2*qb + 2; half = -1; }
  else { const int p = slot - 8; qb = 8 + (p >> 1); half = p & 1;
         const int nh = qb + 1; it0 = half * nh; itn = nh; }

  const int tid = threadIdx.x, lane = tid & 63, wv = tid >> 6;
  const int lr = lane & 15, g = lane >> 4;

  const unsigned short* qp = qkv + ((size_t)(bb*T_ + qb*128))*1536 + hh*64;
  const unsigned short* kp = qkv + ((size_t)bb*T_)*1536 + 512  + hh*64;
  const unsigned short* vp = qkv + ((size_t)bb*T_)*1536 + 1024 + hh*64;

  bf16x8 qf[2];
  qf[0] = *reinterpret_cast<const bf16x8*>(qp + (size_t)(wv*16 + lr)*1536 + g*8);
  qf[1] = *reinterpret_cast<const bf16x8*>(qp + (size_t)(wv*16 + lr)*1536 + 32 + g*8);

  const int krow = wv*8 + (lane >> 3);
  const int khb  = (lane & 7) ^ (lane >> 3);

#define STAGE_K(s0_, buf_)                                           \
  gl_lds16(kp + (size_t)((s0_)*64 + krow)*1536 + khb*8,              \
           (void*)(Ks[buf_] + wv*512));

  uint4 uvr;
#define LOAD_V(s0_)                                                  \
  uvr = *reinterpret_cast<const uint4*>(                             \
      vp + (size_t)((s0_)*64 + lane)*1536 + wv*8);

  f32x4 ov[4];
  #pragma unroll
  for (int n = 0; n < 4; n++) ov[n] = (f32x4){0.f, 0.f, 0.f, 0.f};
  float mrow[4] = {NEGBIG, NEGBIG, NEGBIG, NEGBIG};
  float lrow[4] = {0.f, 0.f, 0.f, 0.f};

  STAGE_K(it0, 0);
  LOAD_V(it0);

  for (int ii = 0; ii < itn; ++ii) {
    const int s0 = it0 + ii;
    const int cur = ii & 1;
    WAITVM(0);                         // K(cur) in LDS, V(cur) in regs
    __builtin_amdgcn_sched_barrier(0);
    {                                  // write V(cur) regs -> Vt[cur] (swizzled)
      union { uint4 v; unsigned short e[8]; } uv; uv.v = uvr;
      #pragma unroll
      for (int j = 0; j < 8; j++)
        Vt[cur][(wv*8 + j)*64 + (((lane >> 3) ^ j) << 3) + (lane & 7)] = uv.e[j];
    }
    WAITLG0;
    __builtin_amdgcn_sched_barrier(0);
    __builtin_amdgcn_s_barrier();      // K/V tile cur visible to all waves
    __builtin_amdgcn_sched_barrier(0);

    if (ii + 1 < itn) {                // async prefetch of next tile
      STAGE_K(s0 + 1, cur ^ 1);
      LOAD_V(s0 + 1);
    }

    // --- S = Q @ K^T
    f32x4 sf[4];
    #pragma unroll
    for (int n = 0; n < 4; n++) sf[n] = (f32x4){0.f, 0.f, 0.f, 0.f};
    __builtin_amdgcn_s_setprio(1);
    #pragma unroll
    for (int kk = 0; kk < 2; kk++) {
      #pragma unroll
      for (int n = 0; n < 4; n++) {
        const bf16x8 kf = *reinterpret_cast<const bf16x8*>(
            &Ks[cur][(n*16 + lr)*64 + (((kk*4 + g) ^ (lr & 7)) << 3)]);
        sf[n] = __builtin_amdgcn_mfma_f32_16x16x32_bf16(qf[kk], kf, sf[n], 0, 0, 0);
      }
    }
    __builtin_amdgcn_s_setprio(0);

    // --- scale + causal mask
    float sv[4][4];
    #pragma unroll
    for (int n = 0; n < 4; n++)
      #pragma unroll
      for (int r = 0; r < 4; r++) {
        const int kvg = s0*64 + n*16 + lr;
        const int qg  = qb*128 + wv*16 + g*4 + r;
        sv[n][r] = (kvg > qg) ? NEGBIG : sf[n][r] * SCALE_;
      }

    float aa[4];
    #pragma unroll
    for (int r = 0; r < 4; r++) {
      float pm = fmaxf(fmaxf(sv[0][r], sv[1][r]), fmaxf(sv[2][r], sv[3][r]));
      pm = fmaxf(pm, __shfl_xor(pm, 1));
      pm = fmaxf(pm, __shfl_xor(pm, 2));
      pm = fmaxf(pm, __shfl_xor(pm, 4));
      pm = fmaxf(pm, __shfl_xor(pm, 8));
      float mn = fmaxf(mrow[r], pm);
      aa[r] = __expf(mrow[r] - mn);
      mrow[r] = mn;
    }
    float rs[4] = {0.f, 0.f, 0.f, 0.f};
    #pragma unroll
    for (int n = 0; n < 4; n++)
      #pragma unroll
      for (int r = 0; r < 4; r++) {
        float p = __expf(sv[n][r] - mrow[r]);
        rs[r] += p;
        Ps[wv][(g*4 + r)*64 + ((((n << 1) + (lr >> 3)) ^ ((g*4 + r) & 7)) << 3) + (lr & 7)] = f2bf(p);
      }
    #pragma unroll
    for (int r = 0; r < 4; r++) {
      float s = rs[r];
      s += __shfl_xor(s, 1); s += __shfl_xor(s, 2);
      s += __shfl_xor(s, 4); s += __shfl_xor(s, 8);
      lrow[r] = lrow[r]*aa[r] + s;
    }
    #pragma unroll
    for (int n = 0; n < 4; n++)
      #pragma unroll
      for (int r = 0; r < 4; r++)
        ov[n][r] *= aa[r];

    // --- O += P @ V
    __builtin_amdgcn_s_setprio(1);
    #pragma unroll
    for (int kk = 0; kk < 2; kk++) {
      const bf16x8 pf = *reinterpret_cast<const bf16x8*>(
          &Ps[wv][lr*64 + (((kk*4 + g) ^ (lr & 7)) << 3)]);
      #pragma unroll
      for (int n = 0; n < 4; n++) {
        const bf16x8 vf = *reinterpret_cast<const bf16x8*>(
            &Vt[cur][(n*16 + lr)*64 + (((kk*4 + g) ^ (lr & 7)) << 3)]);
        ov[n] = __builtin_amdgcn_mfma_f32_16x16x32_bf16(pf, vf, ov[n], 0, 0, 0);
      }
    }
    __builtin_amdgcn_s_setprio(0);
    __builtin_amdgcn_sched_barrier(0);
    __builtin_amdgcn_s_barrier();      // all waves done reading tile cur
  }
#undef STAGE_K
#undef LOAD_V

  if (half < 0) {
    #pragma unroll
    for (int r = 0; r < 4; r++) {
      float inv = 1.0f / lrow[r];
      size_t row = (size_t)(bb*T_ + qb*128 + wv*16 + g*4 + r);
      #pragma unroll
      for (int n = 0; n < 4; n++)
        o[row*D_ + hh*64 + n*16 + lr] = f2bf(ov[n][r] * inv);
    }
  } else {
    const int blk = bh*8 + (qb - 8);
    unsigned short* Od = Opart + ((size_t)blk*2 + half)*128*64;
    #pragma unroll
    for (int r = 0; r < 4; r++) {
      const int rloc = wv*16 + g*4 + r;
      #pragma unroll
      for (int n = 0; n < 4; n++)
        Od[rloc*64 + n*16 + lr] = f2bf(ov[n][r]);
      if (lr == 0)
        ml[((size_t)blk*2 + half)*128 + rloc] = make_float2(mrow[r], lrow[r]);
    }
  }
}

// ---------------------------------------------------------------- attention split-merge (bf16 partials)
__global__ __launch_bounds__(256) void attn_merge(
    const unsigned short* __restrict__ Opart, const float2* __restrict__ ml,
    unsigned short* __restrict__ o)
{
  const int blk = blockIdx.x;              // bh*8 + (qb-8)
  const int bh = blk >> 3, qb = (blk & 7) + 8;
  const int bb = bh >> 3, hh = bh & 7;
  const int tid = threadIdx.x;
  const int row = tid >> 1, ch = (tid & 1) * 32;
  const unsigned short* O0 = Opart + ((size_t)blk*2 + 0)*128*64;
  const unsigned short* O1 = Opart + ((size_t)blk*2 + 1)*128*64;
  const float2 a = ml[(size_t)blk*2*128 + row];
  const float2 b = ml[((size_t)blk*2 + 1)*128 + row];
  const float M  = fmaxf(a.x, b.x);
  const float e0 = __expf(a.x - M), e1 = __expf(b.x - M);
  const float inv = 1.0f / (a.y*e0 + b.y*e1);
  unsigned short* orow = o + ((size_t)(bb*T_ + qb*128 + row))*D_ + hh*64 + ch;
  #pragma unroll
  for (int c = 0; c < 32; c += 4) {
    ushort4 u0 = *reinterpret_cast<const ushort4*>(&O0[row*64 + ch + c]);
    ushort4 u1 = *reinterpret_cast<const ushort4*>(&O1[row*64 + ch + c]);
    ushort4 pk;
    pk.x = f2bf((bf2f(u0.x)*e0 + bf2f(u1.x)*e1) * inv);
    pk.y = f2bf((bf2f(u0.y)*e0 + bf2f(u1.y)*e1) * inv);
    pk.z = f2bf((bf2f(u0.z)*e0 + bf2f(u1.z)*e1) * inv);
    pk.w = f2bf((bf2f(u0.w)*e0 + bf2f(u1.w)*e1) * inv);
    *reinterpret_cast<ushort4*>(&orow[c]) = pk;
  }
}

// ---------------------------------------------------------------- loss: merge per-panel partials
__global__ __launch_bounds__(256) void loss_merge_kernel(
    const float2* __restrict__ ms, const float* __restrict__ logits,
    const int* __restrict__ labels, float* __restrict__ rowloss, int npan)
{
  const int tid = threadIdx.x, lane = tid & 63, wid = tid >> 6;
  const int row = blockIdx.x * 4 + wid;
  float M = NEGBIG, S = 0.f;
  const float2* p = ms + (size_t)row * npan;
  for (int i = lane; i < npan; i += 64) {
    float2 e = p[i];
    float Mn = fmaxf(M, e.x);
    S = S * __expf(M - Mn) + e.y * __expf(e.x - Mn);
    M = Mn;
  }
  #pragma unroll
  for (int off = 1; off < 64; off <<= 1) {
    float Mo = __shfl_xor(M, off), So = __shfl_xor(S, off);
    float Mn = fmaxf(M, Mo);
    S = S * __expf(M - Mn) + So * __expf(Mo - Mn);
    M = Mn;
  }
  if (lane == 0)
    rowloss[row] = logits[(size_t)row * V_ + labels[row]] - M - logf(S);
}

__global__ __launch_bounds__(256) void loss_final_kernel(
    const float* __restrict__ rowloss, float* __restrict__ out)
{
  __shared__ float red[4];
  const int tid = threadIdx.x, lane = tid & 63, wid = tid >> 6;
  float s = 0.f;
  for (int i = tid; i < BT_; i += 256) s += rowloss[i];
  #pragma unroll
  for (int off = 1; off < 64; off <<= 1) s += __shfl_xor(s, off);
  if (lane == 0) red[wid] = s;
  __syncthreads();
  if (tid == 0) out[0] = -(red[0] + red[1] + red[2] + red[3]) * (1.0f / BT_);
}

// ---------------------------------------------------------------- launch
extern "C" void kernel_launch(void* const* d_in, const int* in_sizes, int n_in,
                              void* d_out, int out_size, void* d_ws, size_t ws_size,
                              hipStream_t stream)
{
  (void)in_sizes; (void)n_in; (void)out_size; (void)ws_size;
  const int*   ids    = (const int*)d_in[0];
  const int*   labels = (const int*)d_in[1];
  const float* tok    = (const float*)d_in[2];
  const float* pos    = (const float*)d_in[3];
  const float* Wq     = (const float*)d_in[4];
  const float* Wk     = (const float*)d_in[5];
  const float* Wv     = (const float*)d_in[6];
  const float* Wo     = (const float*)d_in[7];
  const float* bo     = (const float*)d_in[8];
  const float* ln1g   = (const float*)d_in[9];
  const float* ln1b   = (const float*)d_in[10];
  const float* ln2g   = (const float*)d_in[11];
  const float* ln2b   = (const float*)d_in[12];
  const float* W1     = (const float*)d_in[13];
  const float* b1     = (const float*)d_in[14];
  const float* W2     = (const float*)d_in[15];
  const float* b2     = (const float*)d_in[16];
  const float* lnfg   = (const float*)d_in[17];
  const float* lnfb   = (const float*)d_in[18];
  const float* Wp     = (const float*)d_in[19];
  const float* bp     = (const float*)d_in[20];

  float* out = (float*)d_out;
  char* base = (char*)d_ws;
  unsigned short* x       = (unsigned short*)(base + 0);        //  4,194,304 (bf16 residual)
  unsigned short* xn      = (unsigned short*)(base + 8388608);  //  4,194,304
  float*          rowloss = (float*)(base + 12582912);          //     16,384
  unsigned short* WqkvT   = (unsigned short*)(base + 12599296); //  6,291,456
  unsigned short* W1T     = (unsigned short*)(base + 18890752); //  8,388,608
  unsigned short* W2T     = (unsigned short*)(base + 27279360); //  8,388,608
  unsigned short* WoT     = (unsigned short*)(base + 35667968); //  2,097,152
  unsigned short* qkvh    = (unsigned short*)(base + 37765120); // 12,582,912
  unsigned short* ob      = (unsigned short*)(base + 50348032); //  4,194,304
  unsigned short* h1      = (unsigned short*)(base + 54542336); // 16,777,216
  unsigned short* Opart   = (unsigned short*)(base + 54542336); //  4,194,304 (alias h1: dead during attn)
  float2*         mlbuf   = (float2*)(base + 62930944);         //    262,144 (alias h1 upper half)
  unsigned short* WpT     = (unsigned short*)(base + 37765120); // 32,768,000 (alias: dead at logits time)
  float2*         msbuf   = (float2*)(base + 12599296);         //  4,096,000 (alias: weight-T region, dead at logits time)

  embed_kernel<<<BT_ * D_ / 8 / 256, 256, 0, stream>>>(ids, tok, pos, x);

  qkvw_transpose<<<dim3(16, 2, 96), 256, 0, stream>>>(Wq, Wk, Wv, WqkvT);
  transpose_cast<<<dim3(16, 64, 4), 256, 0, stream>>>(W1, W1T, 2048, 512, 1048576, 1048576);
  transpose_cast<<<dim3(64, 16, 4), 256, 0, stream>>>(W2, W2T, 512, 2048, 1048576, 1048576);
  transpose_cast<<<dim3(16, 16, 4), 256, 0, stream>>>(Wo, WoT, 512, 512, 262144, 262144);

  for (int l = 0; l < NL_; l++) {
    ln_kernel<<<BT_ / 4, 256, 0, stream>>>(x, ln1g + l * D_, ln1b + l * D_, xn);
    gemm_pipe<64,64,2,2><<<dim3(64, 24), 256, 0, stream>>>(
        xn, WqkvT + (size_t)l * 1536 * 512, 512, nullptr, nullptr, nullptr, qkvh, 1536, 0);
    attn_mfma<<<dim3(24, B_ * H_), 512, 0, stream>>>(qkvh, ob, Opart, mlbuf);
    attn_merge<<<128, 256, 0, stream>>>(Opart, mlbuf, ob);
    gemm_pipe<64,64,2,2><<<dim3(64, 8), 256, 0, stream>>>(
        ob, WoT + (size_t)l * 512 * 512, 512, bo + l * D_, x, nullptr, x, D_, 0);
    ln_kernel<<<BT_ / 4, 256, 0, stream>>>(x, ln2g + l * D_, ln2b + l * D_, xn);
    gemm_pipe<64,64,2,2><<<dim3(64, 32), 256, 0, stream>>>(
        xn, W1T + (size_t)l * 2048 * 512, 512, b1 + l * 4 * D_, nullptr, nullptr, h1, 4 * D_, 1);
    gemm_pipe<64,64,2,2><<<dim3(64, 8), 256, 0, stream>>>(
        h1, W2T + (size_t)l * 512 * 2048, 2048, b2 + l * D_, x, nullptr, x, D_, 0);
  }

  transpose_cast<<<dim3(16, 1000, 1), 256, 0, stream>>>(Wp, WpT, 32000, 512, 0, 0);
  ln_kernel<<<BT_ / 4, 256, 0, stream>>>(x, lnfg, lnfb, xn);
  gemm_logits<<<dim3(32, 125), 512, 0, stream>>>(
      xn, WpT, 512, bp, out, V_, msbuf, 125);

  loss_merge_kernel<<<BT_ / 4, 256, 0, stream>>>(msbuf, out, labels, rowloss, 125);
  loss_final_kernel<<<1, 256, 0, stream>>>(rowloss, out + (size_t)BT_ * V_);
}

// Round 21
// 874.532 us; speedup vs baseline: 1.0530x; 1.0041x over previous
//
#include <hip/hip_runtime.h>
#include <hip/hip_bf16.h>
#include <math.h>

#define B_ 2
#define T_ 2048
#define D_ 512
#define H_ 8
#define NL_ 4
#define V_ 32000
#define HD_ 64
#define BT_ (B_*T_)
#define EPS_ 1e-5f
#define SCALE_ 0.04419417382415922f  /* 1/sqrt(512) — source scales by D, not HD */
#define NEGBIG -1e30f

typedef __bf16 bf16x8 __attribute__((ext_vector_type(8)));
typedef float  f32x4  __attribute__((ext_vector_type(4)));

__device__ __forceinline__ unsigned short f2bf(float f) {
  union { float f; unsigned u; } v; v.f = f;
  unsigned r = v.u + 0x7fff + ((v.u >> 16) & 1);
  return (unsigned short)(r >> 16);
}
__device__ __forceinline__ float bf2f(unsigned short h) {
  union { unsigned u; float f; } c; c.u = ((unsigned)h) << 16; return c.f;
}

__device__ __forceinline__ void gl_lds16(const void* g, void* l) {
  __builtin_amdgcn_global_load_lds(
      (const __attribute__((address_space(1))) void*)g,
      (__attribute__((address_space(3))) void*)l, 16, 0, 0);
}

#define WAITVM(n) asm volatile("s_waitcnt vmcnt(" #n ")" ::: "memory")
#define WAITLG0   asm volatile("s_waitcnt lgkmcnt(0)" ::: "memory")

// ---------------------------------------------------------------- embed -> bf16 x
__global__ __launch_bounds__(256) void embed_kernel(
    const int* __restrict__ ids, const float* __restrict__ tok,
    const float* __restrict__ pos, unsigned short* __restrict__ x)
{
  int i = blockIdx.x * 256 + threadIdx.x;   // chunk of 8 elems
  int c8 = i & 63;
  int bt = i >> 6;
  int t  = bt & (T_ - 1);
  const float4* tr = reinterpret_cast<const float4*>(tok + (size_t)ids[bt] * D_ + c8*8);
  const float4* pr = reinterpret_cast<const float4*>(pos + (size_t)t * D_ + c8*8);
  float4 a0 = tr[0], a1 = tr[1], p0 = pr[0], p1 = pr[1];
  ushort4 o0, o1;
  o0.x = f2bf(a0.x + p0.x); o0.y = f2bf(a0.y + p0.y);
  o0.z = f2bf(a0.z + p0.z); o0.w = f2bf(a0.w + p0.w);
  o1.x = f2bf(a1.x + p1.x); o1.y = f2bf(a1.y + p1.y);
  o1.z = f2bf(a1.z + p1.z); o1.w = f2bf(a1.w + p1.w);
  unsigned short* orow = x + (size_t)bt * D_ + c8*8;
  *reinterpret_cast<ushort4*>(orow)     = o0;
  *reinterpret_cast<ushort4*>(orow + 4) = o1;
}

// ---------------------------------------------------------------- layernorm (bf16 in) -> bf16 out
__global__ __launch_bounds__(256) void ln_kernel(
    const unsigned short* __restrict__ x, const float* __restrict__ g,
    const float* __restrict__ b, unsigned short* __restrict__ out)
{
  int row  = blockIdx.x * 4 + (threadIdx.x >> 6);
  int lane = threadIdx.x & 63;
  const unsigned short* xr = x + (size_t)row * D_;
  ushort4 u0 = *reinterpret_cast<const ushort4*>(xr + lane*4);
  ushort4 u1 = *reinterpret_cast<const ushort4*>(xr + 256 + lane*4);
  float v0x = bf2f(u0.x), v0y = bf2f(u0.y), v0z = bf2f(u0.z), v0w = bf2f(u0.w);
  float v1x = bf2f(u1.x), v1y = bf2f(u1.y), v1z = bf2f(u1.z), v1w = bf2f(u1.w);
  float s = v0x + v0y + v0z + v0w + v1x + v1y + v1z + v1w;
  float q = v0x*v0x + v0y*v0y + v0z*v0z + v0w*v0w
          + v1x*v1x + v1y*v1y + v1z*v1z + v1w*v1w;
  #pragma unroll
  for (int off = 1; off < 64; off <<= 1) {
    s += __shfl_xor(s, off);
    q += __shfl_xor(q, off);
  }
  float mean = s * (1.0f / D_);
  float var  = q * (1.0f / D_) - mean * mean;
  float rs   = rsqrtf(var + EPS_);
  const float4* g4 = reinterpret_cast<const float4*>(g);
  const float4* b4 = reinterpret_cast<const float4*>(b);
  float4 gv0 = g4[lane], gv1 = g4[lane + 64];
  float4 bv0 = b4[lane], bv1 = b4[lane + 64];
  ushort4 p0, p1;
  p0.x = f2bf((v0x - mean) * rs * gv0.x + bv0.x);
  p0.y = f2bf((v0y - mean) * rs * gv0.y + bv0.y);
  p0.z = f2bf((v0z - mean) * rs * gv0.z + bv0.z);
  p0.w = f2bf((v0w - mean) * rs * gv0.w + bv0.w);
  p1.x = f2bf((v1x - mean) * rs * gv1.x + bv1.x);
  p1.y = f2bf((v1y - mean) * rs * gv1.y + bv1.y);
  p1.z = f2bf((v1z - mean) * rs * gv1.z + bv1.z);
  p1.w = f2bf((v1w - mean) * rs * gv1.w + bv1.w);
  unsigned short* orow = out + (size_t)row * D_;
  *reinterpret_cast<ushort4*>(orow + lane * 4)       = p0;
  *reinterpret_cast<ushort4*>(orow + 256 + lane * 4) = p1;
}

// ---------------------------------------------------------------- transpose+cast fp32 [R][C] -> bf16 [C][R]
__global__ __launch_bounds__(256) void transpose_cast(
    const float* __restrict__ src, unsigned short* __restrict__ dst,
    int C, int R, long sstride, long dstride)
{
  src += (size_t)blockIdx.z * sstride;
  dst += (size_t)blockIdx.z * dstride;
  __shared__ float t[32][33];
  int r0 = blockIdx.x * 32, c0 = blockIdx.y * 32;
  int tx = threadIdx.x & 31, ty = threadIdx.x >> 5;
  #pragma unroll
  for (int i = 0; i < 4; i++)
    t[ty + i*8][tx] = src[(size_t)(r0 + ty + i*8) * C + c0 + tx];
  __syncthreads();
  #pragma unroll
  for (int i = 0; i < 4; i++)
    dst[(size_t)(c0 + ty + i*8) * R + r0 + tx] = f2bf(t[tx][ty + i*8]);
}

// WqkvT[l][mat*512 + h*64 + e][d] = W{q,k,v}[l][h][d][e]
__global__ __launch_bounds__(256) void qkvw_transpose(
    const float* __restrict__ Wq, const float* __restrict__ Wk,
    const float* __restrict__ Wv, unsigned short* __restrict__ dst)
{
  int z = blockIdx.z; int l = z / 24; int rem = z % 24; int mat = rem >> 3; int h = rem & 7;
  const float* W = (mat == 0 ? Wq : (mat == 1 ? Wk : Wv)) + ((size_t)(l * 8 + h)) * D_ * HD_;
  unsigned short* d = dst + ((size_t)l * 1536 + mat * 512 + h * 64) * D_;
  __shared__ float t[32][33];
  int d0 = blockIdx.x * 32, e0 = blockIdx.y * 32;
  int tx = threadIdx.x & 31, ty = threadIdx.x >> 5;
  #pragma unroll
  for (int i = 0; i < 4; i++)
    t[ty + i*8][tx] = W[(size_t)(d0 + ty + i*8) * HD_ + e0 + tx];
  __syncthreads();
  #pragma unroll
  for (int i = 0; i < 4; i++)
    d[(size_t)(e0 + ty + i*8) * D_ + d0 + tx] = f2bf(t[tx][ty + i*8]);
}

// ---------------------------------------------------------------- logits GEMM: 128x256 tile
// 2 LDS buffers, depth-1 counted vmcnt (48 KB LDS -> 3 blocks/CU). Fused
// per-(row,panel) softmax partials (LDS-merged) + 4-chunk LDS-transposed
// nontemporal dwordx4 fp32 stores (32-row chunks keep LDS under 48 KB).
__global__ __launch_bounds__(512, 4) void gemm_logits(
    const unsigned short* __restrict__ A,
    const unsigned short* __restrict__ Bt,
    int K, const float* __restrict__ bias,
    float* __restrict__ outF, int ldc,
    float2* __restrict__ ms, int npan)
{
  __shared__ __align__(16) char smem[49152];
  unsigned short* Abase = (unsigned short*)smem;            // 2 x 4096 shorts (A: 128x32)
  unsigned short* Bbase = (unsigned short*)(smem + 16384);  // 2 x 8192 shorts (B: 256x32)
  float* E = (float*)smem;                                  // 32 x 260 fp32 epilogue chunks
  float2* msL = (float2*)smem;                              // 128 x 4 partials

  const int tid = threadIdx.x;
  const int lane = tid & 63;
  const int lr = lane & 15, g = lane >> 4;
  const int wv = tid >> 6, wm = wv >> 2, wn = wv & 3;

  const int gx = gridDim.x;
  int id = blockIdx.y * gx + blockIdx.x;
  const int nwg = gx * gridDim.y;
  if ((nwg & 7) == 0) { const int q = nwg >> 3; id = (id & 7) * q + (id >> 3); }
  const int bm = (id % gx) * 128, bn = (id / gx) * 256, bnp = id / gx;

  const int schk = (lane & 3) ^ ((lane >> 3) & 3);
  const unsigned short* Ab = A  + (size_t)(bm + wv*16 + (lane >> 2)) * K + schk * 8;
  const unsigned short* Bb = Bt + (size_t)(bn + wv*16 + (lane >> 2)) * K + schk * 8;

#define STAGEL(s, sl)                                                       \
  { const int kof_ = (s) * 32;                                              \
    gl_lds16(Ab + kof_,                 Abase + (sl)*4096 + wv*512);        \
    gl_lds16(Bb + kof_,                 Bbase + (sl)*8192 + wv*512);        \
    gl_lds16(Bb + (size_t)128*K + kof_, Bbase + (sl)*8192 + 4096 + wv*512); }

  f32x4 acc[4][4];
  #pragma unroll
  for (int m = 0; m < 4; m++)
    #pragma unroll
    for (int n = 0; n < 4; n++)
      acc[m][n] = (f32x4){0.f, 0.f, 0.f, 0.f};

  const int nt = K >> 5;
  STAGEL(0, 0);

  const int slotx = (g ^ ((lr >> 1) & 3)) << 3;

  for (int t = 0; t < nt; ++t) {
    __builtin_amdgcn_sched_barrier(0);
    if (t + 1 < nt) { STAGEL(t + 1, (t + 1) & 1); WAITVM(3); }
    else            { WAITVM(0); }
    __builtin_amdgcn_sched_barrier(0);
    __builtin_amdgcn_s_barrier();
    __builtin_amdgcn_sched_barrier(0);

    const unsigned short* Ac = Abase + (t & 1)*4096;
    const unsigned short* Bc = Bbase + (t & 1)*8192;
    bf16x8 af[4], bfr[4];
    #pragma unroll
    for (int m = 0; m < 4; m++)
      af[m] = *reinterpret_cast<const bf16x8*>(&Ac[(wm*64 + m*16 + lr) * 32 + slotx]);
    #pragma unroll
    for (int n = 0; n < 4; n++)
      bfr[n] = *reinterpret_cast<const bf16x8*>(&Bc[(wn*64 + n*16 + lr) * 32 + slotx]);
    __builtin_amdgcn_s_setprio(1);
    #pragma unroll
    for (int m = 0; m < 4; m++)
      #pragma unroll
      for (int n = 0; n < 4; n++)
        acc[m][n] = __builtin_amdgcn_mfma_f32_16x16x32_bf16(af[m], bfr[n], acc[m][n], 0, 0, 0);
    __builtin_amdgcn_s_setprio(0);
    __builtin_amdgcn_sched_barrier(0);
    __builtin_amdgcn_s_barrier();
  }
#undef STAGEL

  #pragma unroll
  for (int n = 0; n < 4; n++) {
    const float bv = bias ? bias[bn + wn*64 + n*16 + lr] : 0.f;
    #pragma unroll
    for (int m = 0; m < 4; m++)
      #pragma unroll
      for (int r = 0; r < 4; r++)
        acc[m][n][r] += bv;
  }

  if (ms) {
    // per-wave (row, 64-col-span) partials -> LDS
    #pragma unroll
    for (int m = 0; m < 4; m++) {
      float vmax[4] = {NEGBIG, NEGBIG, NEGBIG, NEGBIG};
      #pragma unroll
      for (int n = 0; n < 4; n++)
        #pragma unroll
        for (int r = 0; r < 4; r++)
          vmax[r] = fmaxf(vmax[r], acc[m][n][r]);
      #pragma unroll
      for (int r = 0; r < 4; r++) {
        #pragma unroll
        for (int off = 1; off < 16; off <<= 1)
          vmax[r] = fmaxf(vmax[r], __shfl_xor(vmax[r], off));
      }
      float vsum[4] = {0.f, 0.f, 0.f, 0.f};
      #pragma unroll
      for (int n = 0; n < 4; n++)
        #pragma unroll
        for (int r = 0; r < 4; r++)
          vsum[r] += __expf(acc[m][n][r] - vmax[r]);
      #pragma unroll
      for (int r = 0; r < 4; r++) {
        #pragma unroll
        for (int off = 1; off < 16; off <<= 1)
          vsum[r] += __shfl_xor(vsum[r], off);
      }
      if (lr == 0) {
        #pragma unroll
        for (int r = 0; r < 4; r++)
          msL[(wm*64 + m*16 + g*4 + r) * 4 + wn] = make_float2(vmax[r], vsum[r]);
      }
    }
    __syncthreads();
    if (tid < 128) {
      float M = NEGBIG, S = 0.f;
      #pragma unroll
      for (int w = 0; w < 4; w++) {
        float2 e = msL[tid * 4 + w];
        float Mn = fmaxf(M, e.x);
        S = S * __expf(M - Mn) + e.y * __expf(e.x - Mn);
        M = Mn;
      }
      ms[(size_t)(bm + tid) * npan + bnp] = make_float2(M, S);
    }
  }

  // ---- transposed fp32 nontemporal stores via LDS, 4 chunks of 32 rows
  #pragma unroll
  for (int c = 0; c < 4; ++c) {
    __syncthreads();
    if (wm == (c >> 1)) {
      const int mb = (c & 1) * 2;
      #pragma unroll
      for (int mm = 0; mm < 2; mm++)
        #pragma unroll
        for (int n = 0; n < 4; n++)
          #pragma unroll
          for (int r = 0; r < 4; r++)
            E[(mm*16 + g*4 + r) * 260 + wn*64 + n*16 + lr] = acc[mb + mm][n][r];
    }
    __syncthreads();
    #pragma unroll
    for (int rep = 0; rep < 4; rep++) {
      const int row = rep*8 + wv;
      f32x4 v = *reinterpret_cast<const f32x4*>(&E[row*260 + lane*4]);
      __builtin_nontemporal_store(
          v, reinterpret_cast<f32x4*>(&outF[(size_t)(bm + c*32 + row) * ldc + bn + lane*4]));
    }
  }
}

// ---------------------------------------------------------------- pipelined bf16 MFMA GEMM
// BMxBN tile, BK=64 per sync, 2 LDS buffers, depth-1 counted vmcnt, XOR swizzle.
// resid (optional) is bf16; outputs via outF (fp32) or outH (bf16).
template<int BM_T, int BN_T, int WM, int WN>
__global__ __launch_bounds__(256) void gemm_pipe(
    const unsigned short* __restrict__ A,
    const unsigned short* __restrict__ Bt,
    int K,
    const float* __restrict__ bias,
    const unsigned short* __restrict__ resid,
    float* __restrict__ outF,
    unsigned short* __restrict__ outH,
    int ldc, int relu)
{
  constexpr int BKp = 64;
  constexpr int ALOADS = BM_T / 32;
  constexpr int BLOADS = BN_T / 32;
  constexpr int LOADS  = ALOADS + BLOADS;
  constexpr int MR = BM_T / (16 * WM);
  constexpr int NR = BN_T / (16 * WN);
  __shared__ __align__(16) unsigned short As[2][BM_T * BKp];
  __shared__ __align__(16) unsigned short Bs[2][BN_T * BKp];

  const int tid = threadIdx.x;
  const int lane = tid & 63, wv = tid >> 6;
  const int lr = lane & 15, g = lane >> 4;

  const int gx = gridDim.x;
  int id = blockIdx.y * gx + blockIdx.x;
  const int nwg = gx * gridDim.y;
  if ((nwg & 7) == 0) {
    const int q = nwg >> 3;
    id = (id & 7) * q + (id >> 3);
  }
  const int bm = (id % gx) * BM_T, bn = (id / gx) * BN_T;

  const int m0w = (wv / WN) * (BM_T / WM);
  const int n0w = (wv % WN) * (BN_T / WN);

  const int srow = wv*8 + (lane >> 3);
  const int schk = (lane & 7) ^ (lane >> 3);
  const unsigned short* Ab = A  + (size_t)(bm + srow) * K + schk * 8;
  const unsigned short* Bb = Bt + (size_t)(bn + srow) * K + schk * 8;

#define STAGEP(s, sl)                                                           \
  { const int kof_ = (s) * BKp;                                                 \
    _Pragma("unroll")                                                           \
    for (int i_ = 0; i_ < ALOADS; ++i_)                                         \
      gl_lds16(Ab + (size_t)(i_*32)*K + kof_, As[sl] + i_*2048 + wv*512);       \
    _Pragma("unroll")                                                           \
    for (int i_ = 0; i_ < BLOADS; ++i_)                                         \
      gl_lds16(Bb + (size_t)(i_*32)*K + kof_, Bs[sl] + i_*2048 + wv*512); }

  f32x4 acc[MR][NR];
  #pragma unroll
  for (int m = 0; m < MR; m++)
    #pragma unroll
    for (int n = 0; n < NR; n++)
      acc[m][n] = (f32x4){0.f, 0.f, 0.f, 0.f};

  const int nt = K >> 6;
  STAGEP(0, 0);

  for (int t = 0; t < nt; ++t) {
    __builtin_amdgcn_sched_barrier(0);
    if (t + 1 < nt) {
      STAGEP(t + 1, (t + 1) & 1);
      if constexpr (LOADS == 4) WAITVM(4);
      else if constexpr (LOADS == 6) WAITVM(6);
      else WAITVM(8);
    } else {
      WAITVM(0);
    }
    __builtin_amdgcn_sched_barrier(0);
    __builtin_amdgcn_s_barrier();          // tile t visible to all waves
    __builtin_amdgcn_sched_barrier(0);

    const unsigned short* Ac = As[t & 1];
    const unsigned short* Bc = Bs[t & 1];
    #pragma unroll
    for (int kk = 0; kk < 2; ++kk) {
      const int sl = ((kk*4 + g) ^ (lr & 7)) << 3;
      bf16x8 af[MR], bfr[NR];
      #pragma unroll
      for (int m = 0; m < MR; m++)
        af[m] = *reinterpret_cast<const bf16x8*>(&Ac[(m0w + m*16 + lr) * BKp + sl]);
      #pragma unroll
      for (int n = 0; n < NR; n++)
        bfr[n] = *reinterpret_cast<const bf16x8*>(&Bc[(n0w + n*16 + lr) * BKp + sl]);
      __builtin_amdgcn_s_setprio(1);
      #pragma unroll
      for (int m = 0; m < MR; m++)
        #pragma unroll
        for (int n = 0; n < NR; n++)
          acc[m][n] = __builtin_amdgcn_mfma_f32_16x16x32_bf16(af[m], bfr[n], acc[m][n], 0, 0, 0);
      __builtin_amdgcn_s_setprio(0);
    }
    __builtin_amdgcn_sched_barrier(0);
    __builtin_amdgcn_s_barrier();          // all waves done reading buf[t&1]
  }
#undef STAGEP

  const int cr = g * 4;
  const int cc = lr;
  #pragma unroll
  for (int m = 0; m < MR; m++) {
    #pragma unroll
    for (int n = 0; n < NR; n++) {
      int row = bm + m0w + m*16 + cr;
      int col = bn + n0w + n*16 + cc;
      f32x4 a = acc[m][n];
      #pragma unroll
      for (int r = 0; r < 4; r++) {
        float v = a[r];
        if (bias)  v += bias[col];
        if (resid) v += bf2f(resid[(size_t)(row + r) * ldc + col]);
        if (relu)  v = fmaxf(v, 0.f);
        if (outF)  outF[(size_t)(row + r) * ldc + col] = v;
        if (outH)  outH[(size_t)(row + r) * ldc + col] = f2bf(v);
      }
    }
  }
}

// ---------------------------------------------------------------- MFMA flash attention (bf16 in/out)
// 128 q-rows per block, 8 waves. Work-split scheduling: tasks qb<8 run whole;
// qb>=8 split KV range into 2 halves (flash-decoding), merged by attn_merge.
// Split partials stored in bf16 (halves Opart traffic).
__global__ __launch_bounds__(512) void attn_mfma(
    const unsigned short* __restrict__ qkv,  // bf16 [B*T][1536]
    unsigned short* __restrict__ o,          // bf16 [B*T][512]
    unsigned short* __restrict__ Opart,      // [128 blk][2][128][64] bf16
    float2* __restrict__ ml)                 // [128 blk][2][128]
{
  __shared__ __align__(16) unsigned short Ks[2][64*64];
  __shared__ __align__(16) unsigned short Vt[2][64*64];
  __shared__ __align__(16) unsigned short Ps[8][16*64];

  static const unsigned char ord[24] = {7,22,23,20,21,6,18,19,16,17,5,14,15,12,13,4,10,11,8,9,3,2,1,0};
  const int slot = ord[blockIdx.x];
  const int bh = blockIdx.y, bb = bh >> 3, hh = bh & 7;
  int qb, it0, itn, half;
  if (slot < 8) { qb = slot; it0 = 0; itn = 2*qb + 2; half = -1; }
  else { const int p = slot - 8; qb = 8 + (p >> 1); half = p & 1;
         const int nh = qb + 1; it0 = half * nh; itn = nh; }

  const int tid = threadIdx.x, lane = tid & 63, wv = tid >> 6;
  const int lr = lane & 15, g = lane >> 4;

  const unsigned short* qp = qkv + ((size_t)(bb*T_ + qb*128))*1536 + hh*64;
  const unsigned short* kp = qkv + ((size_t)bb*T_)*1536 + 512  + hh*64;
  const unsigned short* vp = qkv + ((size_t)bb*T_)*1536 + 1024 + hh*64;

  bf16x8 qf[2];
  qf[0] = *reinterpret_cast<const bf16x8*>(qp + (size_t)(wv*16 + lr)*1536 + g*8);
  qf[1] = *reinterpret_cast<const bf16x8*>(qp + (size_t)(wv*16 + lr)*1536 + 32 + g*8);

  const int krow = wv*8 + (lane >> 3);
  const int khb  = (lane & 7) ^ (lane >> 3);

#define STAGE_K(s0_, buf_)                                           \
  gl_lds16(kp + (size_t)((s0_)*64 + krow)*1536 + khb*8,              \
           (void*)(Ks[buf_] + wv*512));

  uint4 uvr;
#define LOAD_V(s0_)                                                  \
  uvr = *reinterpret_cast<const uint4*>(                             \
      vp + (size_t)((s0_)*64 + lane)*1536 + wv*8);

  f32x4 ov[4];
  #pragma unroll
  for (int n = 0; n < 4; n++) ov[n] = (f32x4){0.f, 0.f, 0.f, 0.f};
  float mrow[4] = {NEGBIG, NEGBIG, NEGBIG, NEGBIG};
  float lrow[4] = {0.f, 0.f, 0.f, 0.f};

  STAGE_K(it0, 0);
  LOAD_V(it0);

  for (int ii = 0; ii < itn; ++ii) {
    const int s0 = it0 + ii;
    const int cur = ii & 1;
    WAITVM(0);                         // K(cur) in LDS, V(cur) in regs
    __builtin_amdgcn_sched_barrier(0);
    {                                  // write V(cur) regs -> Vt[cur] (swizzled)
      union { uint4 v; unsigned short e[8]; } uv; uv.v = uvr;
      #pragma unroll
      for (int j = 0; j < 8; j++)
        Vt[cur][(wv*8 + j)*64 + (((lane >> 3) ^ j) << 3) + (lane & 7)] = uv.e[j];
    }
    WAITLG0;
    __builtin_amdgcn_sched_barrier(0);
    __builtin_amdgcn_s_barrier();      // K/V tile cur visible to all waves
    __builtin_amdgcn_sched_barrier(0);

    if (ii + 1 < itn) {                // async prefetch of next tile
      STAGE_K(s0 + 1, cur ^ 1);
      LOAD_V(s0 + 1);
    }

    // --- S = Q @ K^T
    f32x4 sf[4];
    #pragma unroll
    for (int n = 0; n < 4; n++) sf[n] = (f32x4){0.f, 0.f, 0.f, 0.f};
    __builtin_amdgcn_s_setprio(1);
    #pragma unroll
    for (int kk = 0; kk < 2; kk++) {
      #pragma unroll
      for (int n = 0; n < 4; n++) {
        const bf16x8 kf = *reinterpret_cast<const bf16x8*>(
            &Ks[cur][(n*16 + lr)*64 + (((kk*4 + g) ^ (lr & 7)) << 3)]);
        sf[n] = __builtin_amdgcn_mfma_f32_16x16x32_bf16(qf[kk], kf, sf[n], 0, 0, 0);
      }
    }
    __builtin_amdgcn_s_setprio(0);

    // --- scale + causal mask
    float sv[4][4];
    #pragma unroll
    for (int n = 0; n < 4; n++)
      #pragma unroll
      for (int r = 0; r < 4; r++) {
        const int kvg = s0*64 + n*16 + lr;
        const int qg  = qb*128 + wv*16 + g*4 + r;
        sv[n][r] = (kvg > qg) ? NEGBIG : sf[n][r] * SCALE_;
      }

    float aa[4];
    #pragma unroll
    for (int r = 0; r < 4; r++) {
      float pm = fmaxf(fmaxf(sv[0][r], sv[1][r]), fmaxf(sv[2][r], sv[3][r]));
      pm = fmaxf(pm, __shfl_xor(pm, 1));
      pm = fmaxf(pm, __shfl_xor(pm, 2));
      pm = fmaxf(pm, __shfl_xor(pm, 4));
      pm = fmaxf(pm, __shfl_xor(pm, 8));
      float mn = fmaxf(mrow[r], pm);
      aa[r] = __expf(mrow[r] - mn);
      mrow[r] = mn;
    }
    float rs[4] = {0.f, 0.f, 0.f, 0.f};
    #pragma unroll
    for (int n = 0; n < 4; n++)
      #pragma unroll
      for (int r = 0; r < 4; r++) {
        float p = __expf(sv[n][r] - mrow[r]);
        rs[r] += p;
        Ps[wv][(g*4 + r)*64 + ((((n << 1) + (lr >> 3)) ^ ((g*4 + r) & 7)) << 3) + (lr & 7)] = f2bf(p);
      }
    #pragma unroll
    for (int r = 0; r < 4; r++) {
      float s = rs[r];
      s += __shfl_xor(s, 1); s += __shfl_xor(s, 2);
      s += __shfl_xor(s, 4); s += __shfl_xor(s, 8);
      lrow[r] = lrow[r]*aa[r] + s;
    }
    #pragma unroll
    for (int n = 0; n < 4; n++)
      #pragma unroll
      for (int r = 0; r < 4; r++)
        ov[n][r] *= aa[r];

    // --- O += P @ V
    __builtin_amdgcn_s_setprio(1);
    #pragma unroll
    for (int kk = 0; kk < 2; kk++) {
      const bf16x8 pf = *reinterpret_cast<const bf16x8*>(
          &Ps[wv][lr*64 + (((kk*4 + g) ^ (lr & 7)) << 3)]);
      #pragma unroll
      for (int n = 0; n < 4; n++) {
        const bf16x8 vf = *reinterpret_cast<const bf16x8*>(
            &Vt[cur][(n*16 + lr)*64 + (((kk*4 + g) ^ (lr & 7)) << 3)]);
        ov[n] = __builtin_amdgcn_mfma_f32_16x16x32_bf16(pf, vf, ov[n], 0, 0, 0);
      }
    }
    __builtin_amdgcn_s_setprio(0);
    __builtin_amdgcn_sched_barrier(0);
    __builtin_amdgcn_s_barrier();      // all waves done reading tile cur
  }
#undef STAGE_K
#undef LOAD_V

  if (half < 0) {
    #pragma unroll
    for (int r = 0; r < 4; r++) {
      float inv = 1.0f / lrow[r];
      size_t row = (size_t)(bb*T_ + qb*128 + wv*16 + g*4 + r);
      #pragma unroll
      for (int n = 0; n < 4; n++)
        o[row*D_ + hh*64 + n*16 + lr] = f2bf(ov[n][r] * inv);
    }
  } else {
    const int blk = bh*8 + (qb - 8);
    unsigned short* Od = Opart + ((size_t)blk*2 + half)*128*64;
    #pragma unroll
    for (int r = 0; r < 4; r++) {
      const int rloc = wv*16 + g*4 + r;
      #pragma unroll
      for (int n = 0; n < 4; n++)
        Od[rloc*64 + n*16 + lr] = f2bf(ov[n][r]);
      if (lr == 0)
        ml[((size_t)blk*2 + half)*128 + rloc] = make_float2(mrow[r], lrow[r]);
    }
  }
}

// ---------------------------------------------------------------- attention split-merge (bf16 partials)
__global__ __launch_bounds__(256) void attn_merge(
    const unsigned short* __restrict__ Opart, const float2* __restrict__ ml,
    unsigned short* __restrict__ o)
{
  const int blk = blockIdx.x;              // bh*8 + (qb-8)
  const int bh = blk >> 3, qb = (blk & 7) + 8;
  const int bb = bh >> 3, hh = bh & 7;
  const int tid = threadIdx.x;
  const int row = tid >> 1, ch = (tid & 1) * 32;
  const unsigned short* O0 = Opart + ((size_t)blk*2 + 0)*128*64;
  const unsigned short* O1 = Opart + ((size_t)blk*2 + 1)*128*64;
  const float2 a = ml[(size_t)blk*2*128 + row];
  const float2 b = ml[((size_t)blk*2 + 1)*128 + row];
  const float M  = fmaxf(a.x, b.x);
  const float e0 = __expf(a.x - M), e1 = __expf(b.x - M);
  const float inv = 1.0f / (a.y*e0 + b.y*e1);
  unsigned short* orow = o + ((size_t)(bb*T_ + qb*128 + row))*D_ + hh*64 + ch;
  #pragma unroll
  for (int c = 0; c < 32; c += 4) {
    ushort4 u0 = *reinterpret_cast<const ushort4*>(&O0[row*64 + ch + c]);
    ushort4 u1 = *reinterpret_cast<const ushort4*>(&O1[row*64 + ch + c]);
    ushort4 pk;
    pk.x = f2bf((bf2f(u0.x)*e0 + bf2f(u1.x)*e1) * inv);
    pk.y = f2bf((bf2f(u0.y)*e0 + bf2f(u1.y)*e1) * inv);
    pk.z = f2bf((bf2f(u0.z)*e0 + bf2f(u1.z)*e1) * inv);
    pk.w = f2bf((bf2f(u0.w)*e0 + bf2f(u1.w)*e1) * inv);
    *reinterpret_cast<ushort4*>(&orow[c]) = pk;
  }
}

// ---------------------------------------------------------------- loss: merge per-panel partials
__global__ __launch_bounds__(256) void loss_merge_kernel(
    const float2* __restrict__ ms, const float* __restrict__ logits,
    const int* __restrict__ labels, float* __restrict__ rowloss, int npan)
{
  const int tid = threadIdx.x, lane = tid & 63, wid = tid >> 6;
  const int row = blockIdx.x * 4 + wid;
  float M = NEGBIG, S = 0.f;
  const float2* p = ms + (size_t)row * npan;
  for (int i = lane; i < npan; i += 64) {
    float2 e = p[i];
    float Mn = fmaxf(M, e.x);
    S = S * __expf(M - Mn) + e.y * __expf(e.x - Mn);
    M = Mn;
  }
  #pragma unroll
  for (int off = 1; off < 64; off <<= 1) {
    float Mo = __shfl_xor(M, off), So = __shfl_xor(S, off);
    float Mn = fmaxf(M, Mo);
    S = S * __expf(M - Mn) + So * __expf(Mo - Mn);
    M = Mn;
  }
  if (lane == 0)
    rowloss[row] = logits[(size_t)row * V_ + labels[row]] - M - logf(S);
}

__global__ __launch_bounds__(256) void loss_final_kernel(
    const float* __restrict__ rowloss, float* __restrict__ out)
{
  __shared__ float red[4];
  const int tid = threadIdx.x, lane = tid & 63, wid = tid >> 6;
  float s = 0.f;
  for (int i = tid; i < BT_; i += 256) s += rowloss[i];
  #pragma unroll
  for (int off = 1; off < 64; off <<= 1) s += __shfl_xor(s, off);
  if (lane == 0) red[wid] = s;
  __syncthreads();
  if (tid == 0) out[0] = -(red[0] + red[1] + red[2] + red[3]) * (1.0f / BT_);
}

// ---------------------------------------------------------------- launch
extern "C" void kernel_launch(void* const* d_in, const int* in_sizes, int n_in,
                              void* d_out, int out_size, void* d_ws, size_t ws_size,
                              hipStream_t stream)
{
  (void)in_sizes; (void)n_in; (void)out_size; (void)ws_size;
  const int*   ids    = (const int*)d_in[0];
  const int*   labels = (const int*)d_in[1];
  const float* tok    = (const float*)d_in[2];
  const float* pos    = (const float*)d_in[3];
  const float* Wq     = (const float*)d_in[4];
  const float* Wk     = (const float*)d_in[5];
  const float* Wv     = (const float*)d_in[6];
  const float* Wo     = (const float*)d_in[7];
  const float* bo     = (const float*)d_in[8];
  const float* ln1g   = (const float*)d_in[9];
  const float* ln1b   = (const float*)d_in[10];
  const float* ln2g   = (const float*)d_in[11];
  const float* ln2b   = (const float*)d_in[12];
  const float* W1     = (const float*)d_in[13];
  const float* b1     = (const float*)d_in[14];
  const float* W2     = (const float*)d_in[15];
  const float* b2     = (const float*)d_in[16];
  const float* lnfg   = (const float*)d_in[17];
  const float* lnfb   = (const float*)d_in[18];
  const float* Wp     = (const float*)d_in[19];
  const float* bp     = (const float*)d_in[20];

  float* out = (float*)d_out;
  char* base = (char*)d_ws;
  unsigned short* x       = (unsigned short*)(base + 0);        //  4,194,304 (bf16 residual)
  unsigned short* xn      = (unsigned short*)(base + 8388608);  //  4,194,304
  float*          rowloss = (float*)(base + 12582912);          //     16,384
  unsigned short* WqkvT   = (unsigned short*)(base + 12599296); //  6,291,456
  unsigned short* W1T     = (unsigned short*)(base + 18890752); //  8,388,608
  unsigned short* W2T     = (unsigned short*)(base + 27279360); //  8,388,608
  unsigned short* WoT     = (unsigned short*)(base + 35667968); //  2,097,152
  unsigned short* qkvh    = (unsigned short*)(base + 37765120); // 12,582,912
  unsigned short* ob      = (unsigned short*)(base + 50348032); //  4,194,304
  unsigned short* h1      = (unsigned short*)(base + 54542336); // 16,777,216
  unsigned short* Opart   = (unsigned short*)(base + 54542336); //  4,194,304 (alias h1: dead during attn)
  float2*         mlbuf   = (float2*)(base + 62930944);         //    262,144 (alias h1 upper half)
  unsigned short* WpT     = (unsigned short*)(base + 37765120); // 32,768,000 (alias: dead at logits time)
  float2*         msbuf   = (float2*)(base + 12599296);         //  4,096,000 (alias: weight-T region, dead at logits time)

  embed_kernel<<<BT_ * D_ / 8 / 256, 256, 0, stream>>>(ids, tok, pos, x);

  qkvw_transpose<<<dim3(16, 2, 96), 256, 0, stream>>>(Wq, Wk, Wv, WqkvT);
  transpose_cast<<<dim3(16, 64, 4), 256, 0, stream>>>(W1, W1T, 2048, 512, 1048576, 1048576);
  transpose_cast<<<dim3(64, 16, 4), 256, 0, stream>>>(W2, W2T, 512, 2048, 1048576, 1048576);
  transpose_cast<<<dim3(16, 16, 4), 256, 0, stream>>>(Wo, WoT, 512, 512, 262144, 262144);

  for (int l = 0; l < NL_; l++) {
    ln_kernel<<<BT_ / 4, 256, 0, stream>>>(x, ln1g + l * D_, ln1b + l * D_, xn);
    gemm_pipe<64,64,2,2><<<dim3(64, 24), 256, 0, stream>>>(
        xn, WqkvT + (size_t)l * 1536 * 512, 512, nullptr, nullptr, nullptr, qkvh, 1536, 0);
    attn_mfma<<<dim3(24, B_ * H_), 512, 0, stream>>>(qkvh, ob, Opart, mlbuf);
    attn_merge<<<128, 256, 0, stream>>>(Opart, mlbuf, ob);
    gemm_pipe<64,64,2,2><<<dim3(64, 8), 256, 0, stream>>>(
        ob, WoT + (size_t)l * 512 * 512, 512, bo + l * D_, x, nullptr, x, D_, 0);
    ln_kernel<<<BT_ / 4, 256, 0, stream>>>(x, ln2g + l * D_, ln2b + l * D_, xn);
    gemm_pipe<64,64,2,2><<<dim3(64, 32), 256, 0, stream>>>(
        xn, W1T + (size_t)l * 2048 * 512, 512, b1 + l * 4 * D_, nullptr, nullptr, h1, 4 * D_, 1);
    gemm_pipe<64,64,2,2><<<dim3(64, 8), 256, 0, stream>>>(
        h1, W2T + (size_t)l * 512 * 2048, 2048, b2 + l * D_, x, nullptr, x, D_, 0);
  }

  transpose_cast<<<dim3(16, 1000, 1), 256, 0, stream>>>(Wp, WpT, 32000, 512, 0, 0);
  ln_kernel<<<BT_ / 4, 256, 0, stream>>>(x, lnfg, lnfb, xn);
  gemm_logits<<<dim3(32, 125), 512, 0, stream>>>(
      xn, WpT, 512, bp, out, V_, msbuf, 125);

  loss_merge_kernel<<<BT_ / 4, 256, 0, stream>>>(msbuf, out, labels, rowloss, 125);
  loss_final_kernel<<<1, 256, 0, stream>>>(rowloss, out + (size_t)BT_ * V_);
}

// Round 22
// 873.054 us; speedup vs baseline: 1.0547x; 1.0017x over previous
//
#include <hip/hip_runtime.h>
#include <hip/hip_bf16.h>
#include <math.h>

#define B_ 2
#define T_ 2048
#define D_ 512
#define H_ 8
#define NL_ 4
#define V_ 32000
#define HD_ 64
#define BT_ (B_*T_)
#define EPS_ 1e-5f
#define SCALE_ 0.04419417382415922f  /* 1/sqrt(512) — source scales by D, not HD */
#define NEGBIG -1e30f

typedef __bf16 bf16x8 __attribute__((ext_vector_type(8)));
typedef float  f32x4  __attribute__((ext_vector_type(4)));

__device__ __forceinline__ unsigned short f2bf(float f) {
  union { float f; unsigned u; } v; v.f = f;
  unsigned r = v.u + 0x7fff + ((v.u >> 16) & 1);
  return (unsigned short)(r >> 16);
}
__device__ __forceinline__ float bf2f(unsigned short h) {
  union { unsigned u; float f; } c; c.u = ((unsigned)h) << 16; return c.f;
}

__device__ __forceinline__ void gl_lds16(const void* g, void* l) {
  __builtin_amdgcn_global_load_lds(
      (const __attribute__((address_space(1))) void*)g,
      (__attribute__((address_space(3))) void*)l, 16, 0, 0);
}

#define WAITVM(n) asm volatile("s_waitcnt vmcnt(" #n ")" ::: "memory")
#define WAITLG0   asm volatile("s_waitcnt lgkmcnt(0)" ::: "memory")

// ---------------------------------------------------------------- embed -> bf16 x
__global__ __launch_bounds__(256) void embed_kernel(
    const int* __restrict__ ids, const float* __restrict__ tok,
    const float* __restrict__ pos, unsigned short* __restrict__ x)
{
  int i = blockIdx.x * 256 + threadIdx.x;   // chunk of 8 elems
  int c8 = i & 63;
  int bt = i >> 6;
  int t  = bt & (T_ - 1);
  const float4* tr = reinterpret_cast<const float4*>(tok + (size_t)ids[bt] * D_ + c8*8);
  const float4* pr = reinterpret_cast<const float4*>(pos + (size_t)t * D_ + c8*8);
  float4 a0 = tr[0], a1 = tr[1], p0 = pr[0], p1 = pr[1];
  ushort4 o0, o1;
  o0.x = f2bf(a0.x + p0.x); o0.y = f2bf(a0.y + p0.y);
  o0.z = f2bf(a0.z + p0.z); o0.w = f2bf(a0.w + p0.w);
  o1.x = f2bf(a1.x + p1.x); o1.y = f2bf(a1.y + p1.y);
  o1.z = f2bf(a1.z + p1.z); o1.w = f2bf(a1.w + p1.w);
  unsigned short* orow = x + (size_t)bt * D_ + c8*8;
  *reinterpret_cast<ushort4*>(orow)     = o0;
  *reinterpret_cast<ushort4*>(orow + 4) = o1;
}

// ---------------------------------------------------------------- layernorm (bf16 in) -> bf16 out
__global__ __launch_bounds__(256) void ln_kernel(
    const unsigned short* __restrict__ x, const float* __restrict__ g,
    const float* __restrict__ b, unsigned short* __restrict__ out)
{
  int row  = blockIdx.x * 4 + (threadIdx.x >> 6);
  int lane = threadIdx.x & 63;
  const unsigned short* xr = x + (size_t)row * D_;
  ushort4 u0 = *reinterpret_cast<const ushort4*>(xr + lane*4);
  ushort4 u1 = *reinterpret_cast<const ushort4*>(xr + 256 + lane*4);
  float v0x = bf2f(u0.x), v0y = bf2f(u0.y), v0z = bf2f(u0.z), v0w = bf2f(u0.w);
  float v1x = bf2f(u1.x), v1y = bf2f(u1.y), v1z = bf2f(u1.z), v1w = bf2f(u1.w);
  float s = v0x + v0y + v0z + v0w + v1x + v1y + v1z + v1w;
  float q = v0x*v0x + v0y*v0y + v0z*v0z + v0w*v0w
          + v1x*v1x + v1y*v1y + v1z*v1z + v1w*v1w;
  #pragma unroll
  for (int off = 1; off < 64; off <<= 1) {
    s += __shfl_xor(s, off);
    q += __shfl_xor(q, off);
  }
  float mean = s * (1.0f / D_);
  float var  = q * (1.0f / D_) - mean * mean;
  float rs   = rsqrtf(var + EPS_);
  const float4* g4 = reinterpret_cast<const float4*>(g);
  const float4* b4 = reinterpret_cast<const float4*>(b);
  float4 gv0 = g4[lane], gv1 = g4[lane + 64];
  float4 bv0 = b4[lane], bv1 = b4[lane + 64];
  ushort4 p0, p1;
  p0.x = f2bf((v0x - mean) * rs * gv0.x + bv0.x);
  p0.y = f2bf((v0y - mean) * rs * gv0.y + bv0.y);
  p0.z = f2bf((v0z - mean) * rs * gv0.z + bv0.z);
  p0.w = f2bf((v0w - mean) * rs * gv0.w + bv0.w);
  p1.x = f2bf((v1x - mean) * rs * gv1.x + bv1.x);
  p1.y = f2bf((v1y - mean) * rs * gv1.y + bv1.y);
  p1.z = f2bf((v1z - mean) * rs * gv1.z + bv1.z);
  p1.w = f2bf((v1w - mean) * rs * gv1.w + bv1.w);
  unsigned short* orow = out + (size_t)row * D_;
  *reinterpret_cast<ushort4*>(orow + lane * 4)       = p0;
  *reinterpret_cast<ushort4*>(orow + 256 + lane * 4) = p1;
}

// ---------------------------------------------------------------- transpose+cast fp32 [R][C] -> bf16 [C][R]
__global__ __launch_bounds__(256) void transpose_cast(
    const float* __restrict__ src, unsigned short* __restrict__ dst,
    int C, int R, long sstride, long dstride)
{
  src += (size_t)blockIdx.z * sstride;
  dst += (size_t)blockIdx.z * dstride;
  __shared__ float t[32][33];
  int r0 = blockIdx.x * 32, c0 = blockIdx.y * 32;
  int tx = threadIdx.x & 31, ty = threadIdx.x >> 5;
  #pragma unroll
  for (int i = 0; i < 4; i++)
    t[ty + i*8][tx] = src[(size_t)(r0 + ty + i*8) * C + c0 + tx];
  __syncthreads();
  #pragma unroll
  for (int i = 0; i < 4; i++)
    dst[(size_t)(c0 + ty + i*8) * R + r0 + tx] = f2bf(t[tx][ty + i*8]);
}

// WqkvT[l][mat*512 + h*64 + e][d] = W{q,k,v}[l][h][d][e]
__global__ __launch_bounds__(256) void qkvw_transpose(
    const float* __restrict__ Wq, const float* __restrict__ Wk,
    const float* __restrict__ Wv, unsigned short* __restrict__ dst)
{
  int z = blockIdx.z; int l = z / 24; int rem = z % 24; int mat = rem >> 3; int h = rem & 7;
  const float* W = (mat == 0 ? Wq : (mat == 1 ? Wk : Wv)) + ((size_t)(l * 8 + h)) * D_ * HD_;
  unsigned short* d = dst + ((size_t)l * 1536 + mat * 512 + h * 64) * D_;
  __shared__ float t[32][33];
  int d0 = blockIdx.x * 32, e0 = blockIdx.y * 32;
  int tx = threadIdx.x & 31, ty = threadIdx.x >> 5;
  #pragma unroll
  for (int i = 0; i < 4; i++)
    t[ty + i*8][tx] = W[(size_t)(d0 + ty + i*8) * HD_ + e0 + tx];
  __syncthreads();
  #pragma unroll
  for (int i = 0; i < 4; i++)
    d[(size_t)(e0 + ty + i*8) * D_ + d0 + tx] = f2bf(t[tx][ty + i*8]);
}

// ---------------------------------------------------------------- logits GEMM: 128x256 tile
// 2 LDS buffers, depth-1 counted vmcnt (48 KB LDS -> 3 blocks/CU). Fused
// per-(row,panel) softmax partials (LDS-merged) + 4-chunk LDS-transposed
// nontemporal dwordx4 fp32 stores.
__global__ __launch_bounds__(512, 4) void gemm_logits(
    const unsigned short* __restrict__ A,
    const unsigned short* __restrict__ Bt,
    int K, const float* __restrict__ bias,
    float* __restrict__ outF, int ldc,
    float2* __restrict__ ms, int npan)
{
  __shared__ __align__(16) char smem[49152];
  unsigned short* Abase = (unsigned short*)smem;
  unsigned short* Bbase = (unsigned short*)(smem + 16384);
  float* E = (float*)smem;
  float2* msL = (float2*)smem;

  const int tid = threadIdx.x;
  const int lane = tid & 63;
  const int lr = lane & 15, g = lane >> 4;
  const int wv = tid >> 6, wm = wv >> 2, wn = wv & 3;

  const int gx = gridDim.x;
  int id = blockIdx.y * gx + blockIdx.x;
  const int nwg = gx * gridDim.y;
  if ((nwg & 7) == 0) { const int q = nwg >> 3; id = (id & 7) * q + (id >> 3); }
  const int bm = (id % gx) * 128, bn = (id / gx) * 256, bnp = id / gx;

  const int schk = (lane & 3) ^ ((lane >> 3) & 3);
  const unsigned short* Ab = A  + (size_t)(bm + wv*16 + (lane >> 2)) * K + schk * 8;
  const unsigned short* Bb = Bt + (size_t)(bn + wv*16 + (lane >> 2)) * K + schk * 8;

#define STAGEL(s, sl)                                                       \
  { const int kof_ = (s) * 32;                                              \
    gl_lds16(Ab + kof_,                 Abase + (sl)*4096 + wv*512);        \
    gl_lds16(Bb + kof_,                 Bbase + (sl)*8192 + wv*512);        \
    gl_lds16(Bb + (size_t)128*K + kof_, Bbase + (sl)*8192 + 4096 + wv*512); }

  f32x4 acc[4][4];
  #pragma unroll
  for (int m = 0; m < 4; m++)
    #pragma unroll
    for (int n = 0; n < 4; n++)
      acc[m][n] = (f32x4){0.f, 0.f, 0.f, 0.f};

  const int nt = K >> 5;
  STAGEL(0, 0);

  const int slotx = (g ^ ((lr >> 1) & 3)) << 3;

  for (int t = 0; t < nt; ++t) {
    __builtin_amdgcn_sched_barrier(0);
    if (t + 1 < nt) { STAGEL(t + 1, (t + 1) & 1); WAITVM(3); }
    else            { WAITVM(0); }
    __builtin_amdgcn_sched_barrier(0);
    __builtin_amdgcn_s_barrier();
    __builtin_amdgcn_sched_barrier(0);

    const unsigned short* Ac = Abase + (t & 1)*4096;
    const unsigned short* Bc = Bbase + (t & 1)*8192;
    bf16x8 af[4], bfr[4];
    #pragma unroll
    for (int m = 0; m < 4; m++)
      af[m] = *reinterpret_cast<const bf16x8*>(&Ac[(wm*64 + m*16 + lr) * 32 + slotx]);
    #pragma unroll
    for (int n = 0; n < 4; n++)
      bfr[n] = *reinterpret_cast<const bf16x8*>(&Bc[(wn*64 + n*16 + lr) * 32 + slotx]);
    __builtin_amdgcn_s_setprio(1);
    #pragma unroll
    for (int m = 0; m < 4; m++)
      #pragma unroll
      for (int n = 0; n < 4; n++)
        acc[m][n] = __builtin_amdgcn_mfma_f32_16x16x32_bf16(af[m], bfr[n], acc[m][n], 0, 0, 0);
    __builtin_amdgcn_s_setprio(0);
    __builtin_amdgcn_sched_barrier(0);
    __builtin_amdgcn_s_barrier();
  }
#undef STAGEL

  #pragma unroll
  for (int n = 0; n < 4; n++) {
    const float bv = bias ? bias[bn + wn*64 + n*16 + lr] : 0.f;
    #pragma unroll
    for (int m = 0; m < 4; m++)
      #pragma unroll
      for (int r = 0; r < 4; r++)
        acc[m][n][r] += bv;
  }

  if (ms) {
    #pragma unroll
    for (int m = 0; m < 4; m++) {
      float vmax[4] = {NEGBIG, NEGBIG, NEGBIG, NEGBIG};
      #pragma unroll
      for (int n = 0; n < 4; n++)
        #pragma unroll
        for (int r = 0; r < 4; r++)
          vmax[r] = fmaxf(vmax[r], acc[m][n][r]);
      #pragma unroll
      for (int r = 0; r < 4; r++) {
        #pragma unroll
        for (int off = 1; off < 16; off <<= 1)
          vmax[r] = fmaxf(vmax[r], __shfl_xor(vmax[r], off));
      }
      float vsum[4] = {0.f, 0.f, 0.f, 0.f};
      #pragma unroll
      for (int n = 0; n < 4; n++)
        #pragma unroll
        for (int r = 0; r < 4; r++)
          vsum[r] += __expf(acc[m][n][r] - vmax[r]);
      #pragma unroll
      for (int r = 0; r < 4; r++) {
        #pragma unroll
        for (int off = 1; off < 16; off <<= 1)
          vsum[r] += __shfl_xor(vsum[r], off);
      }
      if (lr == 0) {
        #pragma unroll
        for (int r = 0; r < 4; r++)
          msL[(wm*64 + m*16 + g*4 + r) * 4 + wn] = make_float2(vmax[r], vsum[r]);
      }
    }
    __syncthreads();
    if (tid < 128) {
      float M = NEGBIG, S = 0.f;
      #pragma unroll
      for (int w = 0; w < 4; w++) {
        float2 e = msL[tid * 4 + w];
        float Mn = fmaxf(M, e.x);
        S = S * __expf(M - Mn) + e.y * __expf(e.x - Mn);
        M = Mn;
      }
      ms[(size_t)(bm + tid) * npan + bnp] = make_float2(M, S);
    }
  }

  #pragma unroll
  for (int c = 0; c < 4; ++c) {
    __syncthreads();
    if (wm == (c >> 1)) {
      const int mb = (c & 1) * 2;
      #pragma unroll
      for (int mm = 0; mm < 2; mm++)
        #pragma unroll
        for (int n = 0; n < 4; n++)
          #pragma unroll
          for (int r = 0; r < 4; r++)
            E[(mm*16 + g*4 + r) * 260 + wn*64 + n*16 + lr] = acc[mb + mm][n][r];
    }
    __syncthreads();
    #pragma unroll
    for (int rep = 0; rep < 4; rep++) {
      const int row = rep*8 + wv;
      f32x4 v = *reinterpret_cast<const f32x4*>(&E[row*260 + lane*4]);
      __builtin_nontemporal_store(
          v, reinterpret_cast<f32x4*>(&outF[(size_t)(bm + c*32 + row) * ldc + bn + lane*4]));
    }
  }
}

// ---------------------------------------------------------------- pipelined bf16 MFMA GEMM
template<int BM_T, int BN_T, int WM, int WN>
__global__ __launch_bounds__(256) void gemm_pipe(
    const unsigned short* __restrict__ A,
    const unsigned short* __restrict__ Bt,
    int K,
    const float* __restrict__ bias,
    const unsigned short* __restrict__ resid,
    float* __restrict__ outF,
    unsigned short* __restrict__ outH,
    int ldc, int relu)
{
  constexpr int BKp = 64;
  constexpr int ALOADS = BM_T / 32;
  constexpr int BLOADS = BN_T / 32;
  constexpr int LOADS  = ALOADS + BLOADS;
  constexpr int MR = BM_T / (16 * WM);
  constexpr int NR = BN_T / (16 * WN);
  __shared__ __align__(16) unsigned short As[2][BM_T * BKp];
  __shared__ __align__(16) unsigned short Bs[2][BN_T * BKp];

  const int tid = threadIdx.x;
  const int lane = tid & 63, wv = tid >> 6;
  const int lr = lane & 15, g = lane >> 4;

  const int gx = gridDim.x;
  int id = blockIdx.y * gx + blockIdx.x;
  const int nwg = gx * gridDim.y;
  if ((nwg & 7) == 0) {
    const int q = nwg >> 3;
    id = (id & 7) * q + (id >> 3);
  }
  const int bm = (id % gx) * BM_T, bn = (id / gx) * BN_T;

  const int m0w = (wv / WN) * (BM_T / WM);
  const int n0w = (wv % WN) * (BN_T / WN);

  const int srow = wv*8 + (lane >> 3);
  const int schk = (lane & 7) ^ (lane >> 3);
  const unsigned short* Ab = A  + (size_t)(bm + srow) * K + schk * 8;
  const unsigned short* Bb = Bt + (size_t)(bn + srow) * K + schk * 8;

#define STAGEP(s, sl)                                                           \
  { const int kof_ = (s) * BKp;                                                 \
    _Pragma("unroll")                                                           \
    for (int i_ = 0; i_ < ALOADS; ++i_)                                         \
      gl_lds16(Ab + (size_t)(i_*32)*K + kof_, As[sl] + i_*2048 + wv*512);       \
    _Pragma("unroll")                                                           \
    for (int i_ = 0; i_ < BLOADS; ++i_)                                         \
      gl_lds16(Bb + (size_t)(i_*32)*K + kof_, Bs[sl] + i_*2048 + wv*512); }

  f32x4 acc[MR][NR];
  #pragma unroll
  for (int m = 0; m < MR; m++)
    #pragma unroll
    for (int n = 0; n < NR; n++)
      acc[m][n] = (f32x4){0.f, 0.f, 0.f, 0.f};

  const int nt = K >> 6;
  STAGEP(0, 0);

  for (int t = 0; t < nt; ++t) {
    __builtin_amdgcn_sched_barrier(0);
    if (t + 1 < nt) {
      STAGEP(t + 1, (t + 1) & 1);
      if constexpr (LOADS == 4) WAITVM(4);
      else if constexpr (LOADS == 6) WAITVM(6);
      else WAITVM(8);
    } else {
      WAITVM(0);
    }
    __builtin_amdgcn_sched_barrier(0);
    __builtin_amdgcn_s_barrier();          // tile t visible to all waves
    __builtin_amdgcn_sched_barrier(0);

    const unsigned short* Ac = As[t & 1];
    const unsigned short* Bc = Bs[t & 1];
    #pragma unroll
    for (int kk = 0; kk < 2; ++kk) {
      const int sl = ((kk*4 + g) ^ (lr & 7)) << 3;
      bf16x8 af[MR], bfr[NR];
      #pragma unroll
      for (int m = 0; m < MR; m++)
        af[m] = *reinterpret_cast<const bf16x8*>(&Ac[(m0w + m*16 + lr) * BKp + sl]);
      #pragma unroll
      for (int n = 0; n < NR; n++)
        bfr[n] = *reinterpret_cast<const bf16x8*>(&Bc[(n0w + n*16 + lr) * BKp + sl]);
      __builtin_amdgcn_s_setprio(1);
      #pragma unroll
      for (int m = 0; m < MR; m++)
        #pragma unroll
        for (int n = 0; n < NR; n++)
          acc[m][n] = __builtin_amdgcn_mfma_f32_16x16x32_bf16(af[m], bfr[n], acc[m][n], 0, 0, 0);
      __builtin_amdgcn_s_setprio(0);
    }
    __builtin_amdgcn_sched_barrier(0);
    __builtin_amdgcn_s_barrier();          // all waves done reading buf[t&1]
  }
#undef STAGEP

  const int cr = g * 4;
  const int cc = lr;
  #pragma unroll
  for (int m = 0; m < MR; m++) {
    #pragma unroll
    for (int n = 0; n < NR; n++) {
      int row = bm + m0w + m*16 + cr;
      int col = bn + n0w + n*16 + cc;
      f32x4 a = acc[m][n];
      #pragma unroll
      for (int r = 0; r < 4; r++) {
        float v = a[r];
        if (bias)  v += bias[col];
        if (resid) v += bf2f(resid[(size_t)(row + r) * ldc + col]);
        if (relu)  v = fmaxf(v, 0.f);
        if (outF)  outF[(size_t)(row + r) * ldc + col] = v;
        if (outH)  outH[(size_t)(row + r) * ldc + col] = f2bf(v);
      }
    }
  }
}

// ---------------------------------------------------------------- MFMA flash attention (bf16 in/out)
// 128 q-rows per block, 8 waves. Fine-grained work-split: whole for qb<=5,
// 2-way halves for qb 6-11, 4-way quarters for qb 12-15 (34 slots/bh, sorted
// heavy-first). Partials (bf16) merged by attn_merge. 28 partial slots per bh.
__global__ __launch_bounds__(512) void attn_mfma(
    const unsigned short* __restrict__ qkv,  // bf16 [B*T][1536]
    unsigned short* __restrict__ o,          // bf16 [B*T][512]
    unsigned short* __restrict__ Opart,      // [16 bh][28][128][64] bf16
    float2* __restrict__ ml)                 // [16 bh][28][128]
{
  __shared__ __align__(16) unsigned short Ks[2][64*64];
  __shared__ __align__(16) unsigned short Vt[2][64*64];
  __shared__ __align__(16) unsigned short Ps[8][16*64];

  // slot tables (heavy-first): qb, it0, itn, partial-slot (255 = whole task)
  static const unsigned char sqb[34]  = {5,11,11,10,10,4,9,9,8,8,3,7,7,14,14,15,15,15,15,6,6,12,12,13,13,13,13,14,14,2,12,12,1,0};
  static const unsigned char sit0[34] = {0,0,12,0,11,0,0,10,0,9,0,0,8,0,8,0,8,16,24,0,7,0,7,0,7,14,21,16,23,0,14,20,0,0};
  static const unsigned char sitn[34] = {12,12,12,11,11,10,10,10,9,9,8,8,8,8,8,8,8,8,8,7,7,7,7,7,7,7,7,7,7,6,6,6,4,2};
  static const unsigned char sps[34]  = {255,10,11,8,9,255,6,7,4,5,255,2,3,20,21,24,25,26,27,0,1,12,13,16,17,18,19,22,23,255,14,15,255,255};

  const int slot = blockIdx.x;
  const int bh = blockIdx.y, bb = bh >> 3, hh = bh & 7;
  const int qb  = sqb[slot];
  const int it0 = sit0[slot];
  const int itn = sitn[slot];
  const int ps  = sps[slot];

  const int tid = threadIdx.x, lane = tid & 63, wv = tid >> 6;
  const int lr = lane & 15, g = lane >> 4;

  const unsigned short* qp = qkv + ((size_t)(bb*T_ + qb*128))*1536 + hh*64;
  const unsigned short* kp = qkv + ((size_t)bb*T_)*1536 + 512  + hh*64;
  const unsigned short* vp = qkv + ((size_t)bb*T_)*1536 + 1024 + hh*64;

  bf16x8 qf[2];
  qf[0] = *reinterpret_cast<const bf16x8*>(qp + (size_t)(wv*16 + lr)*1536 + g*8);
  qf[1] = *reinterpret_cast<const bf16x8*>(qp + (size_t)(wv*16 + lr)*1536 + 32 + g*8);

  const int krow = wv*8 + (lane >> 3);
  const int khb  = (lane & 7) ^ (lane >> 3);

#define STAGE_K(s0_, buf_)                                           \
  gl_lds16(kp + (size_t)((s0_)*64 + krow)*1536 + khb*8,              \
           (void*)(Ks[buf_] + wv*512));

  uint4 uvr;
#define LOAD_V(s0_)                                                  \
  uvr = *reinterpret_cast<const uint4*>(                             \
      vp + (size_t)((s0_)*64 + lane)*1536 + wv*8);

  f32x4 ov[4];
  #pragma unroll
  for (int n = 0; n < 4; n++) ov[n] = (f32x4){0.f, 0.f, 0.f, 0.f};
  float mrow[4] = {NEGBIG, NEGBIG, NEGBIG, NEGBIG};
  float lrow[4] = {0.f, 0.f, 0.f, 0.f};

  STAGE_K(it0, 0);
  LOAD_V(it0);

  for (int ii = 0; ii < itn; ++ii) {
    const int s0 = it0 + ii;
    const int cur = ii & 1;
    WAITVM(0);                         // K(cur) in LDS, V(cur) in regs
    __builtin_amdgcn_sched_barrier(0);
    {                                  // write V(cur) regs -> Vt[cur] (swizzled)
      union { uint4 v; unsigned short e[8]; } uv; uv.v = uvr;
      #pragma unroll
      for (int j = 0; j < 8; j++)
        Vt[cur][(wv*8 + j)*64 + (((lane >> 3) ^ j) << 3) + (lane & 7)] = uv.e[j];
    }
    WAITLG0;
    __builtin_amdgcn_sched_barrier(0);
    __builtin_amdgcn_s_barrier();      // K/V tile cur visible to all waves
    __builtin_amdgcn_sched_barrier(0);

    if (ii + 1 < itn) {                // async prefetch of next tile
      STAGE_K(s0 + 1, cur ^ 1);
      LOAD_V(s0 + 1);
    }

    // --- S = Q @ K^T
    f32x4 sf[4];
    #pragma unroll
    for (int n = 0; n < 4; n++) sf[n] = (f32x4){0.f, 0.f, 0.f, 0.f};
    __builtin_amdgcn_s_setprio(1);
    #pragma unroll
    for (int kk = 0; kk < 2; kk++) {
      #pragma unroll
      for (int n = 0; n < 4; n++) {
        const bf16x8 kf = *reinterpret_cast<const bf16x8*>(
            &Ks[cur][(n*16 + lr)*64 + (((kk*4 + g) ^ (lr & 7)) << 3)]);
        sf[n] = __builtin_amdgcn_mfma_f32_16x16x32_bf16(qf[kk], kf, sf[n], 0, 0, 0);
      }
    }
    __builtin_amdgcn_s_setprio(0);

    // --- scale + causal mask
    float sv[4][4];
    #pragma unroll
    for (int n = 0; n < 4; n++)
      #pragma unroll
      for (int r = 0; r < 4; r++) {
        const int kvg = s0*64 + n*16 + lr;
        const int qg  = qb*128 + wv*16 + g*4 + r;
        sv[n][r] = (kvg > qg) ? NEGBIG : sf[n][r] * SCALE_;
      }

    float aa[4];
    #pragma unroll
    for (int r = 0; r < 4; r++) {
      float pm = fmaxf(fmaxf(sv[0][r], sv[1][r]), fmaxf(sv[2][r], sv[3][r]));
      pm = fmaxf(pm, __shfl_xor(pm, 1));
      pm = fmaxf(pm, __shfl_xor(pm, 2));
      pm = fmaxf(pm, __shfl_xor(pm, 4));
      pm = fmaxf(pm, __shfl_xor(pm, 8));
      float mn = fmaxf(mrow[r], pm);
      aa[r] = __expf(mrow[r] - mn);
      mrow[r] = mn;
    }
    float rs[4] = {0.f, 0.f, 0.f, 0.f};
    #pragma unroll
    for (int n = 0; n < 4; n++)
      #pragma unroll
      for (int r = 0; r < 4; r++) {
        float p = __expf(sv[n][r] - mrow[r]);
        rs[r] += p;
        Ps[wv][(g*4 + r)*64 + ((((n << 1) + (lr >> 3)) ^ ((g*4 + r) & 7)) << 3) + (lr & 7)] = f2bf(p);
      }
    #pragma unroll
    for (int r = 0; r < 4; r++) {
      float s = rs[r];
      s += __shfl_xor(s, 1); s += __shfl_xor(s, 2);
      s += __shfl_xor(s, 4); s += __shfl_xor(s, 8);
      lrow[r] = lrow[r]*aa[r] + s;
    }
    #pragma unroll
    for (int n = 0; n < 4; n++)
      #pragma unroll
      for (int r = 0; r < 4; r++)
        ov[n][r] *= aa[r];

    // --- O += P @ V
    __builtin_amdgcn_s_setprio(1);
    #pragma unroll
    for (int kk = 0; kk < 2; kk++) {
      const bf16x8 pf = *reinterpret_cast<const bf16x8*>(
          &Ps[wv][lr*64 + (((kk*4 + g) ^ (lr & 7)) << 3)]);
      #pragma unroll
      for (int n = 0; n < 4; n++) {
        const bf16x8 vf = *reinterpret_cast<const bf16x8*>(
            &Vt[cur][(n*16 + lr)*64 + (((kk*4 + g) ^ (lr & 7)) << 3)]);
        ov[n] = __builtin_amdgcn_mfma_f32_16x16x32_bf16(pf, vf, ov[n], 0, 0, 0);
      }
    }
    __builtin_amdgcn_s_setprio(0);
    __builtin_amdgcn_sched_barrier(0);
    __builtin_amdgcn_s_barrier();      // all waves done reading tile cur
  }
#undef STAGE_K
#undef LOAD_V

  if (ps == 255) {
    // whole task: normalize + write output
    #pragma unroll
    for (int r = 0; r < 4; r++) {
      float inv = 1.0f / lrow[r];
      size_t row = (size_t)(bb*T_ + qb*128 + wv*16 + g*4 + r);
      #pragma unroll
      for (int n = 0; n < 4; n++)
        o[row*D_ + hh*64 + n*16 + lr] = f2bf(ov[n][r] * inv);
    }
  } else {
    // partial: emit unnormalized O (bf16) + (m,l)
    const size_t blk = (size_t)bh*28 + ps;
    unsigned short* Od = Opart + blk*128*64;
    #pragma unroll
    for (int r = 0; r < 4; r++) {
      const int rloc = wv*16 + g*4 + r;
      #pragma unroll
      for (int n = 0; n < 4; n++)
        Od[rloc*64 + n*16 + lr] = f2bf(ov[n][r]);
      if (lr == 0)
        ml[blk*128 + rloc] = make_float2(mrow[r], lrow[r]);
    }
  }
}

// ---------------------------------------------------------------- attention split-merge (2-way or 4-way)
__global__ __launch_bounds__(256) void attn_merge(
    const unsigned short* __restrict__ Opart, const float2* __restrict__ ml,
    unsigned short* __restrict__ o)
{
  const int j  = blockIdx.x;               // task 0..9 -> qb = 6+j
  const int bh = blockIdx.y;
  const int qb = 6 + j;
  const int bb = bh >> 3, hh = bh & 7;
  const int ns  = (qb < 12) ? 2 : 4;
  const int psb = (qb < 12) ? (2*j) : (12 + (qb - 12)*4);
  const int tid = threadIdx.x;
  const int row = tid >> 1, ch = (tid & 1) * 32;

  float mv[4], lv[4];
  float M = NEGBIG;
  for (int p = 0; p < ns; ++p) {
    float2 e = ml[((size_t)bh*28 + psb + p)*128 + row];
    mv[p] = e.x; lv[p] = e.y;
    M = fmaxf(M, e.x);
  }
  float S = 0.f, ef[4];
  for (int p = 0; p < ns; ++p) { ef[p] = __expf(mv[p] - M); S += lv[p]*ef[p]; }
  const float inv = 1.0f / S;

  unsigned short* orow = o + ((size_t)(bb*T_ + qb*128 + row))*D_ + hh*64 + ch;
  #pragma unroll
  for (int c = 0; c < 32; c += 4) {
    float a0 = 0.f, a1 = 0.f, a2 = 0.f, a3 = 0.f;
    for (int p = 0; p < ns; ++p) {
      const unsigned short* Op = Opart + ((size_t)bh*28 + psb + p)*128*64;
      ushort4 u = *reinterpret_cast<const ushort4*>(&Op[row*64 + ch + c]);
      a0 += bf2f(u.x)*ef[p]; a1 += bf2f(u.y)*ef[p];
      a2 += bf2f(u.z)*ef[p]; a3 += bf2f(u.w)*ef[p];
    }
    ushort4 pk;
    pk.x = f2bf(a0 * inv); pk.y = f2bf(a1 * inv);
    pk.z = f2bf(a2 * inv); pk.w = f2bf(a3 * inv);
    *reinterpret_cast<ushort4*>(&orow[c]) = pk;
  }
}

// ---------------------------------------------------------------- loss: merge per-panel partials
__global__ __launch_bounds__(256) void loss_merge_kernel(
    const float2* __restrict__ ms, const float* __restrict__ logits,
    const int* __restrict__ labels, float* __restrict__ rowloss, int npan)
{
  const int tid = threadIdx.x, lane = tid & 63, wid = tid >> 6;
  const int row = blockIdx.x * 4 + wid;
  float M = NEGBIG, S = 0.f;
  const float2* p = ms + (size_t)row * npan;
  for (int i = lane; i < npan; i += 64) {
    float2 e = p[i];
    float Mn = fmaxf(M, e.x);
    S = S * __expf(M - Mn) + e.y * __expf(e.x - Mn);
    M = Mn;
  }
  #pragma unroll
  for (int off = 1; off < 64; off <<= 1) {
    float Mo = __shfl_xor(M, off), So = __shfl_xor(S, off);
    float Mn = fmaxf(M, Mo);
    S = S * __expf(M - Mn) + So * __expf(Mo - Mn);
    M = Mn;
  }
  if (lane == 0)
    rowloss[row] = logits[(size_t)row * V_ + labels[row]] - M - logf(S);
}

__global__ __launch_bounds__(256) void loss_final_kernel(
    const float* __restrict__ rowloss, float* __restrict__ out)
{
  __shared__ float red[4];
  const int tid = threadIdx.x, lane = tid & 63, wid = tid >> 6;
  float s = 0.f;
  for (int i = tid; i < BT_; i += 256) s += rowloss[i];
  #pragma unroll
  for (int off = 1; off < 64; off <<= 1) s += __shfl_xor(s, off);
  if (lane == 0) red[wid] = s;
  __syncthreads();
  if (tid == 0) out[0] = -(red[0] + red[1] + red[2] + red[3]) * (1.0f / BT_);
}

// ---------------------------------------------------------------- launch
extern "C" void kernel_launch(void* const* d_in, const int* in_sizes, int n_in,
                              void* d_out, int out_size, void* d_ws, size_t ws_size,
                              hipStream_t stream)
{
  (void)in_sizes; (void)n_in; (void)out_size; (void)ws_size;
  const int*   ids    = (const int*)d_in[0];
  const int*   labels = (const int*)d_in[1];
  const float* tok    = (const float*)d_in[2];
  const float* pos    = (const float*)d_in[3];
  const float* Wq     = (const float*)d_in[4];
  const float* Wk     = (const float*)d_in[5];
  const float* Wv     = (const float*)d_in[6];
  const float* Wo     = (const float*)d_in[7];
  const float* bo     = (const float*)d_in[8];
  const float* ln1g   = (const float*)d_in[9];
  const float* ln1b   = (const float*)d_in[10];
  const float* ln2g   = (const float*)d_in[11];
  const float* ln2b   = (const float*)d_in[12];
  const float* W1     = (const float*)d_in[13];
  const float* b1     = (const float*)d_in[14];
  const float* W2     = (const float*)d_in[15];
  const float* b2     = (const float*)d_in[16];
  const float* lnfg   = (const float*)d_in[17];
  const float* lnfb   = (const float*)d_in[18];
  const float* Wp     = (const float*)d_in[19];
  const float* bp     = (const float*)d_in[20];

  float* out = (float*)d_out;
  char* base = (char*)d_ws;
  unsigned short* x       = (unsigned short*)(base + 0);        //  4,194,304 (bf16 residual)
  unsigned short* xn      = (unsigned short*)(base + 8388608);  //  4,194,304
  float*          rowloss = (float*)(base + 12582912);          //     16,384
  unsigned short* WqkvT   = (unsigned short*)(base + 12599296); //  6,291,456
  unsigned short* W1T     = (unsigned short*)(base + 18890752); //  8,388,608
  unsigned short* W2T     = (unsigned short*)(base + 27279360); //  8,388,608
  unsigned short* WoT     = (unsigned short*)(base + 35667968); //  2,097,152
  unsigned short* qkvh    = (unsigned short*)(base + 37765120); // 12,582,912
  unsigned short* ob      = (unsigned short*)(base + 50348032); //  4,194,304
  unsigned short* h1      = (unsigned short*)(base + 54542336); // 16,777,216
  unsigned short* Opart   = (unsigned short*)(base + 54542336); //  7,340,032 (alias h1: dead during attn)
  float2*         mlbuf   = (float2*)(base + 61882368);         //    458,752 (alias h1 upper part)
  unsigned short* WpT     = (unsigned short*)(base + 37765120); // 32,768,000 (alias: dead at logits time)
  float2*         msbuf   = (float2*)(base + 12599296);         //  4,096,000 (alias: weight-T region, dead at logits time)

  embed_kernel<<<BT_ * D_ / 8 / 256, 256, 0, stream>>>(ids, tok, pos, x);

  qkvw_transpose<<<dim3(16, 2, 96), 256, 0, stream>>>(Wq, Wk, Wv, WqkvT);
  transpose_cast<<<dim3(16, 64, 4), 256, 0, stream>>>(W1, W1T, 2048, 512, 1048576, 1048576);
  transpose_cast<<<dim3(64, 16, 4), 256, 0, stream>>>(W2, W2T, 512, 2048, 1048576, 1048576);
  transpose_cast<<<dim3(16, 16, 4), 256, 0, stream>>>(Wo, WoT, 512, 512, 262144, 262144);

  for (int l = 0; l < NL_; l++) {
    ln_kernel<<<BT_ / 4, 256, 0, stream>>>(x, ln1g + l * D_, ln1b + l * D_, xn);
    gemm_pipe<64,64,2,2><<<dim3(64, 24), 256, 0, stream>>>(
        xn, WqkvT + (size_t)l * 1536 * 512, 512, nullptr, nullptr, nullptr, qkvh, 1536, 0);
    attn_mfma<<<dim3(34, B_ * H_), 512, 0, stream>>>(qkvh, ob, Opart, mlbuf);
    attn_merge<<<dim3(10, B_ * H_), 256, 0, stream>>>(Opart, mlbuf, ob);
    gemm_pipe<64,64,2,2><<<dim3(64, 8), 256, 0, stream>>>(
        ob, WoT + (size_t)l * 512 * 512, 512, bo + l * D_, x, nullptr, x, D_, 0);
    ln_kernel<<<BT_ / 4, 256, 0, stream>>>(x, ln2g + l * D_, ln2b + l * D_, xn);
    gemm_pipe<64,64,2,2><<<dim3(64, 32), 256, 0, stream>>>(
        xn, W1T + (size_t)l * 2048 * 512, 512, b1 + l * 4 * D_, nullptr, nullptr, h1, 4 * D_, 1);
    gemm_pipe<64,64,2,2><<<dim3(64, 8), 256, 0, stream>>>(
        h1, W2T + (size_t)l * 512 * 2048, 2048, b2 + l * D_, x, nullptr, x, D_, 0);
  }

  transpose_cast<<<dim3(16, 1000, 1), 256, 0, stream>>>(Wp, WpT, 32000, 512, 0, 0);
  ln_kernel<<<BT_ / 4, 256, 0, stream>>>(x, lnfg, lnfb, xn);
  gemm_logits<<<dim3(32, 125), 512, 0, stream>>>(
      xn, WpT, 512, bp, out, V_, msbuf, 125);

  loss_merge_kernel<<<BT_ / 4, 256, 0, stream>>>(msbuf, out, labels, rowloss, 125);
  loss_final_kernel<<<1, 256, 0, stream>>>(rowloss, out + (size_t)BT_ * V_);
}